// Round 2
// baseline (12987.488 us; speedup 1.0000x reference)
//
#include <hip/hip_runtime.h>

enum { F_INRELU = 1, F_OUTRELU = 2, F_RES = 4 };

__global__ void enorm_k(const float* __restrict__ emb, float* __restrict__ en) {
    int k = blockIdx.x * 256 + threadIdx.x;
    if (k >= 512) return;
    const float4* e = (const float4*)(emb + k * 128);
    float s = 0.f;
    for (int i = 0; i < 32; ++i) {
        float4 v = e[i];
        s += v.x * v.x + v.y * v.y + v.z * v.z + v.w * v.w;
    }
    en[k] = s;
}

// Direct NHWC conv. One thread per output element (co fastest).
// Input reads are wave-uniform (broadcast); weight reads coalesced over co.
__global__ void conv2d_k(const float* __restrict__ in, const float* __restrict__ w,
                         const float* __restrict__ bias, float* __restrict__ out,
                         const float* __restrict__ res,
                         int IH, int IW, int Ci, int OH, int OW, int Co,
                         int KH, int KW, int stride, int pad, int flags, int total)
{
    int idx = blockIdx.x * 256 + threadIdx.x;
    if (idx >= total) return;
    int co = idx % Co;
    int t  = idx / Co;
    int ox = t % OW; t /= OW;
    int oy = t % OH; t /= OH;
    int n  = t;
    float acc = bias ? bias[co] : 0.f;
    const bool inrelu = (flags & F_INRELU) != 0;
    for (int ky = 0; ky < KH; ++ky) {
        int iy = oy * stride - pad + ky;
        if (iy < 0 || iy >= IH) continue;
        for (int kx = 0; kx < KW; ++kx) {
            int ix = ox * stride - pad + kx;
            if (ix < 0 || ix >= IW) continue;
            const float* ip = in + ((size_t)((n * IH + iy) * IW + ix)) * Ci;
            const float* wp = w + (size_t)((ky * KW + kx) * Ci) * Co + co;
            int ci = 0;
            for (; ci + 4 <= Ci; ci += 4) {
                float4 v = *(const float4*)(ip + ci);
                if (inrelu) {
                    v.x = fmaxf(v.x, 0.f); v.y = fmaxf(v.y, 0.f);
                    v.z = fmaxf(v.z, 0.f); v.w = fmaxf(v.w, 0.f);
                }
                const float* wq = wp + (size_t)ci * Co;
                acc = fmaf(v.x, wq[0],        acc);
                acc = fmaf(v.y, wq[Co],       acc);
                acc = fmaf(v.z, wq[2 * Co],   acc);
                acc = fmaf(v.w, wq[3 * Co],   acc);
            }
            for (; ci < Ci; ++ci) {
                float v = ip[ci];
                if (inrelu) v = fmaxf(v, 0.f);
                acc = fmaf(v, wp[(size_t)ci * Co], acc);
            }
        }
    }
    if (flags & F_RES)     acc += res[idx];
    if (flags & F_OUTRELU) acc = fmaxf(acc, 0.f);
    out[idx] = acc;
}

// conv_transpose, kernel 4x4, stride 2, SAME: pad (2,2) on the lhs-dilated input.
// out[oy,ox,co] = sum over ky ≡ oy (mod 2), kx ≡ ox (mod 2), ci of
//   in[(oy+ky-2)/2, (ox+kx-2)/2, ci] * w[ky,kx,ci,co]
__global__ void convt_k(const float* __restrict__ in, const float* __restrict__ w,
                        const float* __restrict__ bias, float* __restrict__ out,
                        int IH, int IW, int Ci, int OH, int OW, int Co,
                        int flags, int total)
{
    int idx = blockIdx.x * 256 + threadIdx.x;
    if (idx >= total) return;
    int co = idx % Co;
    int t  = idx / Co;
    int ox = t % OW; t /= OW;
    int oy = t % OH; t /= OH;
    int n  = t;
    float acc = bias ? bias[co] : 0.f;
    for (int ty = 0; ty < 2; ++ty) {
        int ky  = (oy & 1) + 2 * ty;
        int iy2 = oy + ky - 2;
        if (iy2 < 0) continue;
        int iy = iy2 >> 1;
        if (iy >= IH) continue;
        for (int tx = 0; tx < 2; ++tx) {
            int kx  = (ox & 1) + 2 * tx;
            int ix2 = ox + kx - 2;
            if (ix2 < 0) continue;
            int ix = ix2 >> 1;
            if (ix >= IW) continue;
            const float* ip = in + (size_t)((n * IH + iy) * IW + ix) * Ci;
            const float* wp = w + (size_t)((ky * 4 + kx) * Ci) * Co + co;
            for (int ci = 0; ci + 4 <= Ci; ci += 4) {
                float4 v = *(const float4*)(ip + ci);
                const float* wq = wp + (size_t)ci * Co;
                acc = fmaf(v.x, wq[0],      acc);
                acc = fmaf(v.y, wq[Co],     acc);
                acc = fmaf(v.z, wq[2 * Co], acc);
                acc = fmaf(v.w, wq[3 * Co], acc);
            }
        }
    }
    if (flags & F_OUTRELU) acc = fmaxf(acc, 0.f);
    out[idx] = acc;
}

// VQ: 32 positions per block, 256 threads = 32 pos-lanes x 8 code-lanes.
// argmin_k ( ||e_k||^2 - 2 f.e_k )  (||f||^2 is row-constant); ties -> lowest k
// (matches np.argmin first-occurrence). Fused codebook gather.
__global__ void vq_k(const float* __restrict__ f, const float* __restrict__ emb,
                     const float* __restrict__ en, float* __restrict__ q)
{
    __shared__ float fs[32 * 132];   // stride 132: float4-aligned, banks spread
    __shared__ float bd[256];
    __shared__ int   bidx[256];
    __shared__ int   sel[32];
    int tid  = threadIdx.x;
    int base = blockIdx.x * (32 * 128);
    for (int i = tid; i < 32 * 128; i += 256)
        fs[(i >> 7) * 132 + (i & 127)] = f[base + i];
    __syncthreads();
    int pl = tid & 31;
    int kl = tid >> 5;                 // 0..7
    const float* fp = fs + pl * 132;
    float best = 3.4e38f; int bk = 0;
    for (int j = 0; j < 16; ++j) {
        int k0 = kl * 4 + 32 * j;      // ascending within each lane
        const float4* e0 = (const float4*)(emb + (size_t)(k0    ) * 128);
        const float4* e1 = (const float4*)(emb + (size_t)(k0 + 1) * 128);
        const float4* e2 = (const float4*)(emb + (size_t)(k0 + 2) * 128);
        const float4* e3 = (const float4*)(emb + (size_t)(k0 + 3) * 128);
        float d0 = 0.f, d1 = 0.f, d2 = 0.f, d3 = 0.f;
        for (int c = 0; c < 32; ++c) {
            float4 v = *(const float4*)(fp + c * 4);
            float4 a = e0[c]; d0 += v.x * a.x + v.y * a.y + v.z * a.z + v.w * a.w;
            float4 b = e1[c]; d1 += v.x * b.x + v.y * b.y + v.z * b.z + v.w * b.w;
            float4 g = e2[c]; d2 += v.x * g.x + v.y * g.y + v.z * g.z + v.w * g.w;
            float4 h = e3[c]; d3 += v.x * h.x + v.y * h.y + v.z * h.z + v.w * h.w;
        }
        float D;
        D = en[k0    ] - 2.f * d0; if (D < best) { best = D; bk = k0;     }
        D = en[k0 + 1] - 2.f * d1; if (D < best) { best = D; bk = k0 + 1; }
        D = en[k0 + 2] - 2.f * d2; if (D < best) { best = D; bk = k0 + 2; }
        D = en[k0 + 3] - 2.f * d3; if (D < best) { best = D; bk = k0 + 3; }
    }
    bd[tid] = best; bidx[tid] = bk;
    __syncthreads();
    if (tid < 32) {
        float bb = bd[tid]; int bb_i = bidx[tid];
        for (int l = 1; l < 8; ++l) {
            float d = bd[l * 32 + tid]; int x = bidx[l * 32 + tid];
            if (d < bb || (d == bb && x < bb_i)) { bb = d; bb_i = x; }
        }
        sel[tid] = bb_i;
    }
    __syncthreads();
    for (int i = tid; i < 32 * 128; i += 256)
        q[base + i] = emb[(size_t)sel[i >> 7] * 128 + (i & 127)];
}

extern "C" void kernel_launch(void* const* d_in, const int* in_sizes, int n_in,
                              void* d_out, int out_size, void* d_ws, size_t ws_size,
                              hipStream_t stream)
{
    const float* x       = (const float*)d_in[0];
    const float* emb     = (const float*)d_in[1];
    const float* enc_w1  = (const float*)d_in[2];
    const float* enc_b1  = (const float*)d_in[3];
    const float* enc_w2  = (const float*)d_in[4];
    const float* enc_b2  = (const float*)d_in[5];
    const float* enc_w3  = (const float*)d_in[6];
    const float* enc_b3  = (const float*)d_in[7];
    const float* erb1_w1 = (const float*)d_in[8];
    const float* erb1_w2 = (const float*)d_in[9];
    const float* erb2_w1 = (const float*)d_in[10];
    const float* erb2_w2 = (const float*)d_in[11];
    const float* dec_w   = (const float*)d_in[12];
    const float* dec_b   = (const float*)d_in[13];
    const float* drb1_w1 = (const float*)d_in[14];
    const float* drb1_w2 = (const float*)d_in[15];
    const float* drb2_w1 = (const float*)d_in[16];
    const float* drb2_w2 = (const float*)d_in[17];
    const float* dt1_w   = (const float*)d_in[18];
    const float* dt1_b   = (const float*)d_in[19];
    const float* dt2_w   = (const float*)d_in[20];
    const float* dt2_b   = (const float*)d_in[21];

    // Workspace layout (aliased; ~104 MB total):
    //   A1 (64 MB): enc conv1 out (128x128x64); its base 32 MB ("B") holds the
    //       encoder feature stack after conv2's A2 is consumed; later reused
    //       whole for upsample1 output. All lifetimes disjoint.
    //   A2 (32 MB): enc conv2 out; later decoder activations Y0.
    //   T  (8 MB): res-block hidden (32 ch).
    //   EN (2 KB): codebook squared norms.
    char* wsb = (char*)d_ws;
    float* A1 = (float*)wsb;                          // 16,777,216 floats
    float* B  = A1;                                   // 8,388,608 floats (alias)
    float* A2 = (float*)(wsb + (size_t)16777216 * 4); // 8,388,608 floats
    float* Y0 = A2;                                   // alias
    float* T  = (float*)(wsb + (size_t)25165824 * 4); // 2,097,152 floats
    float* EN = (float*)(wsb + (size_t)27262976 * 4); // 512 floats

    float* outY = (float*)d_out;         // (16,256,256,3)  = 3,145,728
    float* outF = outY + 3145728;        // (16,64,64,128)  = 8,388,608
    float* outQ = outF + 8388608;        // (16,64,64,128)  = 8,388,608

    auto nb = [](int total) { return (total + 255) / 256; };

    enorm_k<<<2, 256, 0, stream>>>(emb, EN);

    // ---- encoder ----
    conv2d_k<<<nb(16777216), 256, 0, stream>>>(x, enc_w1, enc_b1, A1, nullptr,
        256, 256, 3, 128, 128, 64, 4, 4, 2, 1, F_OUTRELU, 16777216);
    conv2d_k<<<nb(8388608), 256, 0, stream>>>(A1, enc_w2, enc_b2, A2, nullptr,
        128, 128, 64, 64, 64, 128, 4, 4, 2, 1, F_OUTRELU, 8388608);
    conv2d_k<<<nb(8388608), 256, 0, stream>>>(A2, enc_w3, enc_b3, B, nullptr,
        64, 64, 128, 64, 64, 128, 3, 3, 1, 1, 0, 8388608);
    // res block e1 (in-place on B)
    conv2d_k<<<nb(2097152), 256, 0, stream>>>(B, erb1_w1, nullptr, T, nullptr,
        64, 64, 128, 64, 64, 32, 3, 3, 1, 1, F_INRELU, 2097152);
    conv2d_k<<<nb(8388608), 256, 0, stream>>>(T, erb1_w2, nullptr, B, B,
        64, 64, 32, 64, 64, 128, 1, 1, 1, 0, F_INRELU | F_RES, 8388608);
    // res block e2; final conv fuses stack-end relu, writes f straight to d_out
    conv2d_k<<<nb(2097152), 256, 0, stream>>>(B, erb2_w1, nullptr, T, nullptr,
        64, 64, 128, 64, 64, 32, 3, 3, 1, 1, F_INRELU, 2097152);
    conv2d_k<<<nb(8388608), 256, 0, stream>>>(T, erb2_w2, nullptr, outF, B,
        64, 64, 32, 64, 64, 128, 1, 1, 1, 0, F_INRELU | F_RES | F_OUTRELU, 8388608);

    // ---- VQ (reads f from d_out, writes q to d_out) ----
    vq_k<<<2048, 256, 0, stream>>>(outF, emb, EN, outQ);

    // ---- decoder ----
    conv2d_k<<<nb(8388608), 256, 0, stream>>>(outQ, dec_w, dec_b, Y0, nullptr,
        64, 64, 128, 64, 64, 128, 3, 3, 1, 1, 0, 8388608);
    conv2d_k<<<nb(2097152), 256, 0, stream>>>(Y0, drb1_w1, nullptr, T, nullptr,
        64, 64, 128, 64, 64, 32, 3, 3, 1, 1, F_INRELU, 2097152);
    conv2d_k<<<nb(8388608), 256, 0, stream>>>(T, drb1_w2, nullptr, Y0, Y0,
        64, 64, 32, 64, 64, 128, 1, 1, 1, 0, F_INRELU | F_RES, 8388608);
    conv2d_k<<<nb(2097152), 256, 0, stream>>>(Y0, drb2_w1, nullptr, T, nullptr,
        64, 64, 128, 64, 64, 32, 3, 3, 1, 1, F_INRELU, 2097152);
    conv2d_k<<<nb(8388608), 256, 0, stream>>>(T, drb2_w2, nullptr, Y0, Y0,
        64, 64, 32, 64, 64, 128, 1, 1, 1, 0, F_INRELU | F_RES | F_OUTRELU, 8388608);
    // upsample (B region of A1 is dead by now; A1 reused whole)
    convt_k<<<nb(16777216), 256, 0, stream>>>(Y0, dt1_w, dt1_b, A1,
        64, 64, 128, 128, 128, 64, F_OUTRELU, 16777216);
    convt_k<<<nb(3145728), 256, 0, stream>>>(A1, dt2_w, dt2_b, outY,
        128, 128, 64, 256, 256, 3, 0, 3145728);
}

// Round 3
// 4278.741 us; speedup vs baseline: 3.0354x; 3.0354x over previous
//
#include <hip/hip_runtime.h>

enum { F_INRELU = 1, F_OUTRELU = 2, F_RES = 4 };

struct TapSet { int dy[16]; int dx[16]; int wi[16]; };

// ---------------- tiled implicit-GEMM conv (fp32) ----------------
// M = N*OHt*OWt output pixels, N-dim = Co. BM=64, BK=16, BN=64 or 32.
// 256 threads, thread tile TM=4 x TN=BN/16. A-tile gathered (im2col) on the
// fly with per-tap (dy,dx,wi) table; output mapped oy = oy'*sy_out + py so
// conv_transpose parity classes reuse the same kernel.
template<int BN>
__global__ __launch_bounds__(256) void conv_gemm_k(
    const float* __restrict__ in, const float* __restrict__ w,
    const float* __restrict__ bias, float* __restrict__ out,
    const float* __restrict__ res,
    int IH, int IW, int Ci, int Co,
    int OHt, int OWt, int OHf, int OWf,
    int sy_in, int sy_out, int py, int px,
    TapSet taps, int ntaps, int flags)
{
    constexpr int BM = 64, BK = 16;
    constexpr int TM = 4, TN = BN / 16;
    __shared__ __align__(16) float As[BK][BM];
    __shared__ __align__(16) float Bs[BK][BN];

    const int tid = threadIdx.x;
    const int m0 = blockIdx.x * BM;
    const int n0 = blockIdx.y * BN;
    const int area = OHt * OWt;

    // A-staging mapping: thread loads float4 of input channels for pixel am
    const int am = tid >> 2;        // 0..63
    const int aq = tid & 3;         // ci quad
    {
    }
    const int gm  = m0 + am;
    const int n_  = gm / area;
    const int r_  = gm % area;
    const int oy_ = (r_ / OWt) * sy_in;
    const int ox_ = (r_ % OWt) * sy_in;
    const int ibase_n = n_ * IH;

    // B-staging mapping
    const int bk  = tid >> 4;                 // 0..15
    const int bn  = (tid & 15) * ((BN == 64) ? 4 : 2);

    const int tx = tid & 15, ty = tid >> 4;

    float acc[TM][TN];
#pragma unroll
    for (int i = 0; i < TM; ++i)
#pragma unroll
        for (int j = 0; j < TN; ++j) acc[i][j] = 0.f;

    const int cpt = Ci / BK;                  // chunks per tap
    const int nchunks = ntaps * cpt;
    const bool inrelu = (flags & F_INRELU) != 0;

    int tap = 0, cc = 0, ci0 = 0;
    for (int c = 0; c < nchunks; ++c) {
        const int dy = taps.dy[tap], dx = taps.dx[tap], wi = taps.wi[tap];
        // global loads (issued before barrier for overlap)
        const int iy = oy_ + dy;
        const int ix = ox_ + dx;
        float4 av = make_float4(0.f, 0.f, 0.f, 0.f);
        if (iy >= 0 && iy < IH && ix >= 0 && ix < IW)
            av = *(const float4*)(in + ((size_t)(ibase_n + iy) * IW + ix) * Ci + ci0 + aq * 4);
        if (inrelu) {
            av.x = fmaxf(av.x, 0.f); av.y = fmaxf(av.y, 0.f);
            av.z = fmaxf(av.z, 0.f); av.w = fmaxf(av.w, 0.f);
        }
        const float* wp = w + (size_t)(wi * Ci + ci0 + bk) * Co + n0 + bn;
        float4 bv4; float2 bv2;
        if (BN == 64) bv4 = *(const float4*)wp; else bv2 = *(const float2*)wp;

        __syncthreads();   // previous chunk's compute done
        As[aq * 4 + 0][am] = av.x;
        As[aq * 4 + 1][am] = av.y;
        As[aq * 4 + 2][am] = av.z;
        As[aq * 4 + 3][am] = av.w;
        if (BN == 64) *(float4*)&Bs[bk][bn] = bv4;
        else          *(float2*)&Bs[bk][bn] = bv2;
        __syncthreads();

#pragma unroll
        for (int k = 0; k < BK; ++k) {
            float4 a = *(const float4*)&As[k][ty * TM];
            if (BN == 64) {
                float4 b = *(const float4*)&Bs[k][tx * 4];
                acc[0][0] = fmaf(a.x, b.x, acc[0][0]); acc[0][1] = fmaf(a.x, b.y, acc[0][1]);
                acc[0][2] = fmaf(a.x, b.z, acc[0][2]); acc[0][3] = fmaf(a.x, b.w, acc[0][3]);
                acc[1][0] = fmaf(a.y, b.x, acc[1][0]); acc[1][1] = fmaf(a.y, b.y, acc[1][1]);
                acc[1][2] = fmaf(a.y, b.z, acc[1][2]); acc[1][3] = fmaf(a.y, b.w, acc[1][3]);
                acc[2][0] = fmaf(a.z, b.x, acc[2][0]); acc[2][1] = fmaf(a.z, b.y, acc[2][1]);
                acc[2][2] = fmaf(a.z, b.z, acc[2][2]); acc[2][3] = fmaf(a.z, b.w, acc[2][3]);
                acc[3][0] = fmaf(a.w, b.x, acc[3][0]); acc[3][1] = fmaf(a.w, b.y, acc[3][1]);
                acc[3][2] = fmaf(a.w, b.z, acc[3][2]); acc[3][3] = fmaf(a.w, b.w, acc[3][3]);
            } else {
                float2 b = *(const float2*)&Bs[k][tx * 2];
                acc[0][0] = fmaf(a.x, b.x, acc[0][0]); acc[0][1] = fmaf(a.x, b.y, acc[0][1]);
                acc[1][0] = fmaf(a.y, b.x, acc[1][0]); acc[1][1] = fmaf(a.y, b.y, acc[1][1]);
                acc[2][0] = fmaf(a.z, b.x, acc[2][0]); acc[2][1] = fmaf(a.z, b.y, acc[2][1]);
                acc[3][0] = fmaf(a.w, b.x, acc[3][0]); acc[3][1] = fmaf(a.w, b.y, acc[3][1]);
            }
        }
        // advance tap/ci counters
        ci0 += BK;
        if (++cc == cpt) { cc = 0; ci0 = 0; ++tap; }
    }

    // epilogue
#pragma unroll
    for (int i = 0; i < TM; ++i) {
        const int m  = m0 + ty * TM + i;
        const int nn = m / area, rr = m % area;
        const int oy = (rr / OWt) * sy_out + py;
        const int ox = (rr % OWt) * sy_out + px;
        const size_t obase = ((size_t)(nn * OHf + oy) * OWf + ox) * Co + n0 + tx * TN;
        if (BN == 64) {
            float4 v = make_float4(acc[i][0], acc[i][1], acc[i][2], acc[i][3]);
            if (bias) {
                float4 bb = *(const float4*)(bias + n0 + tx * 4);
                v.x += bb.x; v.y += bb.y; v.z += bb.z; v.w += bb.w;
            }
            if (flags & F_RES) {
                float4 rr4 = *(const float4*)(res + obase);
                v.x += rr4.x; v.y += rr4.y; v.z += rr4.z; v.w += rr4.w;
            }
            if (flags & F_OUTRELU) {
                v.x = fmaxf(v.x, 0.f); v.y = fmaxf(v.y, 0.f);
                v.z = fmaxf(v.z, 0.f); v.w = fmaxf(v.w, 0.f);
            }
            *(float4*)(out + obase) = v;
        } else {
            float2 v = make_float2(acc[i][0], acc[i][1]);
            if (bias) {
                float2 bb = *(const float2*)(bias + n0 + tx * 2);
                v.x += bb.x; v.y += bb.y;
            }
            if (flags & F_RES) {
                float2 rr2 = *(const float2*)(res + obase);
                v.x += rr2.x; v.y += rr2.y;
            }
            if (flags & F_OUTRELU) { v.x = fmaxf(v.x, 0.f); v.y = fmaxf(v.y, 0.f); }
            *(float2*)(out + obase) = v;
        }
    }
}

// ---------------- direct kernels (enc1: Ci=3; dt2: Co=3) ----------------
__global__ void conv2d_k(const float* __restrict__ in, const float* __restrict__ w,
                         const float* __restrict__ bias, float* __restrict__ out,
                         int IH, int IW, int Ci, int OH, int OW, int Co,
                         int KH, int KW, int stride, int pad, int flags, int total)
{
    int idx = blockIdx.x * 256 + threadIdx.x;
    if (idx >= total) return;
    int co = idx % Co;
    int t  = idx / Co;
    int ox = t % OW; t /= OW;
    int oy = t % OH; t /= OH;
    int n  = t;
    float acc = bias ? bias[co] : 0.f;
    for (int ky = 0; ky < KH; ++ky) {
        int iy = oy * stride - pad + ky;
        if (iy < 0 || iy >= IH) continue;
        for (int kx = 0; kx < KW; ++kx) {
            int ix = ox * stride - pad + kx;
            if (ix < 0 || ix >= IW) continue;
            const float* ip = in + (size_t)((n * IH + iy) * IW + ix) * Ci;
            const float* wp = w + (size_t)((ky * KW + kx) * Ci) * Co + co;
            for (int ci = 0; ci < Ci; ++ci)
                acc = fmaf(ip[ci], wp[(size_t)ci * Co], acc);
        }
    }
    if (flags & F_OUTRELU) acc = fmaxf(acc, 0.f);
    out[idx] = acc;
}

__global__ void convt_k(const float* __restrict__ in, const float* __restrict__ w,
                        const float* __restrict__ bias, float* __restrict__ out,
                        int IH, int IW, int Ci, int OH, int OW, int Co,
                        int flags, int total)
{
    int idx = blockIdx.x * 256 + threadIdx.x;
    if (idx >= total) return;
    int co = idx % Co;
    int t  = idx / Co;
    int ox = t % OW; t /= OW;
    int oy = t % OH; t /= OH;
    int n  = t;
    float acc = bias ? bias[co] : 0.f;
    for (int ty = 0; ty < 2; ++ty) {
        int ky  = (oy & 1) + 2 * ty;
        int iy2 = oy + ky - 2;
        if (iy2 < 0) continue;
        int iy = iy2 >> 1;
        if (iy >= IH) continue;
        for (int tx = 0; tx < 2; ++tx) {
            int kx  = (ox & 1) + 2 * tx;
            int ix2 = ox + kx - 2;
            if (ix2 < 0) continue;
            int ix = ix2 >> 1;
            if (ix >= IW) continue;
            const float* ip = in + (size_t)((n * IH + iy) * IW + ix) * Ci;
            const float* wp = w + (size_t)((ky * 4 + kx) * Ci) * Co + co;
            for (int ci = 0; ci + 4 <= Ci; ci += 4) {
                float4 v = *(const float4*)(ip + ci);
                const float* wq = wp + (size_t)ci * Co;
                acc = fmaf(v.x, wq[0],      acc);
                acc = fmaf(v.y, wq[Co],     acc);
                acc = fmaf(v.z, wq[2 * Co], acc);
                acc = fmaf(v.w, wq[3 * Co], acc);
            }
        }
    }
    if (flags & F_OUTRELU) acc = fmaxf(acc, 0.f);
    out[idx] = acc;
}

// ---------------- VQ ----------------
__global__ void enorm_k(const float* __restrict__ emb, float* __restrict__ en) {
    int k = blockIdx.x * 256 + threadIdx.x;
    if (k >= 512) return;
    const float4* e = (const float4*)(emb + k * 128);
    float s = 0.f;
    for (int i = 0; i < 32; ++i) {
        float4 v = e[i];
        s += v.x * v.x + v.y * v.y + v.z * v.z + v.w * v.w;
    }
    en[k] = s;
}

__global__ void vq_k(const float* __restrict__ f, const float* __restrict__ emb,
                     const float* __restrict__ en, float* __restrict__ q)
{
    __shared__ float fs[32 * 132];
    __shared__ float bd[256];
    __shared__ int   bidx[256];
    __shared__ int   sel[32];
    int tid  = threadIdx.x;
    int base = blockIdx.x * (32 * 128);
    for (int i = tid; i < 32 * 128; i += 256)
        fs[(i >> 7) * 132 + (i & 127)] = f[base + i];
    __syncthreads();
    int pl = tid & 31;
    int kl = tid >> 5;
    const float* fp = fs + pl * 132;
    float best = 3.4e38f; int bk = 0;
    for (int j = 0; j < 16; ++j) {
        int k0 = kl * 4 + 32 * j;
        const float4* e0 = (const float4*)(emb + (size_t)(k0    ) * 128);
        const float4* e1 = (const float4*)(emb + (size_t)(k0 + 1) * 128);
        const float4* e2 = (const float4*)(emb + (size_t)(k0 + 2) * 128);
        const float4* e3 = (const float4*)(emb + (size_t)(k0 + 3) * 128);
        float d0 = 0.f, d1 = 0.f, d2 = 0.f, d3 = 0.f;
        for (int c = 0; c < 32; ++c) {
            float4 v = *(const float4*)(fp + c * 4);
            float4 a = e0[c]; d0 += v.x * a.x + v.y * a.y + v.z * a.z + v.w * a.w;
            float4 b = e1[c]; d1 += v.x * b.x + v.y * b.y + v.z * b.z + v.w * b.w;
            float4 g = e2[c]; d2 += v.x * g.x + v.y * g.y + v.z * g.z + v.w * g.w;
            float4 h = e3[c]; d3 += v.x * h.x + v.y * h.y + v.z * h.z + v.w * h.w;
        }
        float D;
        D = en[k0    ] - 2.f * d0; if (D < best) { best = D; bk = k0;     }
        D = en[k0 + 1] - 2.f * d1; if (D < best) { best = D; bk = k0 + 1; }
        D = en[k0 + 2] - 2.f * d2; if (D < best) { best = D; bk = k0 + 2; }
        D = en[k0 + 3] - 2.f * d3; if (D < best) { best = D; bk = k0 + 3; }
    }
    bd[tid] = best; bidx[tid] = bk;
    __syncthreads();
    if (tid < 32) {
        float bb = bd[tid]; int bb_i = bidx[tid];
        for (int l = 1; l < 8; ++l) {
            float d = bd[l * 32 + tid]; int x = bidx[l * 32 + tid];
            if (d < bb || (d == bb && x < bb_i)) { bb = d; bb_i = x; }
        }
        sel[tid] = bb_i;
    }
    __syncthreads();
    for (int i = tid; i < 32 * 128; i += 256)
        q[base + i] = emb[(size_t)sel[i >> 7] * 128 + (i & 127)];
}

// ---------------- host ----------------
static TapSet conv_taps(int KH, int KW, int pad) {
    TapSet t{};
    for (int ky = 0; ky < KH; ++ky)
        for (int kx = 0; kx < KW; ++kx) {
            int i = ky * KW + kx;
            t.dy[i] = ky - pad; t.dx[i] = kx - pad; t.wi[i] = i;
        }
    return t;
}

static TapSet convt_taps(int py, int px) {
    TapSet t{};
    for (int ty = 0; ty < 2; ++ty)
        for (int tx = 0; tx < 2; ++tx) {
            int i = ty * 2 + tx;
            t.dy[i] = py + ty - 1;
            t.dx[i] = px + tx - 1;
            t.wi[i] = (py + 2 * ty) * 4 + (px + 2 * tx);
        }
    return t;
}

extern "C" void kernel_launch(void* const* d_in, const int* in_sizes, int n_in,
                              void* d_out, int out_size, void* d_ws, size_t ws_size,
                              hipStream_t stream)
{
    const float* x       = (const float*)d_in[0];
    const float* emb     = (const float*)d_in[1];
    const float* enc_w1  = (const float*)d_in[2];
    const float* enc_b1  = (const float*)d_in[3];
    const float* enc_w2  = (const float*)d_in[4];
    const float* enc_b2  = (const float*)d_in[5];
    const float* enc_w3  = (const float*)d_in[6];
    const float* enc_b3  = (const float*)d_in[7];
    const float* erb1_w1 = (const float*)d_in[8];
    const float* erb1_w2 = (const float*)d_in[9];
    const float* erb2_w1 = (const float*)d_in[10];
    const float* erb2_w2 = (const float*)d_in[11];
    const float* dec_w   = (const float*)d_in[12];
    const float* dec_b   = (const float*)d_in[13];
    const float* drb1_w1 = (const float*)d_in[14];
    const float* drb1_w2 = (const float*)d_in[15];
    const float* drb2_w1 = (const float*)d_in[16];
    const float* drb2_w2 = (const float*)d_in[17];
    const float* dt1_w   = (const float*)d_in[18];
    const float* dt1_b   = (const float*)d_in[19];
    const float* dt2_w   = (const float*)d_in[20];
    const float* dt2_b   = (const float*)d_in[21];

    char* wsb = (char*)d_ws;
    float* A1 = (float*)wsb;                          // 16,777,216 floats
    float* B  = A1;                                   // alias (encoder features)
    float* A2 = (float*)(wsb + (size_t)16777216 * 4); // 8,388,608 floats
    float* Y0 = A2;                                   // alias (decoder acts)
    float* T  = (float*)(wsb + (size_t)25165824 * 4); // 2,097,152 floats
    float* EN = (float*)(wsb + (size_t)27262976 * 4); // 512 floats

    float* outY = (float*)d_out;
    float* outF = outY + 3145728;
    float* outQ = outF + 8388608;

    const TapSet t3  = conv_taps(3, 3, 1);
    const TapSet t4  = conv_taps(4, 4, 1);
    const TapSet t1  = conv_taps(1, 1, 0);

    enorm_k<<<2, 256, 0, stream>>>(emb, EN);

    // ---- encoder ----
    conv2d_k<<<(16777216 + 255) / 256, 256, 0, stream>>>(x, enc_w1, enc_b1, A1,
        256, 256, 3, 128, 128, 64, 4, 4, 2, 1, F_OUTRELU, 16777216);
    // enc2: 128x128x64 -> 64x64x128, 4x4 s2
    conv_gemm_k<64><<<dim3(1024, 2), 256, 0, stream>>>(A1, enc_w2, enc_b2, A2, nullptr,
        128, 128, 64, 128, 64, 64, 64, 64, 2, 1, 0, 0, t4, 16, F_OUTRELU);
    // enc3: 3x3 128->128
    conv_gemm_k<64><<<dim3(1024, 2), 256, 0, stream>>>(A2, enc_w3, enc_b3, B, nullptr,
        64, 64, 128, 128, 64, 64, 64, 64, 1, 1, 0, 0, t3, 9, 0);
    // res e1
    conv_gemm_k<32><<<dim3(1024, 1), 256, 0, stream>>>(B, erb1_w1, nullptr, T, nullptr,
        64, 64, 128, 32, 64, 64, 64, 64, 1, 1, 0, 0, t3, 9, F_INRELU);
    conv_gemm_k<64><<<dim3(1024, 2), 256, 0, stream>>>(T, erb1_w2, nullptr, B, B,
        64, 64, 32, 128, 64, 64, 64, 64, 1, 1, 0, 0, t1, 1, F_INRELU | F_RES);
    // res e2 -> outF (fused stack-end relu)
    conv_gemm_k<32><<<dim3(1024, 1), 256, 0, stream>>>(B, erb2_w1, nullptr, T, nullptr,
        64, 64, 128, 32, 64, 64, 64, 64, 1, 1, 0, 0, t3, 9, F_INRELU);
    conv_gemm_k<64><<<dim3(1024, 2), 256, 0, stream>>>(T, erb2_w2, nullptr, outF, B,
        64, 64, 32, 128, 64, 64, 64, 64, 1, 1, 0, 0, t1, 1, F_INRELU | F_RES | F_OUTRELU);

    // ---- VQ ----
    vq_k<<<2048, 256, 0, stream>>>(outF, emb, EN, outQ);

    // ---- decoder ----
    conv_gemm_k<64><<<dim3(1024, 2), 256, 0, stream>>>(outQ, dec_w, dec_b, Y0, nullptr,
        64, 64, 128, 128, 64, 64, 64, 64, 1, 1, 0, 0, t3, 9, 0);
    conv_gemm_k<32><<<dim3(1024, 1), 256, 0, stream>>>(Y0, drb1_w1, nullptr, T, nullptr,
        64, 64, 128, 32, 64, 64, 64, 64, 1, 1, 0, 0, t3, 9, F_INRELU);
    conv_gemm_k<64><<<dim3(1024, 2), 256, 0, stream>>>(T, drb1_w2, nullptr, Y0, Y0,
        64, 64, 32, 128, 64, 64, 64, 64, 1, 1, 0, 0, t1, 1, F_INRELU | F_RES);
    conv_gemm_k<32><<<dim3(1024, 1), 256, 0, stream>>>(Y0, drb2_w1, nullptr, T, nullptr,
        64, 64, 128, 32, 64, 64, 64, 64, 1, 1, 0, 0, t3, 9, F_INRELU);
    conv_gemm_k<64><<<dim3(1024, 2), 256, 0, stream>>>(T, drb2_w2, nullptr, Y0, Y0,
        64, 64, 32, 128, 64, 64, 64, 64, 1, 1, 0, 0, t1, 1, F_INRELU | F_RES | F_OUTRELU);

    // dt1 as 4 parity-class implicit GEMMs: Y0 (64x64x128) -> A1 (128x128x64)
    for (int py = 0; py < 2; ++py)
        for (int px = 0; px < 2; ++px) {
            const TapSet tt = convt_taps(py, px);
            conv_gemm_k<64><<<dim3(1024, 1), 256, 0, stream>>>(Y0, dt1_w, dt1_b, A1, nullptr,
                64, 64, 128, 64, 64, 64, 128, 128, 1, 2, py, px, tt, 4, F_OUTRELU);
        }
    // dt2 direct
    convt_k<<<(3145728 + 255) / 256, 256, 0, stream>>>(A1, dt2_w, dt2_b, outY,
        128, 128, 64, 256, 256, 3, 0, 3145728);
}

// Round 4
// 2984.232 us; speedup vs baseline: 4.3520x; 1.4338x over previous
//
#include <hip/hip_runtime.h>

enum { F_INRELU = 1, F_OUTRELU = 2, F_RES = 4 };

struct TapSet { int dy[16]; int dx[16]; int wi[16]; };

// ---------------- tiled implicit-GEMM conv (fp32) ----------------
template<int BN>
__global__ __launch_bounds__(256) void conv_gemm_k(
    const float* __restrict__ in, const float* __restrict__ w,
    const float* __restrict__ bias, float* __restrict__ out,
    const float* __restrict__ res,
    int IH, int IW, int Ci, int Co,
    int OHt, int OWt, int OHf, int OWf,
    int sy_in, int sy_out, int py, int px,
    TapSet taps, int ntaps, int flags)
{
    constexpr int BM = 64, BK = 16;
    constexpr int TM = 4, TN = BN / 16;
    __shared__ __align__(16) float As[BK][BM];
    __shared__ __align__(16) float Bs[BK][BN];

    const int tid = threadIdx.x;
    const int m0 = blockIdx.x * BM;
    const int n0 = blockIdx.y * BN;
    const int area = OHt * OWt;

    const int am = tid >> 2;
    const int aq = tid & 3;
    const int gm  = m0 + am;
    const int n_  = gm / area;
    const int r_  = gm % area;
    const int oy_ = (r_ / OWt) * sy_in;
    const int ox_ = (r_ % OWt) * sy_in;
    const int ibase_n = n_ * IH;

    const int bk  = tid >> 4;
    const int bn  = (tid & 15) * ((BN == 64) ? 4 : 2);

    const int tx = tid & 15, ty = tid >> 4;

    float acc[TM][TN];
#pragma unroll
    for (int i = 0; i < TM; ++i)
#pragma unroll
        for (int j = 0; j < TN; ++j) acc[i][j] = 0.f;

    const int cpt = Ci / BK;
    const int nchunks = ntaps * cpt;
    const bool inrelu = (flags & F_INRELU) != 0;

    int tap = 0, cc = 0, ci0 = 0;
    for (int c = 0; c < nchunks; ++c) {
        const int dy = taps.dy[tap], dx = taps.dx[tap], wi = taps.wi[tap];
        const int iy = oy_ + dy;
        const int ix = ox_ + dx;
        float4 av = make_float4(0.f, 0.f, 0.f, 0.f);
        if (iy >= 0 && iy < IH && ix >= 0 && ix < IW)
            av = *(const float4*)(in + ((size_t)(ibase_n + iy) * IW + ix) * Ci + ci0 + aq * 4);
        if (inrelu) {
            av.x = fmaxf(av.x, 0.f); av.y = fmaxf(av.y, 0.f);
            av.z = fmaxf(av.z, 0.f); av.w = fmaxf(av.w, 0.f);
        }
        const float* wp = w + (size_t)(wi * Ci + ci0 + bk) * Co + n0 + bn;
        float4 bv4; float2 bv2;
        if (BN == 64) bv4 = *(const float4*)wp; else bv2 = *(const float2*)wp;

        __syncthreads();
        As[aq * 4 + 0][am] = av.x;
        As[aq * 4 + 1][am] = av.y;
        As[aq * 4 + 2][am] = av.z;
        As[aq * 4 + 3][am] = av.w;
        if (BN == 64) *(float4*)&Bs[bk][bn] = bv4;
        else          *(float2*)&Bs[bk][bn] = bv2;
        __syncthreads();

#pragma unroll
        for (int k = 0; k < BK; ++k) {
            float4 a = *(const float4*)&As[k][ty * TM];
            if (BN == 64) {
                float4 b = *(const float4*)&Bs[k][tx * 4];
                acc[0][0] = fmaf(a.x, b.x, acc[0][0]); acc[0][1] = fmaf(a.x, b.y, acc[0][1]);
                acc[0][2] = fmaf(a.x, b.z, acc[0][2]); acc[0][3] = fmaf(a.x, b.w, acc[0][3]);
                acc[1][0] = fmaf(a.y, b.x, acc[1][0]); acc[1][1] = fmaf(a.y, b.y, acc[1][1]);
                acc[1][2] = fmaf(a.y, b.z, acc[1][2]); acc[1][3] = fmaf(a.y, b.w, acc[1][3]);
                acc[2][0] = fmaf(a.z, b.x, acc[2][0]); acc[2][1] = fmaf(a.z, b.y, acc[2][1]);
                acc[2][2] = fmaf(a.z, b.z, acc[2][2]); acc[2][3] = fmaf(a.z, b.w, acc[2][3]);
                acc[3][0] = fmaf(a.w, b.x, acc[3][0]); acc[3][1] = fmaf(a.w, b.y, acc[3][1]);
                acc[3][2] = fmaf(a.w, b.z, acc[3][2]); acc[3][3] = fmaf(a.w, b.w, acc[3][3]);
            } else {
                float2 b = *(const float2*)&Bs[k][tx * 2];
                acc[0][0] = fmaf(a.x, b.x, acc[0][0]); acc[0][1] = fmaf(a.x, b.y, acc[0][1]);
                acc[1][0] = fmaf(a.y, b.x, acc[1][0]); acc[1][1] = fmaf(a.y, b.y, acc[1][1]);
                acc[2][0] = fmaf(a.z, b.x, acc[2][0]); acc[2][1] = fmaf(a.z, b.y, acc[2][1]);
                acc[3][0] = fmaf(a.w, b.x, acc[3][0]); acc[3][1] = fmaf(a.w, b.y, acc[3][1]);
            }
        }
        ci0 += BK;
        if (++cc == cpt) { cc = 0; ci0 = 0; ++tap; }
    }

#pragma unroll
    for (int i = 0; i < TM; ++i) {
        const int m  = m0 + ty * TM + i;
        const int nn = m / area, rr = m % area;
        const int oy = (rr / OWt) * sy_out + py;
        const int ox = (rr % OWt) * sy_out + px;
        const size_t obase = ((size_t)(nn * OHf + oy) * OWf + ox) * Co + n0 + tx * TN;
        if (BN == 64) {
            float4 v = make_float4(acc[i][0], acc[i][1], acc[i][2], acc[i][3]);
            if (bias) {
                float4 bb = *(const float4*)(bias + n0 + tx * 4);
                v.x += bb.x; v.y += bb.y; v.z += bb.z; v.w += bb.w;
            }
            if (flags & F_RES) {
                float4 rr4 = *(const float4*)(res + obase);
                v.x += rr4.x; v.y += rr4.y; v.z += rr4.z; v.w += rr4.w;
            }
            if (flags & F_OUTRELU) {
                v.x = fmaxf(v.x, 0.f); v.y = fmaxf(v.y, 0.f);
                v.z = fmaxf(v.z, 0.f); v.w = fmaxf(v.w, 0.f);
            }
            *(float4*)(out + obase) = v;
        } else {
            float2 v = make_float2(acc[i][0], acc[i][1]);
            if (bias) {
                float2 bb = *(const float2*)(bias + n0 + tx * 2);
                v.x += bb.x; v.y += bb.y;
            }
            if (flags & F_RES) {
                float2 rr2 = *(const float2*)(res + obase);
                v.x += rr2.x; v.y += rr2.y;
            }
            if (flags & F_OUTRELU) { v.x = fmaxf(v.x, 0.f); v.y = fmaxf(v.y, 0.f); }
            *(float2*)(out + obase) = v;
        }
    }
}

// ---------------- direct kernels (enc1: Ci=3; dt2: Co=3) ----------------
__global__ void conv2d_k(const float* __restrict__ in, const float* __restrict__ w,
                         const float* __restrict__ bias, float* __restrict__ out,
                         int IH, int IW, int Ci, int OH, int OW, int Co,
                         int KH, int KW, int stride, int pad, int flags, int total)
{
    int idx = blockIdx.x * 256 + threadIdx.x;
    if (idx >= total) return;
    int co = idx % Co;
    int t  = idx / Co;
    int ox = t % OW; t /= OW;
    int oy = t % OH; t /= OH;
    int n  = t;
    float acc = bias ? bias[co] : 0.f;
    for (int ky = 0; ky < KH; ++ky) {
        int iy = oy * stride - pad + ky;
        if (iy < 0 || iy >= IH) continue;
        for (int kx = 0; kx < KW; ++kx) {
            int ix = ox * stride - pad + kx;
            if (ix < 0 || ix >= IW) continue;
            const float* ip = in + (size_t)((n * IH + iy) * IW + ix) * Ci;
            const float* wp = w + (size_t)((ky * KW + kx) * Ci) * Co + co;
            for (int ci = 0; ci < Ci; ++ci)
                acc = fmaf(ip[ci], wp[(size_t)ci * Co], acc);
        }
    }
    if (flags & F_OUTRELU) acc = fmaxf(acc, 0.f);
    out[idx] = acc;
}

__global__ void convt_k(const float* __restrict__ in, const float* __restrict__ w,
                        const float* __restrict__ bias, float* __restrict__ out,
                        int IH, int IW, int Ci, int OH, int OW, int Co,
                        int flags, int total)
{
    int idx = blockIdx.x * 256 + threadIdx.x;
    if (idx >= total) return;
    int co = idx % Co;
    int t  = idx / Co;
    int ox = t % OW; t /= OW;
    int oy = t % OH; t /= OH;
    int n  = t;
    float acc = bias ? bias[co] : 0.f;
    for (int ty = 0; ty < 2; ++ty) {
        int ky  = (oy & 1) + 2 * ty;
        int iy2 = oy + ky - 2;
        if (iy2 < 0) continue;
        int iy = iy2 >> 1;
        if (iy >= IH) continue;
        for (int tx = 0; tx < 2; ++tx) {
            int kx  = (ox & 1) + 2 * tx;
            int ix2 = ox + kx - 2;
            if (ix2 < 0) continue;
            int ix = ix2 >> 1;
            if (ix >= IW) continue;
            const float* ip = in + (size_t)((n * IH + iy) * IW + ix) * Ci;
            const float* wp = w + (size_t)((ky * 4 + kx) * Ci) * Co + co;
            for (int ci = 0; ci + 4 <= Ci; ci += 4) {
                float4 v = *(const float4*)(ip + ci);
                const float* wq = wp + (size_t)ci * Co;
                acc = fmaf(v.x, wq[0],      acc);
                acc = fmaf(v.y, wq[Co],     acc);
                acc = fmaf(v.z, wq[2 * Co], acc);
                acc = fmaf(v.w, wq[3 * Co], acc);
            }
        }
    }
    if (flags & F_OUTRELU) acc = fmaxf(acc, 0.f);
    out[idx] = acc;
}

// ---------------- VQ ----------------
__global__ void enorm_k(const float* __restrict__ emb, float* __restrict__ en) {
    int k = blockIdx.x * 256 + threadIdx.x;
    if (k >= 512) return;
    const float4* e = (const float4*)(emb + k * 128);
    float s = 0.f;
    for (int i = 0; i < 32; ++i) {
        float4 v = e[i];
        s += v.x * v.x + v.y * v.y + v.z * v.z + v.w * v.w;
    }
    en[k] = s;
}

// Fused SGEMM + argmin VQ. Block = 64 positions; 8 chunks of 64 codes staged
// in LDS (pre-scaled by -2); 4x4 register tile; running (best,idx) per pos;
// 16-lane shfl lexicographic reduce; fused codebook gather.
__global__ __launch_bounds__(256) void vq_fused_k(
    const float* __restrict__ f, const float* __restrict__ emb,
    const float* __restrict__ en, float* __restrict__ q)
{
    __shared__ __align__(16) float Fs[128][64];   // [k][pos]
    __shared__ __align__(16) float Es[128][64];   // [k][code], holds -2*emb
    const int tid  = threadIdx.x;
    const int pos0 = blockIdx.x * 64;
    const int ty = tid >> 4, tx = tid & 15;

    // stage Fs (coalesced float4 along k; conflict-lite scalar LDS writes)
    {
        const int p  = tid >> 2;
        const int kq = tid & 3;
        const float* fr = f + (size_t)(pos0 + p) * 128;
#pragma unroll
        for (int jj = 0; jj < 8; ++jj) {
            const int k4 = jj * 4 + kq;
            float4 v = *(const float4*)(fr + k4 * 4);
            Fs[k4 * 4 + 0][p] = v.x;
            Fs[k4 * 4 + 1][p] = v.y;
            Fs[k4 * 4 + 2][p] = v.z;
            Fs[k4 * 4 + 3][p] = v.w;
        }
    }

    float best[4] = {3.4e38f, 3.4e38f, 3.4e38f, 3.4e38f};
    int   bidx[4] = {0, 0, 0, 0};

    for (int chunk = 0; chunk < 8; ++chunk) {
        const int cbase = chunk * 64;
        __syncthreads();   // prior chunk's Es reads done
        {
            const int c  = tid >> 2;
            const int kq = tid & 3;
            const float* er = emb + (size_t)(cbase + c) * 128;
#pragma unroll
            for (int jj = 0; jj < 8; ++jj) {
                const int k4 = jj * 4 + kq;
                float4 v = *(const float4*)(er + k4 * 4);
                Es[k4 * 4 + 0][c] = -2.f * v.x;
                Es[k4 * 4 + 1][c] = -2.f * v.y;
                Es[k4 * 4 + 2][c] = -2.f * v.z;
                Es[k4 * 4 + 3][c] = -2.f * v.w;
            }
        }
        __syncthreads();

        float acc[4][4];
#pragma unroll
        for (int i = 0; i < 4; ++i)
#pragma unroll
            for (int j = 0; j < 4; ++j) acc[i][j] = 0.f;

#pragma unroll 8
        for (int k = 0; k < 128; ++k) {
            float4 a = *(const float4*)&Fs[k][ty * 4];
            float4 b = *(const float4*)&Es[k][tx * 4];
            acc[0][0] = fmaf(a.x, b.x, acc[0][0]); acc[0][1] = fmaf(a.x, b.y, acc[0][1]);
            acc[0][2] = fmaf(a.x, b.z, acc[0][2]); acc[0][3] = fmaf(a.x, b.w, acc[0][3]);
            acc[1][0] = fmaf(a.y, b.x, acc[1][0]); acc[1][1] = fmaf(a.y, b.y, acc[1][1]);
            acc[1][2] = fmaf(a.y, b.z, acc[1][2]); acc[1][3] = fmaf(a.y, b.w, acc[1][3]);
            acc[2][0] = fmaf(a.z, b.x, acc[2][0]); acc[2][1] = fmaf(a.z, b.y, acc[2][1]);
            acc[2][2] = fmaf(a.z, b.z, acc[2][2]); acc[2][3] = fmaf(a.z, b.w, acc[2][3]);
            acc[3][0] = fmaf(a.w, b.x, acc[3][0]); acc[3][1] = fmaf(a.w, b.y, acc[3][1]);
            acc[3][2] = fmaf(a.w, b.z, acc[3][2]); acc[3][3] = fmaf(a.w, b.w, acc[3][3]);
        }

        // fold into running argmin (codes ascend: strict < = first occurrence)
        const float4 e4 = *(const float4*)&en[cbase + tx * 4];
        const float enj[4] = {e4.x, e4.y, e4.z, e4.w};
#pragma unroll
        for (int j = 0; j < 4; ++j) {
            const int code = cbase + tx * 4 + j;
#pragma unroll
            for (int i = 0; i < 4; ++i) {
                float d = enj[j] + acc[i][j];
                if (d < best[i]) { best[i] = d; bidx[i] = code; }
            }
        }
    }

    __syncthreads();           // all Es reads done before reuse as sel
    int* sel = (int*)&Es[0][0];
#pragma unroll
    for (int i = 0; i < 4; ++i) {
        float d = best[i]; int ix = bidx[i];
#pragma unroll
        for (int m = 1; m < 16; m <<= 1) {
            float d2 = __shfl_xor(d, m);
            int   x2 = __shfl_xor(ix, m);
            if (d2 < d || (d2 == d && x2 < ix)) { d = d2; ix = x2; }
        }
        if (tx == 0) sel[ty * 4 + i] = ix;
    }
    __syncthreads();

    // gather: 64 pos x 128 ch = 8192 floats, 32 per thread, coalesced
#pragma unroll
    for (int jj = 0; jj < 32; ++jj) {
        int id = jj * 256 + tid;
        int p = id >> 7, k = id & 127;
        q[(size_t)(pos0 + p) * 128 + k] = emb[(size_t)sel[p] * 128 + k];
    }
}

// ---------------- host ----------------
static TapSet conv_taps(int KH, int KW, int pad) {
    TapSet t{};
    for (int ky = 0; ky < KH; ++ky)
        for (int kx = 0; kx < KW; ++kx) {
            int i = ky * KW + kx;
            t.dy[i] = ky - pad; t.dx[i] = kx - pad; t.wi[i] = i;
        }
    return t;
}

static TapSet convt_taps(int py, int px) {
    TapSet t{};
    for (int ty = 0; ty < 2; ++ty)
        for (int tx = 0; tx < 2; ++tx) {
            int i = ty * 2 + tx;
            t.dy[i] = py + ty - 1;
            t.dx[i] = px + tx - 1;
            t.wi[i] = (py + 2 * ty) * 4 + (px + 2 * tx);
        }
    return t;
}

extern "C" void kernel_launch(void* const* d_in, const int* in_sizes, int n_in,
                              void* d_out, int out_size, void* d_ws, size_t ws_size,
                              hipStream_t stream)
{
    const float* x       = (const float*)d_in[0];
    const float* emb     = (const float*)d_in[1];
    const float* enc_w1  = (const float*)d_in[2];
    const float* enc_b1  = (const float*)d_in[3];
    const float* enc_w2  = (const float*)d_in[4];
    const float* enc_b2  = (const float*)d_in[5];
    const float* enc_w3  = (const float*)d_in[6];
    const float* enc_b3  = (const float*)d_in[7];
    const float* erb1_w1 = (const float*)d_in[8];
    const float* erb1_w2 = (const float*)d_in[9];
    const float* erb2_w1 = (const float*)d_in[10];
    const float* erb2_w2 = (const float*)d_in[11];
    const float* dec_w   = (const float*)d_in[12];
    const float* dec_b   = (const float*)d_in[13];
    const float* drb1_w1 = (const float*)d_in[14];
    const float* drb1_w2 = (const float*)d_in[15];
    const float* drb2_w1 = (const float*)d_in[16];
    const float* drb2_w2 = (const float*)d_in[17];
    const float* dt1_w   = (const float*)d_in[18];
    const float* dt1_b   = (const float*)d_in[19];
    const float* dt2_w   = (const float*)d_in[20];
    const float* dt2_b   = (const float*)d_in[21];

    char* wsb = (char*)d_ws;
    float* A1 = (float*)wsb;                          // 16,777,216 floats
    float* B  = A1;                                   // alias (encoder features)
    float* A2 = (float*)(wsb + (size_t)16777216 * 4); // 8,388,608 floats
    float* Y0 = A2;                                   // alias (decoder acts)
    float* T  = (float*)(wsb + (size_t)25165824 * 4); // 2,097,152 floats
    float* EN = (float*)(wsb + (size_t)27262976 * 4); // 512 floats

    float* outY = (float*)d_out;
    float* outF = outY + 3145728;
    float* outQ = outF + 8388608;

    const TapSet t3  = conv_taps(3, 3, 1);
    const TapSet t4  = conv_taps(4, 4, 1);
    const TapSet t1  = conv_taps(1, 1, 0);

    enorm_k<<<2, 256, 0, stream>>>(emb, EN);

    // ---- encoder ----
    conv2d_k<<<(16777216 + 255) / 256, 256, 0, stream>>>(x, enc_w1, enc_b1, A1,
        256, 256, 3, 128, 128, 64, 4, 4, 2, 1, F_OUTRELU, 16777216);
    conv_gemm_k<64><<<dim3(1024, 2), 256, 0, stream>>>(A1, enc_w2, enc_b2, A2, nullptr,
        128, 128, 64, 128, 64, 64, 64, 64, 2, 1, 0, 0, t4, 16, F_OUTRELU);
    conv_gemm_k<64><<<dim3(1024, 2), 256, 0, stream>>>(A2, enc_w3, enc_b3, B, nullptr,
        64, 64, 128, 128, 64, 64, 64, 64, 1, 1, 0, 0, t3, 9, 0);
    conv_gemm_k<32><<<dim3(1024, 1), 256, 0, stream>>>(B, erb1_w1, nullptr, T, nullptr,
        64, 64, 128, 32, 64, 64, 64, 64, 1, 1, 0, 0, t3, 9, F_INRELU);
    conv_gemm_k<64><<<dim3(1024, 2), 256, 0, stream>>>(T, erb1_w2, nullptr, B, B,
        64, 64, 32, 128, 64, 64, 64, 64, 1, 1, 0, 0, t1, 1, F_INRELU | F_RES);
    conv_gemm_k<32><<<dim3(1024, 1), 256, 0, stream>>>(B, erb2_w1, nullptr, T, nullptr,
        64, 64, 128, 32, 64, 64, 64, 64, 1, 1, 0, 0, t3, 9, F_INRELU);
    conv_gemm_k<64><<<dim3(1024, 2), 256, 0, stream>>>(T, erb2_w2, nullptr, outF, B,
        64, 64, 32, 128, 64, 64, 64, 64, 1, 1, 0, 0, t1, 1, F_INRELU | F_RES | F_OUTRELU);

    // ---- VQ ----
    vq_fused_k<<<1024, 256, 0, stream>>>(outF, emb, EN, outQ);

    // ---- decoder ----
    conv_gemm_k<64><<<dim3(1024, 2), 256, 0, stream>>>(outQ, dec_w, dec_b, Y0, nullptr,
        64, 64, 128, 128, 64, 64, 64, 64, 1, 1, 0, 0, t3, 9, 0);
    conv_gemm_k<32><<<dim3(1024, 1), 256, 0, stream>>>(Y0, drb1_w1, nullptr, T, nullptr,
        64, 64, 128, 32, 64, 64, 64, 64, 1, 1, 0, 0, t3, 9, F_INRELU);
    conv_gemm_k<64><<<dim3(1024, 2), 256, 0, stream>>>(T, drb1_w2, nullptr, Y0, Y0,
        64, 64, 32, 128, 64, 64, 64, 64, 1, 1, 0, 0, t1, 1, F_INRELU | F_RES);
    conv_gemm_k<32><<<dim3(1024, 1), 256, 0, stream>>>(Y0, drb2_w1, nullptr, T, nullptr,
        64, 64, 128, 32, 64, 64, 64, 64, 1, 1, 0, 0, t3, 9, F_INRELU);
    conv_gemm_k<64><<<dim3(1024, 2), 256, 0, stream>>>(T, drb2_w2, nullptr, Y0, Y0,
        64, 64, 32, 128, 64, 64, 64, 64, 1, 1, 0, 0, t1, 1, F_INRELU | F_RES | F_OUTRELU);

    for (int py = 0; py < 2; ++py)
        for (int px = 0; px < 2; ++px) {
            const TapSet tt = convt_taps(py, px);
            conv_gemm_k<64><<<dim3(1024, 1), 256, 0, stream>>>(Y0, dt1_w, dt1_b, A1, nullptr,
                64, 64, 128, 64, 64, 64, 128, 128, 1, 2, py, px, tt, 4, F_OUTRELU);
        }
    convt_k<<<(3145728 + 255) / 256, 256, 0, stream>>>(A1, dt2_w, dt2_b, outY,
        128, 128, 64, 256, 256, 3, 0, 3145728);
}

// Round 5
// 2062.075 us; speedup vs baseline: 6.2983x; 1.4472x over previous
//
#include <hip/hip_runtime.h>

enum { F_INRELU = 1, F_OUTRELU = 2, F_RES = 4 };

struct TapSet { int dy[16]; int dx[16]; int wi[16]; };

// ---------------- tiled implicit-GEMM conv (fp32) ----------------
template<int BN>
__global__ __launch_bounds__(256) void conv_gemm_k(
    const float* __restrict__ in, const float* __restrict__ w,
    const float* __restrict__ bias, float* __restrict__ out,
    const float* __restrict__ res,
    int IH, int IW, int Ci, int Co,
    int OHt, int OWt, int OHf, int OWf,
    int sy_in, int sy_out, int py, int px,
    TapSet taps, int ntaps, int flags)
{
    constexpr int BM = 64, BK = 16;
    constexpr int TM = 4, TN = BN / 16;
    __shared__ __align__(16) float As[BK][BM];
    __shared__ __align__(16) float Bs[BK][BN];

    const int tid = threadIdx.x;
    const int m0 = blockIdx.x * BM;
    const int n0 = blockIdx.y * BN;
    const int area = OHt * OWt;

    const int am = tid >> 2;
    const int aq = tid & 3;
    const int gm  = m0 + am;
    const int n_  = gm / area;
    const int r_  = gm % area;
    const int oy_ = (r_ / OWt) * sy_in;
    const int ox_ = (r_ % OWt) * sy_in;
    const int ibase_n = n_ * IH;

    const int bk  = tid >> 4;
    const int bn  = (tid & 15) * ((BN == 64) ? 4 : 2);

    const int tx = tid & 15, ty = tid >> 4;

    float acc[TM][TN];
#pragma unroll
    for (int i = 0; i < TM; ++i)
#pragma unroll
        for (int j = 0; j < TN; ++j) acc[i][j] = 0.f;

    const int cpt = Ci / BK;
    const int nchunks = ntaps * cpt;
    const bool inrelu = (flags & F_INRELU) != 0;

    int tap = 0, cc = 0, ci0 = 0;
    for (int c = 0; c < nchunks; ++c) {
        const int dy = taps.dy[tap], dx = taps.dx[tap], wi = taps.wi[tap];
        const int iy = oy_ + dy;
        const int ix = ox_ + dx;
        float4 av = make_float4(0.f, 0.f, 0.f, 0.f);
        if (iy >= 0 && iy < IH && ix >= 0 && ix < IW)
            av = *(const float4*)(in + ((size_t)(ibase_n + iy) * IW + ix) * Ci + ci0 + aq * 4);
        if (inrelu) {
            av.x = fmaxf(av.x, 0.f); av.y = fmaxf(av.y, 0.f);
            av.z = fmaxf(av.z, 0.f); av.w = fmaxf(av.w, 0.f);
        }
        const float* wp = w + (size_t)(wi * Ci + ci0 + bk) * Co + n0 + bn;
        float4 bv4; float2 bv2;
        if (BN == 64) bv4 = *(const float4*)wp; else bv2 = *(const float2*)wp;

        __syncthreads();
        As[aq * 4 + 0][am] = av.x;
        As[aq * 4 + 1][am] = av.y;
        As[aq * 4 + 2][am] = av.z;
        As[aq * 4 + 3][am] = av.w;
        if (BN == 64) *(float4*)&Bs[bk][bn] = bv4;
        else          *(float2*)&Bs[bk][bn] = bv2;
        __syncthreads();

#pragma unroll
        for (int k = 0; k < BK; ++k) {
            float4 a = *(const float4*)&As[k][ty * TM];
            if (BN == 64) {
                float4 b = *(const float4*)&Bs[k][tx * 4];
                acc[0][0] = fmaf(a.x, b.x, acc[0][0]); acc[0][1] = fmaf(a.x, b.y, acc[0][1]);
                acc[0][2] = fmaf(a.x, b.z, acc[0][2]); acc[0][3] = fmaf(a.x, b.w, acc[0][3]);
                acc[1][0] = fmaf(a.y, b.x, acc[1][0]); acc[1][1] = fmaf(a.y, b.y, acc[1][1]);
                acc[1][2] = fmaf(a.y, b.z, acc[1][2]); acc[1][3] = fmaf(a.y, b.w, acc[1][3]);
                acc[2][0] = fmaf(a.z, b.x, acc[2][0]); acc[2][1] = fmaf(a.z, b.y, acc[2][1]);
                acc[2][2] = fmaf(a.z, b.z, acc[2][2]); acc[2][3] = fmaf(a.z, b.w, acc[2][3]);
                acc[3][0] = fmaf(a.w, b.x, acc[3][0]); acc[3][1] = fmaf(a.w, b.y, acc[3][1]);
                acc[3][2] = fmaf(a.w, b.z, acc[3][2]); acc[3][3] = fmaf(a.w, b.w, acc[3][3]);
            } else {
                float2 b = *(const float2*)&Bs[k][tx * 2];
                acc[0][0] = fmaf(a.x, b.x, acc[0][0]); acc[0][1] = fmaf(a.x, b.y, acc[0][1]);
                acc[1][0] = fmaf(a.y, b.x, acc[1][0]); acc[1][1] = fmaf(a.y, b.y, acc[1][1]);
                acc[2][0] = fmaf(a.z, b.x, acc[2][0]); acc[2][1] = fmaf(a.z, b.y, acc[2][1]);
                acc[3][0] = fmaf(a.w, b.x, acc[3][0]); acc[3][1] = fmaf(a.w, b.y, acc[3][1]);
            }
        }
        ci0 += BK;
        if (++cc == cpt) { cc = 0; ci0 = 0; ++tap; }
    }

#pragma unroll
    for (int i = 0; i < TM; ++i) {
        const int m  = m0 + ty * TM + i;
        const int nn = m / area, rr = m % area;
        const int oy = (rr / OWt) * sy_out + py;
        const int ox = (rr % OWt) * sy_out + px;
        const size_t obase = ((size_t)(nn * OHf + oy) * OWf + ox) * Co + n0 + tx * TN;
        if (BN == 64) {
            float4 v = make_float4(acc[i][0], acc[i][1], acc[i][2], acc[i][3]);
            if (bias) {
                float4 bb = *(const float4*)(bias + n0 + tx * 4);
                v.x += bb.x; v.y += bb.y; v.z += bb.z; v.w += bb.w;
            }
            if (flags & F_RES) {
                float4 rr4 = *(const float4*)(res + obase);
                v.x += rr4.x; v.y += rr4.y; v.z += rr4.z; v.w += rr4.w;
            }
            if (flags & F_OUTRELU) {
                v.x = fmaxf(v.x, 0.f); v.y = fmaxf(v.y, 0.f);
                v.z = fmaxf(v.z, 0.f); v.w = fmaxf(v.w, 0.f);
            }
            *(float4*)(out + obase) = v;
        } else {
            float2 v = make_float2(acc[i][0], acc[i][1]);
            if (bias) {
                float2 bb = *(const float2*)(bias + n0 + tx * 2);
                v.x += bb.x; v.y += bb.y;
            }
            if (flags & F_RES) {
                float2 rr2 = *(const float2*)(res + obase);
                v.x += rr2.x; v.y += rr2.y;
            }
            if (flags & F_OUTRELU) { v.x = fmaxf(v.x, 0.f); v.y = fmaxf(v.y, 0.f); }
            *(float2*)(out + obase) = v;
        }
    }
}

// ---------------- enc1: 4x4 s2 conv, 3->64, thread = (pixel, co-quad) ----------------
__global__ __launch_bounds__(256) void enc1_k(
    const float* __restrict__ x, const float* __restrict__ w,
    const float* __restrict__ bias, float* __restrict__ out)
{
    int idx = blockIdx.x * 256 + threadIdx.x;       // 16*128*128*16
    int cq  = (idx & 15) * 4;
    int pix = idx >> 4;
    int ox  = pix & 127;
    int t   = pix >> 7;
    int oy  = t & 127;
    int n   = t >> 7;
    float4 acc = *(const float4*)(bias + cq);
#pragma unroll
    for (int ky = 0; ky < 4; ++ky) {
        int iy = oy * 2 - 1 + ky;
        if (iy < 0 || iy >= 256) continue;
#pragma unroll
        for (int kx = 0; kx < 4; ++kx) {
            int ix = ox * 2 - 1 + kx;
            if (ix < 0 || ix >= 256) continue;
            const float* ip = x + (size_t)((n * 256 + iy) * 256 + ix) * 3;
            const float* wp = w + (size_t)((ky * 4 + kx) * 3) * 64 + cq;
#pragma unroll
            for (int c = 0; c < 3; ++c) {
                float xv = ip[c];
                float4 wv = *(const float4*)(wp + c * 64);
                acc.x = fmaf(xv, wv.x, acc.x);
                acc.y = fmaf(xv, wv.y, acc.y);
                acc.z = fmaf(xv, wv.z, acc.z);
                acc.w = fmaf(xv, wv.w, acc.w);
            }
        }
    }
    acc.x = fmaxf(acc.x, 0.f); acc.y = fmaxf(acc.y, 0.f);
    acc.z = fmaxf(acc.z, 0.f); acc.w = fmaxf(acc.w, 0.f);
    *(float4*)(out + (size_t)pix * 64 + cq) = acc;
}

// ---------------- dt2: convT 4x4 s2, 64->3, block = one output row ----------------
// Wave-uniform ox-parity -> wave-uniform taps & LDS weight broadcasts; input
// float4 loads lane-consecutive in ix; 3 co x 2 partial accumulators for ILP.
__global__ __launch_bounds__(256) void convt_final_k(
    const float* __restrict__ in,   // (16,128,128,64)
    const float* __restrict__ w,    // (4,4,64,3)
    const float* __restrict__ bias, // (3)
    float* __restrict__ out)        // (16,256,256,3)
{
    __shared__ __align__(16) float Wl[1536];  // [co][kyi*4+kx][ci]
    const int tid = threadIdx.x;
    const int row = blockIdx.x;               // n*256 + oy
    const int n   = row >> 8;
    const int oy  = row & 255;
    const int pY  = oy & 1;
    for (int i = tid; i < 1536; i += 256) {
        int co  = i >> 9;
        int rem = i & 511;
        int tap = rem >> 6;
        int ci  = rem & 63;
        int ky  = pY + ((tap >> 2) << 1);
        int kx  = tap & 3;
        Wl[i] = w[(size_t)((ky * 4 + kx) * 64 + ci) * 3 + co];
    }
    __syncthreads();
    const int wv = tid >> 6;
    const int p  = wv & 1;                        // ox parity (wave-uniform)
    const int m  = ((wv >> 1) << 6) + (tid & 63); // 0..127
    const int ox = 2 * m + p;
    float a0a = bias[0], a1a = bias[1], a2a = bias[2];
    float a0b = 0.f, a1b = 0.f, a2b = 0.f;
#pragma unroll
    for (int kyi = 0; kyi < 2; ++kyi) {
        int iy2 = oy + pY + 2 * kyi - 2;
        if (iy2 < 0 || iy2 >= 256) continue;
        int iy = iy2 >> 1;
#pragma unroll
        for (int t = 0; t < 2; ++t) {
            int ix = m + p + t - 1;
            if (ix < 0 || ix >= 128) continue;
            const float* ip = in + (size_t)((n * 128 + iy) * 128 + ix) * 64;
            const int kx = p + 2 * t;
            const float* w0 = Wl + ((kyi * 4 + kx) << 6);
            const float* w1 = w0 + 512;
            const float* w2 = w1 + 512;
#pragma unroll
            for (int q = 0; q < 16; ++q) {
                float4 v  = *(const float4*)(ip + q * 4);
                float4 b0 = *(const float4*)(w0 + q * 4);
                float4 b1 = *(const float4*)(w1 + q * 4);
                float4 b2 = *(const float4*)(w2 + q * 4);
                a0a = fmaf(v.x, b0.x, a0a); a0b = fmaf(v.y, b0.y, a0b);
                a0a = fmaf(v.z, b0.z, a0a); a0b = fmaf(v.w, b0.w, a0b);
                a1a = fmaf(v.x, b1.x, a1a); a1b = fmaf(v.y, b1.y, a1b);
                a1a = fmaf(v.z, b1.z, a1a); a1b = fmaf(v.w, b1.w, a1b);
                a2a = fmaf(v.x, b2.x, a2a); a2b = fmaf(v.y, b2.y, a2b);
                a2a = fmaf(v.z, b2.z, a2a); a2b = fmaf(v.w, b2.w, a2b);
            }
        }
    }
    float* op = out + (size_t)((n * 256 + oy) * 256 + ox) * 3;
    op[0] = a0a + a0b;
    op[1] = a1a + a1b;
    op[2] = a2a + a2b;
}

// ---------------- VQ ----------------
__global__ void enorm_k(const float* __restrict__ emb, float* __restrict__ en) {
    int k = blockIdx.x * 256 + threadIdx.x;
    if (k >= 512) return;
    const float4* e = (const float4*)(emb + k * 128);
    float s = 0.f;
    for (int i = 0; i < 32; ++i) {
        float4 v = e[i];
        s += v.x * v.x + v.y * v.y + v.z * v.z + v.w * v.w;
    }
    en[k] = s;
}

__global__ __launch_bounds__(256) void vq_fused_k(
    const float* __restrict__ f, const float* __restrict__ emb,
    const float* __restrict__ en, float* __restrict__ q)
{
    __shared__ __align__(16) float Fs[128][64];   // [k][pos]
    __shared__ __align__(16) float Es[128][64];   // [k][code], holds -2*emb
    const int tid  = threadIdx.x;
    const int pos0 = blockIdx.x * 64;
    const int ty = tid >> 4, tx = tid & 15;

    {
        const int p  = tid >> 2;
        const int kq = tid & 3;
        const float* fr = f + (size_t)(pos0 + p) * 128;
#pragma unroll
        for (int jj = 0; jj < 8; ++jj) {
            const int k4 = jj * 4 + kq;
            float4 v = *(const float4*)(fr + k4 * 4);
            Fs[k4 * 4 + 0][p] = v.x;
            Fs[k4 * 4 + 1][p] = v.y;
            Fs[k4 * 4 + 2][p] = v.z;
            Fs[k4 * 4 + 3][p] = v.w;
        }
    }

    float best[4] = {3.4e38f, 3.4e38f, 3.4e38f, 3.4e38f};
    int   bidx[4] = {0, 0, 0, 0};

    for (int chunk = 0; chunk < 8; ++chunk) {
        const int cbase = chunk * 64;
        __syncthreads();
        {
            const int c  = tid >> 2;
            const int kq = tid & 3;
            const float* er = emb + (size_t)(cbase + c) * 128;
#pragma unroll
            for (int jj = 0; jj < 8; ++jj) {
                const int k4 = jj * 4 + kq;
                float4 v = *(const float4*)(er + k4 * 4);
                Es[k4 * 4 + 0][c] = -2.f * v.x;
                Es[k4 * 4 + 1][c] = -2.f * v.y;
                Es[k4 * 4 + 2][c] = -2.f * v.z;
                Es[k4 * 4 + 3][c] = -2.f * v.w;
            }
        }
        __syncthreads();

        float acc[4][4];
#pragma unroll
        for (int i = 0; i < 4; ++i)
#pragma unroll
            for (int j = 0; j < 4; ++j) acc[i][j] = 0.f;

#pragma unroll 8
        for (int k = 0; k < 128; ++k) {
            float4 a = *(const float4*)&Fs[k][ty * 4];
            float4 b = *(const float4*)&Es[k][tx * 4];
            acc[0][0] = fmaf(a.x, b.x, acc[0][0]); acc[0][1] = fmaf(a.x, b.y, acc[0][1]);
            acc[0][2] = fmaf(a.x, b.z, acc[0][2]); acc[0][3] = fmaf(a.x, b.w, acc[0][3]);
            acc[1][0] = fmaf(a.y, b.x, acc[1][0]); acc[1][1] = fmaf(a.y, b.y, acc[1][1]);
            acc[1][2] = fmaf(a.y, b.z, acc[1][2]); acc[1][3] = fmaf(a.y, b.w, acc[1][3]);
            acc[2][0] = fmaf(a.z, b.x, acc[2][0]); acc[2][1] = fmaf(a.z, b.y, acc[2][1]);
            acc[2][2] = fmaf(a.z, b.z, acc[2][2]); acc[2][3] = fmaf(a.z, b.w, acc[2][3]);
            acc[3][0] = fmaf(a.w, b.x, acc[3][0]); acc[3][1] = fmaf(a.w, b.y, acc[3][1]);
            acc[3][2] = fmaf(a.w, b.z, acc[3][2]); acc[3][3] = fmaf(a.w, b.w, acc[3][3]);
        }

        const float4 e4 = *(const float4*)&en[cbase + tx * 4];
        const float enj[4] = {e4.x, e4.y, e4.z, e4.w};
#pragma unroll
        for (int j = 0; j < 4; ++j) {
            const int code = cbase + tx * 4 + j;
#pragma unroll
            for (int i = 0; i < 4; ++i) {
                float d = enj[j] + acc[i][j];
                if (d < best[i]) { best[i] = d; bidx[i] = code; }
            }
        }
    }

    __syncthreads();
    int* sel = (int*)&Es[0][0];
#pragma unroll
    for (int i = 0; i < 4; ++i) {
        float d = best[i]; int ix = bidx[i];
#pragma unroll
        for (int m = 1; m < 16; m <<= 1) {
            float d2 = __shfl_xor(d, m);
            int   x2 = __shfl_xor(ix, m);
            if (d2 < d || (d2 == d && x2 < ix)) { d = d2; ix = x2; }
        }
        if (tx == 0) sel[ty * 4 + i] = ix;
    }
    __syncthreads();

#pragma unroll
    for (int jj = 0; jj < 32; ++jj) {
        int id = jj * 256 + tid;
        int p = id >> 7, k = id & 127;
        q[(size_t)(pos0 + p) * 128 + k] = emb[(size_t)sel[p] * 128 + k];
    }
}

// ---------------- host ----------------
static TapSet conv_taps(int KH, int KW, int pad) {
    TapSet t{};
    for (int ky = 0; ky < KH; ++ky)
        for (int kx = 0; kx < KW; ++kx) {
            int i = ky * KW + kx;
            t.dy[i] = ky - pad; t.dx[i] = kx - pad; t.wi[i] = i;
        }
    return t;
}

static TapSet convt_taps(int py, int px) {
    TapSet t{};
    for (int ty = 0; ty < 2; ++ty)
        for (int tx = 0; tx < 2; ++tx) {
            int i = ty * 2 + tx;
            t.dy[i] = py + ty - 1;
            t.dx[i] = px + tx - 1;
            t.wi[i] = (py + 2 * ty) * 4 + (px + 2 * tx);
        }
    return t;
}

extern "C" void kernel_launch(void* const* d_in, const int* in_sizes, int n_in,
                              void* d_out, int out_size, void* d_ws, size_t ws_size,
                              hipStream_t stream)
{
    const float* x       = (const float*)d_in[0];
    const float* emb     = (const float*)d_in[1];
    const float* enc_w1  = (const float*)d_in[2];
    const float* enc_b1  = (const float*)d_in[3];
    const float* enc_w2  = (const float*)d_in[4];
    const float* enc_b2  = (const float*)d_in[5];
    const float* enc_w3  = (const float*)d_in[6];
    const float* enc_b3  = (const float*)d_in[7];
    const float* erb1_w1 = (const float*)d_in[8];
    const float* erb1_w2 = (const float*)d_in[9];
    const float* erb2_w1 = (const float*)d_in[10];
    const float* erb2_w2 = (const float*)d_in[11];
    const float* dec_w   = (const float*)d_in[12];
    const float* dec_b   = (const float*)d_in[13];
    const float* drb1_w1 = (const float*)d_in[14];
    const float* drb1_w2 = (const float*)d_in[15];
    const float* drb2_w1 = (const float*)d_in[16];
    const float* drb2_w2 = (const float*)d_in[17];
    const float* dt1_w   = (const float*)d_in[18];
    const float* dt1_b   = (const float*)d_in[19];
    const float* dt2_w   = (const float*)d_in[20];
    const float* dt2_b   = (const float*)d_in[21];

    char* wsb = (char*)d_ws;
    float* A1 = (float*)wsb;                          // 16,777,216 floats
    float* B  = A1;                                   // alias (encoder features)
    float* A2 = (float*)(wsb + (size_t)16777216 * 4); // 8,388,608 floats
    float* Y0 = A2;                                   // alias (decoder acts)
    float* T  = (float*)(wsb + (size_t)25165824 * 4); // 2,097,152 floats
    float* EN = (float*)(wsb + (size_t)27262976 * 4); // 512 floats

    float* outY = (float*)d_out;
    float* outF = outY + 3145728;
    float* outQ = outF + 8388608;

    const TapSet t3  = conv_taps(3, 3, 1);
    const TapSet t4  = conv_taps(4, 4, 1);
    const TapSet t1  = conv_taps(1, 1, 0);

    enorm_k<<<2, 256, 0, stream>>>(emb, EN);

    // ---- encoder ----
    enc1_k<<<16384, 256, 0, stream>>>(x, enc_w1, enc_b1, A1);
    conv_gemm_k<64><<<dim3(1024, 2), 256, 0, stream>>>(A1, enc_w2, enc_b2, A2, nullptr,
        128, 128, 64, 128, 64, 64, 64, 64, 2, 1, 0, 0, t4, 16, F_OUTRELU);
    conv_gemm_k<64><<<dim3(1024, 2), 256, 0, stream>>>(A2, enc_w3, enc_b3, B, nullptr,
        64, 64, 128, 128, 64, 64, 64, 64, 1, 1, 0, 0, t3, 9, 0);
    conv_gemm_k<32><<<dim3(1024, 1), 256, 0, stream>>>(B, erb1_w1, nullptr, T, nullptr,
        64, 64, 128, 32, 64, 64, 64, 64, 1, 1, 0, 0, t3, 9, F_INRELU);
    conv_gemm_k<64><<<dim3(1024, 2), 256, 0, stream>>>(T, erb1_w2, nullptr, B, B,
        64, 64, 32, 128, 64, 64, 64, 64, 1, 1, 0, 0, t1, 1, F_INRELU | F_RES);
    conv_gemm_k<32><<<dim3(1024, 1), 256, 0, stream>>>(B, erb2_w1, nullptr, T, nullptr,
        64, 64, 128, 32, 64, 64, 64, 64, 1, 1, 0, 0, t3, 9, F_INRELU);
    conv_gemm_k<64><<<dim3(1024, 2), 256, 0, stream>>>(T, erb2_w2, nullptr, outF, B,
        64, 64, 32, 128, 64, 64, 64, 64, 1, 1, 0, 0, t1, 1, F_INRELU | F_RES | F_OUTRELU);

    // ---- VQ ----
    vq_fused_k<<<1024, 256, 0, stream>>>(outF, emb, EN, outQ);

    // ---- decoder ----
    conv_gemm_k<64><<<dim3(1024, 2), 256, 0, stream>>>(outQ, dec_w, dec_b, Y0, nullptr,
        64, 64, 128, 128, 64, 64, 64, 64, 1, 1, 0, 0, t3, 9, 0);
    conv_gemm_k<32><<<dim3(1024, 1), 256, 0, stream>>>(Y0, drb1_w1, nullptr, T, nullptr,
        64, 64, 128, 32, 64, 64, 64, 64, 1, 1, 0, 0, t3, 9, F_INRELU);
    conv_gemm_k<64><<<dim3(1024, 2), 256, 0, stream>>>(T, drb1_w2, nullptr, Y0, Y0,
        64, 64, 32, 128, 64, 64, 64, 64, 1, 1, 0, 0, t1, 1, F_INRELU | F_RES);
    conv_gemm_k<32><<<dim3(1024, 1), 256, 0, stream>>>(Y0, drb2_w1, nullptr, T, nullptr,
        64, 64, 128, 32, 64, 64, 64, 64, 1, 1, 0, 0, t3, 9, F_INRELU);
    conv_gemm_k<64><<<dim3(1024, 2), 256, 0, stream>>>(T, drb2_w2, nullptr, Y0, Y0,
        64, 64, 32, 128, 64, 64, 64, 64, 1, 1, 0, 0, t1, 1, F_INRELU | F_RES | F_OUTRELU);

    for (int py = 0; py < 2; ++py)
        for (int px = 0; px < 2; ++px) {
            const TapSet tt = convt_taps(py, px);
            conv_gemm_k<64><<<dim3(1024, 1), 256, 0, stream>>>(Y0, dt1_w, dt1_b, A1, nullptr,
                64, 64, 128, 64, 64, 64, 128, 128, 1, 2, py, px, tt, 4, F_OUTRELU);
        }
    convt_final_k<<<4096, 256, 0, stream>>>(A1, dt2_w, dt2_b, outY);
}

// Round 6
// 1495.417 us; speedup vs baseline: 8.6849x; 1.3789x over previous
//
#include <hip/hip_runtime.h>
#include <hip/hip_bf16.h>

using bf16 = __hip_bfloat16;
using frag_ab = __attribute__((ext_vector_type(8))) short;
using frag_cd = __attribute__((ext_vector_type(4))) float;

enum { F_INRELU = 1, F_OUTRELU = 2, F_RES = 4 };

struct TapSet { int dy[16]; int dx[16]; int wi[16]; };

__device__ __forceinline__ unsigned int relu2bf(unsigned int v) {
    unsigned int m = ((v & 0x80008000u) >> 15) * 0xFFFFu;
    return v & ~m;
}

// ---------------- tiled implicit-GEMM conv (fp32, encoder) ----------------
template<int BN>
__global__ __launch_bounds__(256) void conv_gemm_k(
    const float* __restrict__ in, const float* __restrict__ w,
    const float* __restrict__ bias, float* __restrict__ out,
    const float* __restrict__ res,
    int IH, int IW, int Ci, int Co,
    int OHt, int OWt, int OHf, int OWf,
    int sy_in, int sy_out, int py, int px,
    TapSet taps, int ntaps, int flags)
{
    constexpr int BM = 64, BK = 16;
    constexpr int TM = 4, TN = BN / 16;
    __shared__ __align__(16) float As[BK][BM];
    __shared__ __align__(16) float Bs[BK][BN];

    const int tid = threadIdx.x;
    const int m0 = blockIdx.x * BM;
    const int n0 = blockIdx.y * BN;
    const int area = OHt * OWt;

    const int am = tid >> 2;
    const int aq = tid & 3;
    const int gm  = m0 + am;
    const int n_  = gm / area;
    const int r_  = gm % area;
    const int oy_ = (r_ / OWt) * sy_in;
    const int ox_ = (r_ % OWt) * sy_in;
    const int ibase_n = n_ * IH;

    const int bk  = tid >> 4;
    const int bn  = (tid & 15) * ((BN == 64) ? 4 : 2);

    const int tx = tid & 15, ty = tid >> 4;

    float acc[TM][TN];
#pragma unroll
    for (int i = 0; i < TM; ++i)
#pragma unroll
        for (int j = 0; j < TN; ++j) acc[i][j] = 0.f;

    const int cpt = Ci / BK;
    const int nchunks = ntaps * cpt;
    const bool inrelu = (flags & F_INRELU) != 0;

    int tap = 0, cc = 0, ci0 = 0;
    for (int c = 0; c < nchunks; ++c) {
        const int dy = taps.dy[tap], dx = taps.dx[tap], wi = taps.wi[tap];
        const int iy = oy_ + dy;
        const int ix = ox_ + dx;
        float4 av = make_float4(0.f, 0.f, 0.f, 0.f);
        if (iy >= 0 && iy < IH && ix >= 0 && ix < IW)
            av = *(const float4*)(in + ((size_t)(ibase_n + iy) * IW + ix) * Ci + ci0 + aq * 4);
        if (inrelu) {
            av.x = fmaxf(av.x, 0.f); av.y = fmaxf(av.y, 0.f);
            av.z = fmaxf(av.z, 0.f); av.w = fmaxf(av.w, 0.f);
        }
        const float* wp = w + (size_t)(wi * Ci + ci0 + bk) * Co + n0 + bn;
        float4 bv4; float2 bv2;
        if (BN == 64) bv4 = *(const float4*)wp; else bv2 = *(const float2*)wp;

        __syncthreads();
        As[aq * 4 + 0][am] = av.x;
        As[aq * 4 + 1][am] = av.y;
        As[aq * 4 + 2][am] = av.z;
        As[aq * 4 + 3][am] = av.w;
        if (BN == 64) *(float4*)&Bs[bk][bn] = bv4;
        else          *(float2*)&Bs[bk][bn] = bv2;
        __syncthreads();

#pragma unroll
        for (int k = 0; k < BK; ++k) {
            float4 a = *(const float4*)&As[k][ty * TM];
            if (BN == 64) {
                float4 b = *(const float4*)&Bs[k][tx * 4];
                acc[0][0] = fmaf(a.x, b.x, acc[0][0]); acc[0][1] = fmaf(a.x, b.y, acc[0][1]);
                acc[0][2] = fmaf(a.x, b.z, acc[0][2]); acc[0][3] = fmaf(a.x, b.w, acc[0][3]);
                acc[1][0] = fmaf(a.y, b.x, acc[1][0]); acc[1][1] = fmaf(a.y, b.y, acc[1][1]);
                acc[1][2] = fmaf(a.y, b.z, acc[1][2]); acc[1][3] = fmaf(a.y, b.w, acc[1][3]);
                acc[2][0] = fmaf(a.z, b.x, acc[2][0]); acc[2][1] = fmaf(a.z, b.y, acc[2][1]);
                acc[2][2] = fmaf(a.z, b.z, acc[2][2]); acc[2][3] = fmaf(a.z, b.w, acc[2][3]);
                acc[3][0] = fmaf(a.w, b.x, acc[3][0]); acc[3][1] = fmaf(a.w, b.y, acc[3][1]);
                acc[3][2] = fmaf(a.w, b.z, acc[3][2]); acc[3][3] = fmaf(a.w, b.w, acc[3][3]);
            } else {
                float2 b = *(const float2*)&Bs[k][tx * 2];
                acc[0][0] = fmaf(a.x, b.x, acc[0][0]); acc[0][1] = fmaf(a.x, b.y, acc[0][1]);
                acc[1][0] = fmaf(a.y, b.x, acc[1][0]); acc[1][1] = fmaf(a.y, b.y, acc[1][1]);
                acc[2][0] = fmaf(a.z, b.x, acc[2][0]); acc[2][1] = fmaf(a.z, b.y, acc[2][1]);
                acc[3][0] = fmaf(a.w, b.x, acc[3][0]); acc[3][1] = fmaf(a.w, b.y, acc[3][1]);
            }
        }
        ci0 += BK;
        if (++cc == cpt) { cc = 0; ci0 = 0; ++tap; }
    }

#pragma unroll
    for (int i = 0; i < TM; ++i) {
        const int m  = m0 + ty * TM + i;
        const int nn = m / area, rr = m % area;
        const int oy = (rr / OWt) * sy_out + py;
        const int ox = (rr % OWt) * sy_out + px;
        const size_t obase = ((size_t)(nn * OHf + oy) * OWf + ox) * Co + n0 + tx * TN;
        if (BN == 64) {
            float4 v = make_float4(acc[i][0], acc[i][1], acc[i][2], acc[i][3]);
            if (bias) {
                float4 bb = *(const float4*)(bias + n0 + tx * 4);
                v.x += bb.x; v.y += bb.y; v.z += bb.z; v.w += bb.w;
            }
            if (flags & F_RES) {
                float4 rr4 = *(const float4*)(res + obase);
                v.x += rr4.x; v.y += rr4.y; v.z += rr4.z; v.w += rr4.w;
            }
            if (flags & F_OUTRELU) {
                v.x = fmaxf(v.x, 0.f); v.y = fmaxf(v.y, 0.f);
                v.z = fmaxf(v.z, 0.f); v.w = fmaxf(v.w, 0.f);
            }
            *(float4*)(out + obase) = v;
        } else {
            float2 v = make_float2(acc[i][0], acc[i][1]);
            if (bias) {
                float2 bb = *(const float2*)(bias + n0 + tx * 2);
                v.x += bb.x; v.y += bb.y;
            }
            if (flags & F_RES) {
                float2 rr2 = *(const float2*)(res + obase);
                v.x += rr2.x; v.y += rr2.y;
            }
            if (flags & F_OUTRELU) { v.x = fmaxf(v.x, 0.f); v.y = fmaxf(v.y, 0.f); }
            *(float2*)(out + obase) = v;
        }
    }
}

// ---------------- weight pre-pack into MFMA B-fragment layout ----------------
// dst[((c*nblocks+nb)*4 + q)*BN*8 + nl*8 + j] = bf16(w[wi[tap]*Ci + ci][n])
//   where c=(tap,ci0) chunk, k_local=q*8+j, ci=ci0+k_local, n=nb*BN+nl
__global__ void pack_w_k(const float* __restrict__ w, bf16* __restrict__ dst,
                         int Ci, int Co, int BN, TapSet taps, int total)
{
    int idx = blockIdx.x * 256 + threadIdx.x;
    if (idx >= total) return;
    int j  = idx & 7;
    int r1 = idx >> 3;
    int nl = r1 % BN;
    int r2 = r1 / BN;
    int q  = r2 & 3;
    int cb = r2 >> 2;
    int nblocks = Co / BN;
    int c  = cb / nblocks;
    int nb = cb - c * nblocks;
    int cpt = Ci >> 5;
    int tap = c / cpt;
    int ci  = (c - tap * cpt) * 32 + q * 8 + j;
    int n   = nb * BN + nl;
    dst[idx] = __float2bfloat16(w[(size_t)(taps.wi[tap] * Ci + ci) * Co + n]);
}

// ---------------- bf16 MFMA implicit-GEMM conv (decoder) ----------------
// BM=64, BK=32, BN=64 or 32. 4 waves; 16x16x32 bf16 MFMA.
// A: bf16 NHWC activations (64x64 spatial), im2col gather, optional relu.
// B: pre-packed (pack_w_k). Epilogue: bias/res(fp32)/relu, fp32+bf16 outputs.
template<int BN>
__global__ __launch_bounds__(256) void conv_mfma_k(
    const bf16* __restrict__ a, const bf16* __restrict__ wp,
    const float* __restrict__ bias,
    float* __restrict__ out, bf16* __restrict__ out_bf,
    const float* __restrict__ res,
    int Ci, int Co, int OHf, int OWf, int sy_out, int py, int px,
    TapSet taps, int ntaps, int flags)
{
    __shared__ __align__(16) short As[64 * 32];   // [q][m][8]
    __shared__ __align__(16) short Bs[BN * 32];   // [q][n][8]

    const int tid = threadIdx.x;
    const int m0 = blockIdx.x * 64;
    const int n0 = blockIdx.y * BN;

    // A staging mapping
    const int am = tid >> 2;
    const int aq = tid & 3;
    const int gm  = m0 + am;
    const int nn_ = gm >> 12;          // area = 64*64
    const int rr_ = gm & 4095;
    const int oy_ = rr_ >> 6;
    const int ox_ = rr_ & 63;

    const int lane = tid & 63;
    const int wv4 = tid >> 6;
    constexpr int MT = (BN == 64) ? 2 : 1;
    constexpr int NT = 2;
    const int wm = (BN == 64) ? (wv4 & 1) * 32 : wv4 * 16;
    const int wn = (BN == 64) ? (wv4 >> 1) * 32 : 0;
    const int lm = lane & 15, lq = lane >> 4;
    constexpr int NLOAD = BN * 32 / 8;   // threads copying B

    frag_cd acc[MT][NT];
#pragma unroll
    for (int i = 0; i < MT; ++i)
#pragma unroll
        for (int j = 0; j < NT; ++j)
#pragma unroll
            for (int r = 0; r < 4; ++r) acc[i][j][r] = 0.f;

    const int cpt = Ci >> 5;
    const int nch = ntaps * cpt;
    const bool inrelu = (flags & F_INRELU) != 0;

    int tap = 0, cc = 0, ci0 = 0;
    for (int c = 0; c < nch; ++c) {
        const int iy = oy_ + taps.dy[tap];
        const int ix = ox_ + taps.dx[tap];
        uint4 av = make_uint4(0u, 0u, 0u, 0u);
        if (iy >= 0 && iy < 64 && ix >= 0 && ix < 64)
            av = *(const uint4*)(a + (size_t)((nn_ * 64 + iy) * 64 + ix) * Ci + ci0 + aq * 8);
        if (inrelu) {
            av.x = relu2bf(av.x); av.y = relu2bf(av.y);
            av.z = relu2bf(av.z); av.w = relu2bf(av.w);
        }
        uint4 bv;
        if (tid < NLOAD)
            bv = *(const uint4*)(wp + ((size_t)c * gridDim.y + blockIdx.y) * (BN * 32) + tid * 8);

        __syncthreads();
        *(uint4*)&As[(aq * 64 + am) * 8] = av;
        if (tid < NLOAD) *(uint4*)&Bs[tid * 8] = bv;
        __syncthreads();

        frag_ab af[MT], bfr[NT];
#pragma unroll
        for (int i = 0; i < MT; ++i)
            af[i] = *(const frag_ab*)&As[(lq * 64 + wm + i * 16 + lm) * 8];
#pragma unroll
        for (int j = 0; j < NT; ++j)
            bfr[j] = *(const frag_ab*)&Bs[(lq * BN + wn + j * 16 + lm) * 8];
#pragma unroll
        for (int i = 0; i < MT; ++i)
#pragma unroll
            for (int j = 0; j < NT; ++j)
                acc[i][j] = __builtin_amdgcn_mfma_f32_16x16x32_bf16(af[i], bfr[j], acc[i][j], 0, 0, 0);

        ci0 += 32;
        if (++cc == cpt) { cc = 0; ci0 = 0; ++tap; }
    }

    // epilogue: C/D layout n = lane&15, m = quad*4+reg
#pragma unroll
    for (int j = 0; j < NT; ++j) {
        const int n_g = n0 + wn + j * 16 + lm;
        const float bv = bias ? bias[n_g] : 0.f;
#pragma unroll
        for (int i = 0; i < MT; ++i) {
#pragma unroll
            for (int r = 0; r < 4; ++r) {
                const int m_g = m0 + wm + i * 16 + lq * 4 + r;
                const int nn2 = m_g >> 12;
                const int rr2 = m_g & 4095;
                const int oy = (rr2 >> 6) * sy_out + py;
                const int ox = (rr2 & 63) * sy_out + px;
                const size_t ob = ((size_t)(nn2 * OHf + oy) * OWf + ox) * Co + n_g;
                float v = acc[i][j][r] + bv;
                if (flags & F_RES)     v += res[ob];
                if (flags & F_OUTRELU) v = fmaxf(v, 0.f);
                if (out)    out[ob]    = v;
                if (out_bf) out_bf[ob] = __float2bfloat16(v);
            }
        }
    }
}

// ---------------- enc1: 4x4 s2 conv, 3->64 ----------------
__global__ __launch_bounds__(256) void enc1_k(
    const float* __restrict__ x, const float* __restrict__ w,
    const float* __restrict__ bias, float* __restrict__ out)
{
    int idx = blockIdx.x * 256 + threadIdx.x;
    int cq  = (idx & 15) * 4;
    int pix = idx >> 4;
    int ox  = pix & 127;
    int t   = pix >> 7;
    int oy  = t & 127;
    int n   = t >> 7;
    float4 acc = *(const float4*)(bias + cq);
#pragma unroll
    for (int ky = 0; ky < 4; ++ky) {
        int iy = oy * 2 - 1 + ky;
        if (iy < 0 || iy >= 256) continue;
#pragma unroll
        for (int kx = 0; kx < 4; ++kx) {
            int ix = ox * 2 - 1 + kx;
            if (ix < 0 || ix >= 256) continue;
            const float* ip = x + (size_t)((n * 256 + iy) * 256 + ix) * 3;
            const float* wpk = w + (size_t)((ky * 4 + kx) * 3) * 64 + cq;
#pragma unroll
            for (int c = 0; c < 3; ++c) {
                float xv = ip[c];
                float4 wv = *(const float4*)(wpk + c * 64);
                acc.x = fmaf(xv, wv.x, acc.x);
                acc.y = fmaf(xv, wv.y, acc.y);
                acc.z = fmaf(xv, wv.z, acc.z);
                acc.w = fmaf(xv, wv.w, acc.w);
            }
        }
    }
    acc.x = fmaxf(acc.x, 0.f); acc.y = fmaxf(acc.y, 0.f);
    acc.z = fmaxf(acc.z, 0.f); acc.w = fmaxf(acc.w, 0.f);
    *(float4*)(out + (size_t)pix * 64 + cq) = acc;
}

// ---------------- dt2: convT 4x4 s2, 64->3 ----------------
__global__ __launch_bounds__(256) void convt_final_k(
    const float* __restrict__ in, const float* __restrict__ w,
    const float* __restrict__ bias, float* __restrict__ out)
{
    __shared__ __align__(16) float Wl[1536];
    const int tid = threadIdx.x;
    const int row = blockIdx.x;
    const int n   = row >> 8;
    const int oy  = row & 255;
    const int pY  = oy & 1;
    for (int i = tid; i < 1536; i += 256) {
        int co  = i >> 9;
        int rem = i & 511;
        int tap = rem >> 6;
        int ci  = rem & 63;
        int ky  = pY + ((tap >> 2) << 1);
        int kx  = tap & 3;
        Wl[i] = w[(size_t)((ky * 4 + kx) * 64 + ci) * 3 + co];
    }
    __syncthreads();
    const int wv = tid >> 6;
    const int p  = wv & 1;
    const int m  = ((wv >> 1) << 6) + (tid & 63);
    const int ox = 2 * m + p;
    float a0a = bias[0], a1a = bias[1], a2a = bias[2];
    float a0b = 0.f, a1b = 0.f, a2b = 0.f;
#pragma unroll
    for (int kyi = 0; kyi < 2; ++kyi) {
        int iy2 = oy + pY + 2 * kyi - 2;
        if (iy2 < 0 || iy2 >= 256) continue;
        int iy = iy2 >> 1;
#pragma unroll
        for (int t = 0; t < 2; ++t) {
            int ix = m + p + t - 1;
            if (ix < 0 || ix >= 128) continue;
            const float* ip = in + (size_t)((n * 128 + iy) * 128 + ix) * 64;
            const int kx = p + 2 * t;
            const float* w0 = Wl + ((kyi * 4 + kx) << 6);
            const float* w1 = w0 + 512;
            const float* w2 = w1 + 512;
#pragma unroll
            for (int q = 0; q < 16; ++q) {
                float4 v  = *(const float4*)(ip + q * 4);
                float4 b0 = *(const float4*)(w0 + q * 4);
                float4 b1 = *(const float4*)(w1 + q * 4);
                float4 b2 = *(const float4*)(w2 + q * 4);
                a0a = fmaf(v.x, b0.x, a0a); a0b = fmaf(v.y, b0.y, a0b);
                a0a = fmaf(v.z, b0.z, a0a); a0b = fmaf(v.w, b0.w, a0b);
                a1a = fmaf(v.x, b1.x, a1a); a1b = fmaf(v.y, b1.y, a1b);
                a1a = fmaf(v.z, b1.z, a1a); a1b = fmaf(v.w, b1.w, a1b);
                a2a = fmaf(v.x, b2.x, a2a); a2b = fmaf(v.y, b2.y, a2b);
                a2a = fmaf(v.z, b2.z, a2a); a2b = fmaf(v.w, b2.w, a2b);
            }
        }
    }
    float* op = out + (size_t)((n * 256 + oy) * 256 + ox) * 3;
    op[0] = a0a + a0b;
    op[1] = a1a + a1b;
    op[2] = a2a + a2b;
}

// ---------------- VQ ----------------
__global__ void enorm_k(const float* __restrict__ emb, float* __restrict__ en) {
    int k = blockIdx.x * 256 + threadIdx.x;
    if (k >= 512) return;
    const float4* e = (const float4*)(emb + k * 128);
    float s = 0.f;
    for (int i = 0; i < 32; ++i) {
        float4 v = e[i];
        s += v.x * v.x + v.y * v.y + v.z * v.z + v.w * v.w;
    }
    en[k] = s;
}

__global__ __launch_bounds__(256) void vq_fused_k(
    const float* __restrict__ f, const float* __restrict__ emb,
    const float* __restrict__ en, float* __restrict__ q, bf16* __restrict__ qb)
{
    __shared__ __align__(16) float Fs[128][64];
    __shared__ __align__(16) float Es[128][64];
    const int tid  = threadIdx.x;
    const int pos0 = blockIdx.x * 64;
    const int ty = tid >> 4, tx = tid & 15;

    {
        const int p  = tid >> 2;
        const int kq = tid & 3;
        const float* fr = f + (size_t)(pos0 + p) * 128;
#pragma unroll
        for (int jj = 0; jj < 8; ++jj) {
            const int k4 = jj * 4 + kq;
            float4 v = *(const float4*)(fr + k4 * 4);
            Fs[k4 * 4 + 0][p] = v.x;
            Fs[k4 * 4 + 1][p] = v.y;
            Fs[k4 * 4 + 2][p] = v.z;
            Fs[k4 * 4 + 3][p] = v.w;
        }
    }

    float best[4] = {3.4e38f, 3.4e38f, 3.4e38f, 3.4e38f};
    int   bidx[4] = {0, 0, 0, 0};

    for (int chunk = 0; chunk < 8; ++chunk) {
        const int cbase = chunk * 64;
        __syncthreads();
        {
            const int c  = tid >> 2;
            const int kq = tid & 3;
            const float* er = emb + (size_t)(cbase + c) * 128;
#pragma unroll
            for (int jj = 0; jj < 8; ++jj) {
                const int k4 = jj * 4 + kq;
                float4 v = *(const float4*)(er + k4 * 4);
                Es[k4 * 4 + 0][c] = -2.f * v.x;
                Es[k4 * 4 + 1][c] = -2.f * v.y;
                Es[k4 * 4 + 2][c] = -2.f * v.z;
                Es[k4 * 4 + 3][c] = -2.f * v.w;
            }
        }
        __syncthreads();

        float acc[4][4];
#pragma unroll
        for (int i = 0; i < 4; ++i)
#pragma unroll
            for (int j = 0; j < 4; ++j) acc[i][j] = 0.f;

#pragma unroll 8
        for (int k = 0; k < 128; ++k) {
            float4 a = *(const float4*)&Fs[k][ty * 4];
            float4 b = *(const float4*)&Es[k][tx * 4];
            acc[0][0] = fmaf(a.x, b.x, acc[0][0]); acc[0][1] = fmaf(a.x, b.y, acc[0][1]);
            acc[0][2] = fmaf(a.x, b.z, acc[0][2]); acc[0][3] = fmaf(a.x, b.w, acc[0][3]);
            acc[1][0] = fmaf(a.y, b.x, acc[1][0]); acc[1][1] = fmaf(a.y, b.y, acc[1][1]);
            acc[1][2] = fmaf(a.y, b.z, acc[1][2]); acc[1][3] = fmaf(a.y, b.w, acc[1][3]);
            acc[2][0] = fmaf(a.z, b.x, acc[2][0]); acc[2][1] = fmaf(a.z, b.y, acc[2][1]);
            acc[2][2] = fmaf(a.z, b.z, acc[2][2]); acc[2][3] = fmaf(a.z, b.w, acc[2][3]);
            acc[3][0] = fmaf(a.w, b.x, acc[3][0]); acc[3][1] = fmaf(a.w, b.y, acc[3][1]);
            acc[3][2] = fmaf(a.w, b.z, acc[3][2]); acc[3][3] = fmaf(a.w, b.w, acc[3][3]);
        }

        const float4 e4 = *(const float4*)&en[cbase + tx * 4];
        const float enj[4] = {e4.x, e4.y, e4.z, e4.w};
#pragma unroll
        for (int j = 0; j < 4; ++j) {
            const int code = cbase + tx * 4 + j;
#pragma unroll
            for (int i = 0; i < 4; ++i) {
                float d = enj[j] + acc[i][j];
                if (d < best[i]) { best[i] = d; bidx[i] = code; }
            }
        }
    }

    __syncthreads();
    int* sel = (int*)&Es[0][0];
#pragma unroll
    for (int i = 0; i < 4; ++i) {
        float d = best[i]; int ix = bidx[i];
#pragma unroll
        for (int m = 1; m < 16; m <<= 1) {
            float d2 = __shfl_xor(d, m);
            int   x2 = __shfl_xor(ix, m);
            if (d2 < d || (d2 == d && x2 < ix)) { d = d2; ix = x2; }
        }
        if (tx == 0) sel[ty * 4 + i] = ix;
    }
    __syncthreads();

#pragma unroll
    for (int jj = 0; jj < 32; ++jj) {
        int id = jj * 256 + tid;
        int p = id >> 7, k = id & 127;
        float v = emb[(size_t)sel[p] * 128 + k];
        q[(size_t)(pos0 + p) * 128 + k]  = v;
        qb[(size_t)(pos0 + p) * 128 + k] = __float2bfloat16(v);
    }
}

// ---------------- host ----------------
static TapSet conv_taps(int KH, int KW, int pad) {
    TapSet t{};
    for (int ky = 0; ky < KH; ++ky)
        for (int kx = 0; kx < KW; ++kx) {
            int i = ky * KW + kx;
            t.dy[i] = ky - pad; t.dx[i] = kx - pad; t.wi[i] = i;
        }
    return t;
}

static TapSet convt_taps(int py, int px) {
    TapSet t{};
    for (int ty = 0; ty < 2; ++ty)
        for (int tx = 0; tx < 2; ++tx) {
            int i = ty * 2 + tx;
            t.dy[i] = py + ty - 1;
            t.dx[i] = px + tx - 1;
            t.wi[i] = (py + 2 * ty) * 4 + (px + 2 * tx);
        }
    return t;
}

extern "C" void kernel_launch(void* const* d_in, const int* in_sizes, int n_in,
                              void* d_out, int out_size, void* d_ws, size_t ws_size,
                              hipStream_t stream)
{
    const float* x       = (const float*)d_in[0];
    const float* emb     = (const float*)d_in[1];
    const float* enc_w1  = (const float*)d_in[2];
    const float* enc_b1  = (const float*)d_in[3];
    const float* enc_w2  = (const float*)d_in[4];
    const float* enc_b2  = (const float*)d_in[5];
    const float* enc_w3  = (const float*)d_in[6];
    const float* enc_b3  = (const float*)d_in[7];
    const float* erb1_w1 = (const float*)d_in[8];
    const float* erb1_w2 = (const float*)d_in[9];
    const float* erb2_w1 = (const float*)d_in[10];
    const float* erb2_w2 = (const float*)d_in[11];
    const float* dec_w   = (const float*)d_in[12];
    const float* dec_b   = (const float*)d_in[13];
    const float* drb1_w1 = (const float*)d_in[14];
    const float* drb1_w2 = (const float*)d_in[15];
    const float* drb2_w1 = (const float*)d_in[16];
    const float* drb2_w2 = (const float*)d_in[17];
    const float* dt1_w   = (const float*)d_in[18];
    const float* dt1_b   = (const float*)d_in[19];
    const float* dt2_w   = (const float*)d_in[20];
    const float* dt2_b   = (const float*)d_in[21];

    char* wsb = (char*)d_ws;
    // fp32 regions
    float* A1 = (float*)wsb;                          // 64 MB (enc1 out / dt1 out)
    float* B  = A1;                                   // enc features (32 MB alias)
    float* Y0 = A1;                                   // dec out fp32 (32 MB alias)
    float* Y1 = (float*)(wsb + (size_t)33554432);     // drb1 out fp32 (32 MB)
    float* A2 = (float*)(wsb + (size_t)67108864);     // 32 MB (enc2 out)
    float* T  = (float*)(wsb + (size_t)100663296);    // 8 MB (res hidden fp32)
    float* EN = (float*)(wsb + (size_t)109051904);    // 2 KB
    // bf16 regions (aliased into dead fp32 regions during decoder phase)
    bf16* Qb  = (bf16*)(wsb + (size_t)67108864);      // 16 MB (A2 base)
    bf16* Db  = (bf16*)(wsb + (size_t)83886080);      // 16 MB (A2+16MB)
    bf16* Y1b = Qb;                                   // reuse after dec conv
    bf16* Y2b = Db;                                   // reuse after drb1_w1
    bf16* Tb  = (bf16*)(wsb + (size_t)100663296);     // 4 MB (T base)
    // packed weights
    char* pk = wsb + (size_t)109056000;
    bf16* Pdec  = (bf16*)pk;             pk += 147456 * 2;
    bf16* Pd1w1 = (bf16*)pk;             pk += 36864 * 2;
    bf16* Pd1w2 = (bf16*)pk;             pk += 4096 * 2;
    bf16* Pd2w1 = (bf16*)pk;             pk += 36864 * 2;
    bf16* Pd2w2 = (bf16*)pk;             pk += 4096 * 2;
    bf16* Pdt1[4];
    for (int i = 0; i < 4; ++i) { Pdt1[i] = (bf16*)pk; pk += 65536 * 2; }

    float* outY = (float*)d_out;
    float* outF = outY + 3145728;
    float* outQ = outF + 8388608;

    const TapSet t3 = conv_taps(3, 3, 1);
    const TapSet t4 = conv_taps(4, 4, 1);
    const TapSet t1 = conv_taps(1, 1, 0);
    TapSet tdt[4];
    for (int p = 0; p < 4; ++p) tdt[p] = convt_taps(p >> 1, p & 1);

    enorm_k<<<2, 256, 0, stream>>>(emb, EN);

    // ---- weight packing (tiny) ----
    pack_w_k<<<(147456 + 255) / 256, 256, 0, stream>>>(dec_w, Pdec, 128, 128, 64, t3, 147456);
    pack_w_k<<<(36864 + 255) / 256, 256, 0, stream>>>(drb1_w1, Pd1w1, 128, 32, 32, t3, 36864);
    pack_w_k<<<(4096 + 255) / 256, 256, 0, stream>>>(drb1_w2, Pd1w2, 32, 128, 64, t1, 4096);
    pack_w_k<<<(36864 + 255) / 256, 256, 0, stream>>>(drb2_w1, Pd2w1, 128, 32, 32, t3, 36864);
    pack_w_k<<<(4096 + 255) / 256, 256, 0, stream>>>(drb2_w2, Pd2w2, 32, 128, 64, t1, 4096);
    for (int p = 0; p < 4; ++p)
        pack_w_k<<<(65536 + 255) / 256, 256, 0, stream>>>(dt1_w, Pdt1[p], 128, 64, 64, tdt[p], 65536);

    // ---- encoder (fp32) ----
    enc1_k<<<16384, 256, 0, stream>>>(x, enc_w1, enc_b1, A1);
    conv_gemm_k<64><<<dim3(1024, 2), 256, 0, stream>>>(A1, enc_w2, enc_b2, A2, nullptr,
        128, 128, 64, 128, 64, 64, 64, 64, 2, 1, 0, 0, t4, 16, F_OUTRELU);
    conv_gemm_k<64><<<dim3(1024, 2), 256, 0, stream>>>(A2, enc_w3, enc_b3, B, nullptr,
        64, 64, 128, 128, 64, 64, 64, 64, 1, 1, 0, 0, t3, 9, 0);
    conv_gemm_k<32><<<dim3(1024, 1), 256, 0, stream>>>(B, erb1_w1, nullptr, T, nullptr,
        64, 64, 128, 32, 64, 64, 64, 64, 1, 1, 0, 0, t3, 9, F_INRELU);
    conv_gemm_k<64><<<dim3(1024, 2), 256, 0, stream>>>(T, erb1_w2, nullptr, B, B,
        64, 64, 32, 128, 64, 64, 64, 64, 1, 1, 0, 0, t1, 1, F_INRELU | F_RES);
    conv_gemm_k<32><<<dim3(1024, 1), 256, 0, stream>>>(B, erb2_w1, nullptr, T, nullptr,
        64, 64, 128, 32, 64, 64, 64, 64, 1, 1, 0, 0, t3, 9, F_INRELU);
    conv_gemm_k<64><<<dim3(1024, 2), 256, 0, stream>>>(T, erb2_w2, nullptr, outF, B,
        64, 64, 32, 128, 64, 64, 64, 64, 1, 1, 0, 0, t1, 1, F_INRELU | F_RES | F_OUTRELU);

    // ---- VQ (fp32 distances; emits fp32 q + bf16 q) ----
    vq_fused_k<<<1024, 256, 0, stream>>>(outF, emb, EN, outQ, Qb);

    // ---- decoder (bf16 MFMA) ----
    conv_mfma_k<64><<<dim3(1024, 2), 256, 0, stream>>>(Qb, Pdec, dec_b, Y0, Db, nullptr,
        128, 128, 64, 64, 1, 0, 0, t3, 9, 0);
    conv_mfma_k<32><<<dim3(1024, 1), 256, 0, stream>>>(Db, Pd1w1, nullptr, nullptr, Tb, nullptr,
        128, 32, 64, 64, 1, 0, 0, t3, 9, F_INRELU);
    conv_mfma_k<64><<<dim3(1024, 2), 256, 0, stream>>>(Tb, Pd1w2, nullptr, Y1, Y1b, Y0,
        32, 128, 64, 64, 1, 0, 0, t1, 1, F_INRELU | F_RES);
    conv_mfma_k<32><<<dim3(1024, 1), 256, 0, stream>>>(Y1b, Pd2w1, nullptr, nullptr, Tb, nullptr,
        128, 32, 64, 64, 1, 0, 0, t3, 9, F_INRELU);
    conv_mfma_k<64><<<dim3(1024, 2), 256, 0, stream>>>(Tb, Pd2w2, nullptr, nullptr, Y2b, Y1,
        32, 128, 64, 64, 1, 0, 0, t1, 1, F_INRELU | F_RES | F_OUTRELU);
    for (int p = 0; p < 4; ++p)
        conv_mfma_k<64><<<dim3(1024, 1), 256, 0, stream>>>(Y2b, Pdt1[p], dt1_b, A1, nullptr, nullptr,
            128, 64, 128, 128, 2, p >> 1, p & 1, tdt[p], 4, F_OUTRELU);
    convt_final_k<<<4096, 256, 0, stream>>>(A1, dt2_w, dt2_b, outY);
}

// Round 7
// 1073.015 us; speedup vs baseline: 12.1037x; 1.3937x over previous
//
#include <hip/hip_runtime.h>
#include <hip/hip_bf16.h>
#include <hip/hip_fp16.h>

using bf16 = __hip_bfloat16;
using frag_ab = __attribute__((ext_vector_type(8))) short;
using f16x8  = __attribute__((ext_vector_type(8))) _Float16;
using frag_cd = __attribute__((ext_vector_type(4))) float;

enum { F_INRELU = 1, F_OUTRELU = 2, F_RES = 4 };

struct TapSet { int dy[16]; int dx[16]; int wi[16]; };

__device__ __forceinline__ unsigned int relu_pk(unsigned int v) {
    unsigned int m = ((v & 0x80008000u) >> 15) * 0xFFFFu;
    return v & ~m;
}
// zero lanes of v where h has sign bit set
__device__ __forceinline__ unsigned int mask_by(unsigned int v, unsigned int h) {
    unsigned int m = ((h & 0x80008000u) >> 15) * 0xFFFFu;
    return v & ~m;
}

// ---------------- weight pre-pack: bf16 (decoder) ----------------
__global__ void pack_w_k(const float* __restrict__ w, bf16* __restrict__ dst,
                         int Ci, int Co, int BN, TapSet taps, int total)
{
    int idx = blockIdx.x * 256 + threadIdx.x;
    if (idx >= total) return;
    int j  = idx & 7;
    int r1 = idx >> 3;
    int nl = r1 % BN;
    int r2 = r1 / BN;
    int q  = r2 & 3;
    int cb = r2 >> 2;
    int nblocks = Co / BN;
    int c  = cb / nblocks;
    int nb = cb - c * nblocks;
    int cpt = Ci >> 5;
    int tap = c / cpt;
    int ci  = (c - tap * cpt) * 32 + q * 8 + j;
    int n   = nb * BN + nl;
    dst[idx] = __float2bfloat16(w[(size_t)(taps.wi[tap] * Ci + ci) * Co + n]);
}

// ---------------- weight pre-pack: fp16 hi/lo split (encoder) ----------------
// layout: per chunk cb: [hi BN*32 halves][lo BN*32 halves]
__global__ void pack_w2_k(const float* __restrict__ w, __half* __restrict__ dst,
                          int Ci, int Co, int BN, TapSet taps, int total)
{
    int idx = blockIdx.x * 256 + threadIdx.x;
    if (idx >= total) return;
    int j  = idx & 7;
    int r1 = idx >> 3;
    int nl = r1 % BN;
    int r2 = r1 / BN;
    int q  = r2 & 3;
    int cb = r2 >> 2;
    int nblocks = Co / BN;
    int c  = cb / nblocks;
    int nb = cb - c * nblocks;
    int cpt = Ci >> 5;
    int tap = c / cpt;
    int ci  = (c - tap * cpt) * 32 + q * 8 + j;
    int n   = nb * BN + nl;
    float v = w[(size_t)(taps.wi[tap] * Ci + ci) * Co + n];
    __half h = __float2half(v);
    __half l = __float2half((v - __half2float(h)) * 2048.0f);
    size_t base = (size_t)cb * (BN * 64) + (q * BN + nl) * 8 + j;
    dst[base] = h;
    dst[base + BN * 32] = l;
}

// ---------------- fp16-split MFMA implicit-GEMM conv (encoder) ----------------
// Output tile fixed 64x64 spatial per image, sy_out=1. A = (h,l) half planes.
// acc = accA(h*h) + accB(h*l' + l'*h) * 2^-11, fp32-equivalent accuracy.
template<int BN>
__global__ __launch_bounds__(256) void conv_mfma2_k(
    const __half* __restrict__ ah, const __half* __restrict__ al,
    const __half* __restrict__ wp, const float* __restrict__ bias,
    float* __restrict__ out, __half* __restrict__ oh, __half* __restrict__ ol,
    const __half* __restrict__ rh, const __half* __restrict__ rl,
    int IH, int IW, int Ci, int Co, int sy_in,
    TapSet taps, int ntaps, int flags)
{
    __shared__ __align__(16) short Ash[64 * 32];
    __shared__ __align__(16) short Asl[64 * 32];
    __shared__ __align__(16) short Bsh[BN * 32];
    __shared__ __align__(16) short Bsl[BN * 32];

    const int tid = threadIdx.x;
    const int m0 = blockIdx.x * 64;
    const int n0 = blockIdx.y * BN;

    const int am = tid >> 2;
    const int aq = tid & 3;
    const int gm  = m0 + am;
    const int nn_ = gm >> 12;
    const int rr_ = gm & 4095;
    const int oy_ = (rr_ >> 6) * sy_in;
    const int ox_ = (rr_ & 63) * sy_in;

    const int lane = tid & 63;
    const int wv4 = tid >> 6;
    constexpr int MT = (BN == 64) ? 2 : 1;
    constexpr int NT = 2;
    const int wm = (BN == 64) ? (wv4 & 1) * 32 : wv4 * 16;
    const int wn = (BN == 64) ? (wv4 >> 1) * 32 : 0;
    const int lm = lane & 15, lq = lane >> 4;
    constexpr int NLOAD = BN * 32 / 8;

    frag_cd accA[MT][NT], accB[MT][NT];
#pragma unroll
    for (int i = 0; i < MT; ++i)
#pragma unroll
        for (int j = 0; j < NT; ++j)
#pragma unroll
            for (int r = 0; r < 4; ++r) { accA[i][j][r] = 0.f; accB[i][j][r] = 0.f; }

    const int cpt = Ci >> 5;
    const int nch = ntaps * cpt;
    const bool inrelu = (flags & F_INRELU) != 0;

    int tap = 0, cc = 0, ci0 = 0;
    for (int c = 0; c < nch; ++c) {
        const int iy = oy_ + taps.dy[tap];
        const int ix = ox_ + taps.dx[tap];
        uint4 avh = make_uint4(0u, 0u, 0u, 0u);
        uint4 avl = make_uint4(0u, 0u, 0u, 0u);
        if (iy >= 0 && iy < IH && ix >= 0 && ix < IW) {
            const size_t off = (size_t)((nn_ * IH + iy) * IW + ix) * Ci + ci0 + aq * 8;
            avh = *(const uint4*)(ah + off);
            avl = *(const uint4*)(al + off);
        }
        if (inrelu) {
            avl.x = mask_by(avl.x, avh.x); avl.y = mask_by(avl.y, avh.y);
            avl.z = mask_by(avl.z, avh.z); avl.w = mask_by(avl.w, avh.w);
            avh.x = relu_pk(avh.x); avh.y = relu_pk(avh.y);
            avh.z = relu_pk(avh.z); avh.w = relu_pk(avh.w);
        }
        uint4 bvh, bvl;
        if (tid < NLOAD) {
            const __half* wc = wp + (size_t)(c * gridDim.y + blockIdx.y) * (BN * 64);
            bvh = *(const uint4*)(wc + tid * 8);
            bvl = *(const uint4*)(wc + BN * 32 + tid * 8);
        }

        __syncthreads();
        *(uint4*)&Ash[(aq * 64 + am) * 8] = avh;
        *(uint4*)&Asl[(aq * 64 + am) * 8] = avl;
        if (tid < NLOAD) {
            *(uint4*)&Bsh[tid * 8] = bvh;
            *(uint4*)&Bsl[tid * 8] = bvl;
        }
        __syncthreads();

        f16x8 afh[MT], afl[MT], bfh[NT], bfl[NT];
#pragma unroll
        for (int i = 0; i < MT; ++i) {
            afh[i] = *(const f16x8*)&Ash[(lq * 64 + wm + i * 16 + lm) * 8];
            afl[i] = *(const f16x8*)&Asl[(lq * 64 + wm + i * 16 + lm) * 8];
        }
#pragma unroll
        for (int j = 0; j < NT; ++j) {
            bfh[j] = *(const f16x8*)&Bsh[(lq * BN + wn + j * 16 + lm) * 8];
            bfl[j] = *(const f16x8*)&Bsl[(lq * BN + wn + j * 16 + lm) * 8];
        }
#pragma unroll
        for (int i = 0; i < MT; ++i)
#pragma unroll
            for (int j = 0; j < NT; ++j) {
                accA[i][j] = __builtin_amdgcn_mfma_f32_16x16x32_f16(afh[i], bfh[j], accA[i][j], 0, 0, 0);
                accB[i][j] = __builtin_amdgcn_mfma_f32_16x16x32_f16(afh[i], bfl[j], accB[i][j], 0, 0, 0);
                accB[i][j] = __builtin_amdgcn_mfma_f32_16x16x32_f16(afl[i], bfh[j], accB[i][j], 0, 0, 0);
            }

        ci0 += 32;
        if (++cc == cpt) { cc = 0; ci0 = 0; ++tap; }
    }

    const float s = 1.0f / 2048.0f;
#pragma unroll
    for (int j = 0; j < NT; ++j) {
        const int n_g = n0 + wn + j * 16 + lm;
        const float bv = bias ? bias[n_g] : 0.f;
#pragma unroll
        for (int i = 0; i < MT; ++i) {
#pragma unroll
            for (int r = 0; r < 4; ++r) {
                const int m_g = m0 + wm + i * 16 + lq * 4 + r;
                const size_t ob = (size_t)m_g * Co + n_g;   // NHWC 64x64 tile
                float v = accA[i][j][r] + accB[i][j][r] * s + bv;
                if (flags & F_RES)
                    v += __half2float(rh[ob]) + __half2float(rl[ob]) * s;
                if (flags & F_OUTRELU) v = fmaxf(v, 0.f);
                if (out) out[ob] = v;
                if (oh) {
                    __half h = __float2half(v);
                    oh[ob] = h;
                    ol[ob] = __float2half((v - __half2float(h)) * 2048.0f);
                }
            }
        }
    }
}

// ---------------- bf16 MFMA implicit-GEMM conv (decoder) ----------------
template<int BN>
__global__ __launch_bounds__(256) void conv_mfma_k(
    const bf16* __restrict__ a, const bf16* __restrict__ wp,
    const float* __restrict__ bias,
    float* __restrict__ out, bf16* __restrict__ out_bf,
    const float* __restrict__ res,
    int Ci, int Co, int OHf, int OWf, int sy_out, int py, int px,
    TapSet taps, int ntaps, int flags)
{
    __shared__ __align__(16) short As[64 * 32];
    __shared__ __align__(16) short Bs[BN * 32];

    const int tid = threadIdx.x;
    const int m0 = blockIdx.x * 64;
    const int n0 = blockIdx.y * BN;

    const int am = tid >> 2;
    const int aq = tid & 3;
    const int gm  = m0 + am;
    const int nn_ = gm >> 12;
    const int rr_ = gm & 4095;
    const int oy_ = rr_ >> 6;
    const int ox_ = rr_ & 63;

    const int lane = tid & 63;
    const int wv4 = tid >> 6;
    constexpr int MT = (BN == 64) ? 2 : 1;
    constexpr int NT = 2;
    const int wm = (BN == 64) ? (wv4 & 1) * 32 : wv4 * 16;
    const int wn = (BN == 64) ? (wv4 >> 1) * 32 : 0;
    const int lm = lane & 15, lq = lane >> 4;
    constexpr int NLOAD = BN * 32 / 8;

    frag_cd acc[MT][NT];
#pragma unroll
    for (int i = 0; i < MT; ++i)
#pragma unroll
        for (int j = 0; j < NT; ++j)
#pragma unroll
            for (int r = 0; r < 4; ++r) acc[i][j][r] = 0.f;

    const int cpt = Ci >> 5;
    const int nch = ntaps * cpt;
    const bool inrelu = (flags & F_INRELU) != 0;

    int tap = 0, cc = 0, ci0 = 0;
    for (int c = 0; c < nch; ++c) {
        const int iy = oy_ + taps.dy[tap];
        const int ix = ox_ + taps.dx[tap];
        uint4 av = make_uint4(0u, 0u, 0u, 0u);
        if (iy >= 0 && iy < 64 && ix >= 0 && ix < 64)
            av = *(const uint4*)(a + (size_t)((nn_ * 64 + iy) * 64 + ix) * Ci + ci0 + aq * 8);
        if (inrelu) {
            av.x = relu_pk(av.x); av.y = relu_pk(av.y);
            av.z = relu_pk(av.z); av.w = relu_pk(av.w);
        }
        uint4 bv;
        if (tid < NLOAD)
            bv = *(const uint4*)(wp + ((size_t)c * gridDim.y + blockIdx.y) * (BN * 32) + tid * 8);

        __syncthreads();
        *(uint4*)&As[(aq * 64 + am) * 8] = av;
        if (tid < NLOAD) *(uint4*)&Bs[tid * 8] = bv;
        __syncthreads();

        frag_ab af[MT], bfr[NT];
#pragma unroll
        for (int i = 0; i < MT; ++i)
            af[i] = *(const frag_ab*)&As[(lq * 64 + wm + i * 16 + lm) * 8];
#pragma unroll
        for (int j = 0; j < NT; ++j)
            bfr[j] = *(const frag_ab*)&Bs[(lq * BN + wn + j * 16 + lm) * 8];
#pragma unroll
        for (int i = 0; i < MT; ++i)
#pragma unroll
            for (int j = 0; j < NT; ++j)
                acc[i][j] = __builtin_amdgcn_mfma_f32_16x16x32_bf16(af[i], bfr[j], acc[i][j], 0, 0, 0);

        ci0 += 32;
        if (++cc == cpt) { cc = 0; ci0 = 0; ++tap; }
    }

#pragma unroll
    for (int j = 0; j < NT; ++j) {
        const int n_g = n0 + wn + j * 16 + lm;
        const float bv = bias ? bias[n_g] : 0.f;
#pragma unroll
        for (int i = 0; i < MT; ++i) {
#pragma unroll
            for (int r = 0; r < 4; ++r) {
                const int m_g = m0 + wm + i * 16 + lq * 4 + r;
                const int nn2 = m_g >> 12;
                const int rr2 = m_g & 4095;
                const int oy = (rr2 >> 6) * sy_out + py;
                const int ox = (rr2 & 63) * sy_out + px;
                const size_t ob = ((size_t)(nn2 * OHf + oy) * OWf + ox) * Co + n_g;
                float v = acc[i][j][r] + bv;
                if (flags & F_RES)     v += res[ob];
                if (flags & F_OUTRELU) v = fmaxf(v, 0.f);
                if (out)    out[ob]    = v;
                if (out_bf) out_bf[ob] = __float2bfloat16(v);
            }
        }
    }
}

// ---------------- enc1: 4x4 s2 conv, 3->64, writes fp16 hi/lo planes ----------------
__global__ __launch_bounds__(256) void enc1_k(
    const float* __restrict__ x, const float* __restrict__ w,
    const float* __restrict__ bias, __half* __restrict__ oh, __half* __restrict__ ol)
{
    int idx = blockIdx.x * 256 + threadIdx.x;
    int cq  = (idx & 15) * 4;
    int pix = idx >> 4;
    int ox  = pix & 127;
    int t   = pix >> 7;
    int oy  = t & 127;
    int n   = t >> 7;
    float4 acc = *(const float4*)(bias + cq);
#pragma unroll
    for (int ky = 0; ky < 4; ++ky) {
        int iy = oy * 2 - 1 + ky;
        if (iy < 0 || iy >= 256) continue;
#pragma unroll
        for (int kx = 0; kx < 4; ++kx) {
            int ix = ox * 2 - 1 + kx;
            if (ix < 0 || ix >= 256) continue;
            const float* ip = x + (size_t)((n * 256 + iy) * 256 + ix) * 3;
            const float* wpk = w + (size_t)((ky * 4 + kx) * 3) * 64 + cq;
#pragma unroll
            for (int c = 0; c < 3; ++c) {
                float xv = ip[c];
                float4 wv = *(const float4*)(wpk + c * 64);
                acc.x = fmaf(xv, wv.x, acc.x);
                acc.y = fmaf(xv, wv.y, acc.y);
                acc.z = fmaf(xv, wv.z, acc.z);
                acc.w = fmaf(xv, wv.w, acc.w);
            }
        }
    }
    float v[4] = {fmaxf(acc.x, 0.f), fmaxf(acc.y, 0.f), fmaxf(acc.z, 0.f), fmaxf(acc.w, 0.f)};
    unsigned short hb[4], lb[4];
#pragma unroll
    for (int i = 0; i < 4; ++i) {
        __half h = __float2half(v[i]);
        hb[i] = __half_as_ushort(h);
        lb[i] = __half_as_ushort(__float2half((v[i] - __half2float(h)) * 2048.0f));
    }
    uint2 hv = make_uint2((unsigned)hb[0] | ((unsigned)hb[1] << 16),
                          (unsigned)hb[2] | ((unsigned)hb[3] << 16));
    uint2 lv = make_uint2((unsigned)lb[0] | ((unsigned)lb[1] << 16),
                          (unsigned)lb[2] | ((unsigned)lb[3] << 16));
    *(uint2*)(oh + (size_t)pix * 64 + cq) = hv;
    *(uint2*)(ol + (size_t)pix * 64 + cq) = lv;
}

// ---------------- dt2: convT 4x4 s2, 64->3 ----------------
__global__ __launch_bounds__(256) void convt_final_k(
    const float* __restrict__ in, const float* __restrict__ w,
    const float* __restrict__ bias, float* __restrict__ out)
{
    __shared__ __align__(16) float Wl[1536];
    const int tid = threadIdx.x;
    const int row = blockIdx.x;
    const int n   = row >> 8;
    const int oy  = row & 255;
    const int pY  = oy & 1;
    for (int i = tid; i < 1536; i += 256) {
        int co  = i >> 9;
        int rem = i & 511;
        int tap = rem >> 6;
        int ci  = rem & 63;
        int ky  = pY + ((tap >> 2) << 1);
        int kx  = tap & 3;
        Wl[i] = w[(size_t)((ky * 4 + kx) * 64 + ci) * 3 + co];
    }
    __syncthreads();
    const int wv = tid >> 6;
    const int p  = wv & 1;
    const int m  = ((wv >> 1) << 6) + (tid & 63);
    const int ox = 2 * m + p;
    float a0a = bias[0], a1a = bias[1], a2a = bias[2];
    float a0b = 0.f, a1b = 0.f, a2b = 0.f;
#pragma unroll
    for (int kyi = 0; kyi < 2; ++kyi) {
        int iy2 = oy + pY + 2 * kyi - 2;
        if (iy2 < 0 || iy2 >= 256) continue;
        int iy = iy2 >> 1;
#pragma unroll
        for (int t = 0; t < 2; ++t) {
            int ix = m + p + t - 1;
            if (ix < 0 || ix >= 128) continue;
            const float* ip = in + (size_t)((n * 128 + iy) * 128 + ix) * 64;
            const int kx = p + 2 * t;
            const float* w0 = Wl + ((kyi * 4 + kx) << 6);
            const float* w1 = w0 + 512;
            const float* w2 = w1 + 512;
#pragma unroll
            for (int q = 0; q < 16; ++q) {
                float4 v  = *(const float4*)(ip + q * 4);
                float4 b0 = *(const float4*)(w0 + q * 4);
                float4 b1 = *(const float4*)(w1 + q * 4);
                float4 b2 = *(const float4*)(w2 + q * 4);
                a0a = fmaf(v.x, b0.x, a0a); a0b = fmaf(v.y, b0.y, a0b);
                a0a = fmaf(v.z, b0.z, a0a); a0b = fmaf(v.w, b0.w, a0b);
                a1a = fmaf(v.x, b1.x, a1a); a1b = fmaf(v.y, b1.y, a1b);
                a1a = fmaf(v.z, b1.z, a1a); a1b = fmaf(v.w, b1.w, a1b);
                a2a = fmaf(v.x, b2.x, a2a); a2b = fmaf(v.y, b2.y, a2b);
                a2a = fmaf(v.z, b2.z, a2a); a2b = fmaf(v.w, b2.w, a2b);
            }
        }
    }
    float* op = out + (size_t)((n * 256 + oy) * 256 + ox) * 3;
    op[0] = a0a + a0b;
    op[1] = a1a + a1b;
    op[2] = a2a + a2b;
}

// ---------------- VQ ----------------
__global__ void enorm_k(const float* __restrict__ emb, float* __restrict__ en) {
    int k = blockIdx.x * 256 + threadIdx.x;
    if (k >= 512) return;
    const float4* e = (const float4*)(emb + k * 128);
    float s = 0.f;
    for (int i = 0; i < 32; ++i) {
        float4 v = e[i];
        s += v.x * v.x + v.y * v.y + v.z * v.z + v.w * v.w;
    }
    en[k] = s;
}

__global__ __launch_bounds__(256) void vq_fused_k(
    const float* __restrict__ f, const float* __restrict__ emb,
    const float* __restrict__ en, float* __restrict__ q, bf16* __restrict__ qb)
{
    __shared__ __align__(16) float Fs[128][64];
    __shared__ __align__(16) float Es[128][64];
    const int tid  = threadIdx.x;
    const int pos0 = blockIdx.x * 64;
    const int ty = tid >> 4, tx = tid & 15;

    {
        const int p  = tid >> 2;
        const int kq = tid & 3;
        const float* fr = f + (size_t)(pos0 + p) * 128;
#pragma unroll
        for (int jj = 0; jj < 8; ++jj) {
            const int k4 = jj * 4 + kq;
            float4 v = *(const float4*)(fr + k4 * 4);
            Fs[k4 * 4 + 0][p] = v.x;
            Fs[k4 * 4 + 1][p] = v.y;
            Fs[k4 * 4 + 2][p] = v.z;
            Fs[k4 * 4 + 3][p] = v.w;
        }
    }

    float best[4] = {3.4e38f, 3.4e38f, 3.4e38f, 3.4e38f};
    int   bidx[4] = {0, 0, 0, 0};

    for (int chunk = 0; chunk < 8; ++chunk) {
        const int cbase = chunk * 64;
        __syncthreads();
        {
            const int c  = tid >> 2;
            const int kq = tid & 3;
            const float* er = emb + (size_t)(cbase + c) * 128;
#pragma unroll
            for (int jj = 0; jj < 8; ++jj) {
                const int k4 = jj * 4 + kq;
                float4 v = *(const float4*)(er + k4 * 4);
                Es[k4 * 4 + 0][c] = -2.f * v.x;
                Es[k4 * 4 + 1][c] = -2.f * v.y;
                Es[k4 * 4 + 2][c] = -2.f * v.z;
                Es[k4 * 4 + 3][c] = -2.f * v.w;
            }
        }
        __syncthreads();

        float acc[4][4];
#pragma unroll
        for (int i = 0; i < 4; ++i)
#pragma unroll
            for (int j = 0; j < 4; ++j) acc[i][j] = 0.f;

#pragma unroll 8
        for (int k = 0; k < 128; ++k) {
            float4 a = *(const float4*)&Fs[k][ty * 4];
            float4 b = *(const float4*)&Es[k][tx * 4];
            acc[0][0] = fmaf(a.x, b.x, acc[0][0]); acc[0][1] = fmaf(a.x, b.y, acc[0][1]);
            acc[0][2] = fmaf(a.x, b.z, acc[0][2]); acc[0][3] = fmaf(a.x, b.w, acc[0][3]);
            acc[1][0] = fmaf(a.y, b.x, acc[1][0]); acc[1][1] = fmaf(a.y, b.y, acc[1][1]);
            acc[1][2] = fmaf(a.y, b.z, acc[1][2]); acc[1][3] = fmaf(a.y, b.w, acc[1][3]);
            acc[2][0] = fmaf(a.z, b.x, acc[2][0]); acc[2][1] = fmaf(a.z, b.y, acc[2][1]);
            acc[2][2] = fmaf(a.z, b.z, acc[2][2]); acc[2][3] = fmaf(a.z, b.w, acc[2][3]);
            acc[3][0] = fmaf(a.w, b.x, acc[3][0]); acc[3][1] = fmaf(a.w, b.y, acc[3][1]);
            acc[3][2] = fmaf(a.w, b.z, acc[3][2]); acc[3][3] = fmaf(a.w, b.w, acc[3][3]);
        }

        const float4 e4 = *(const float4*)&en[cbase + tx * 4];
        const float enj[4] = {e4.x, e4.y, e4.z, e4.w};
#pragma unroll
        for (int j = 0; j < 4; ++j) {
            const int code = cbase + tx * 4 + j;
#pragma unroll
            for (int i = 0; i < 4; ++i) {
                float d = enj[j] + acc[i][j];
                if (d < best[i]) { best[i] = d; bidx[i] = code; }
            }
        }
    }

    __syncthreads();
    int* sel = (int*)&Es[0][0];
#pragma unroll
    for (int i = 0; i < 4; ++i) {
        float d = best[i]; int ix = bidx[i];
#pragma unroll
        for (int m = 1; m < 16; m <<= 1) {
            float d2 = __shfl_xor(d, m);
            int   x2 = __shfl_xor(ix, m);
            if (d2 < d || (d2 == d && x2 < ix)) { d = d2; ix = x2; }
        }
        if (tx == 0) sel[ty * 4 + i] = ix;
    }
    __syncthreads();

#pragma unroll
    for (int jj = 0; jj < 32; ++jj) {
        int id = jj * 256 + tid;
        int p = id >> 7, k = id & 127;
        float v = emb[(size_t)sel[p] * 128 + k];
        q[(size_t)(pos0 + p) * 128 + k]  = v;
        qb[(size_t)(pos0 + p) * 128 + k] = __float2bfloat16(v);
    }
}

// ---------------- host ----------------
static TapSet conv_taps(int KH, int KW, int pad) {
    TapSet t{};
    for (int ky = 0; ky < KH; ++ky)
        for (int kx = 0; kx < KW; ++kx) {
            int i = ky * KW + kx;
            t.dy[i] = ky - pad; t.dx[i] = kx - pad; t.wi[i] = i;
        }
    return t;
}

static TapSet convt_taps(int py, int px) {
    TapSet t{};
    for (int ty = 0; ty < 2; ++ty)
        for (int tx = 0; tx < 2; ++tx) {
            int i = ty * 2 + tx;
            t.dy[i] = py + ty - 1;
            t.dx[i] = px + tx - 1;
            t.wi[i] = (py + 2 * ty) * 4 + (px + 2 * tx);
        }
    return t;
}

extern "C" void kernel_launch(void* const* d_in, const int* in_sizes, int n_in,
                              void* d_out, int out_size, void* d_ws, size_t ws_size,
                              hipStream_t stream)
{
    const float* x       = (const float*)d_in[0];
    const float* emb     = (const float*)d_in[1];
    const float* enc_w1  = (const float*)d_in[2];
    const float* enc_b1  = (const float*)d_in[3];
    const float* enc_w2  = (const float*)d_in[4];
    const float* enc_b2  = (const float*)d_in[5];
    const float* enc_w3  = (const float*)d_in[6];
    const float* enc_b3  = (const float*)d_in[7];
    const float* erb1_w1 = (const float*)d_in[8];
    const float* erb1_w2 = (const float*)d_in[9];
    const float* erb2_w1 = (const float*)d_in[10];
    const float* erb2_w2 = (const float*)d_in[11];
    const float* dec_w   = (const float*)d_in[12];
    const float* dec_b   = (const float*)d_in[13];
    const float* drb1_w1 = (const float*)d_in[14];
    const float* drb1_w2 = (const float*)d_in[15];
    const float* drb2_w1 = (const float*)d_in[16];
    const float* drb2_w2 = (const float*)d_in[17];
    const float* dt1_w   = (const float*)d_in[18];
    const float* dt1_b   = (const float*)d_in[19];
    const float* dt2_w   = (const float*)d_in[20];
    const float* dt2_b   = (const float*)d_in[21];

    char* wsb = (char*)d_ws;
    // encoder fp16 hi/lo planes (aliased through phases)
    __half* H1 = (__half*)wsb;                           // 33.55 MB
    __half* L1 = (__half*)(wsb + (size_t)33554432);      // 33.55 MB
    __half* H2 = (__half*)(wsb + (size_t)67108864);      // 16.78 MB
    __half* L2 = (__half*)(wsb + (size_t)83886080);      // 16.78 MB
    __half* H3 = (__half*)wsb;                           // reuse (enc1 planes dead)
    __half* L3 = (__half*)(wsb + (size_t)16777216);
    __half* H4 = (__half*)(wsb + (size_t)33554432);
    __half* L4 = (__half*)(wsb + (size_t)50331648);
    __half* Ht = (__half*)(wsb + (size_t)100663296);     // 4.19 MB
    __half* Lt = (__half*)(wsb + (size_t)104857600);     // 4.19 MB
    float*  EN = (float*)(wsb + (size_t)109051904);      // 2 KB
    // decoder buffers (regions dead by decoder phase)
    bf16* Qb  = (bf16*)(wsb + (size_t)67108864);
    bf16* Db  = (bf16*)(wsb + (size_t)83886080);
    bf16* Y1b = Qb;
    bf16* Y2b = Db;
    bf16* Tb  = (bf16*)(wsb + (size_t)100663296);
    float* Y0 = (float*)wsb;                             // 33.55 MB
    float* Y1 = (float*)(wsb + (size_t)33554432);        // 33.55 MB
    float* A1 = (float*)wsb;                             // 67 MB (dt1 out)
    // packed weights
    char* pk = wsb + (size_t)109056000;
    bf16* Pdec  = (bf16*)pk;  pk += 147456 * 2;
    bf16* Pd1w1 = (bf16*)pk;  pk += 36864 * 2;
    bf16* Pd1w2 = (bf16*)pk;  pk += 4096 * 2;
    bf16* Pd2w1 = (bf16*)pk;  pk += 36864 * 2;
    bf16* Pd2w2 = (bf16*)pk;  pk += 4096 * 2;
    bf16* Pdt1[4];
    for (int i = 0; i < 4; ++i) { Pdt1[i] = (bf16*)pk; pk += 65536 * 2; }
    __half* P2enc2 = (__half*)pk; pk += 131072 * 4;
    __half* P2enc3 = (__half*)pk; pk += 147456 * 4;
    __half* P2e1w1 = (__half*)pk; pk += 36864 * 4;
    __half* P2e1w2 = (__half*)pk; pk += 4096 * 4;
    __half* P2e2w1 = (__half*)pk; pk += 36864 * 4;
    __half* P2e2w2 = (__half*)pk; pk += 4096 * 4;

    float* outY = (float*)d_out;
    float* outF = outY + 3145728;
    float* outQ = outF + 8388608;

    const TapSet t3 = conv_taps(3, 3, 1);
    const TapSet t4 = conv_taps(4, 4, 1);
    const TapSet t1 = conv_taps(1, 1, 0);
    TapSet tdt[4];
    for (int p = 0; p < 4; ++p) tdt[p] = convt_taps(p >> 1, p & 1);

    enorm_k<<<2, 256, 0, stream>>>(emb, EN);

    // ---- weight packing ----
    pack_w_k<<<(147456 + 255) / 256, 256, 0, stream>>>(dec_w, Pdec, 128, 128, 64, t3, 147456);
    pack_w_k<<<(36864 + 255) / 256, 256, 0, stream>>>(drb1_w1, Pd1w1, 128, 32, 32, t3, 36864);
    pack_w_k<<<(4096 + 255) / 256, 256, 0, stream>>>(drb1_w2, Pd1w2, 32, 128, 64, t1, 4096);
    pack_w_k<<<(36864 + 255) / 256, 256, 0, stream>>>(drb2_w1, Pd2w1, 128, 32, 32, t3, 36864);
    pack_w_k<<<(4096 + 255) / 256, 256, 0, stream>>>(drb2_w2, Pd2w2, 32, 128, 64, t1, 4096);
    for (int p = 0; p < 4; ++p)
        pack_w_k<<<(65536 + 255) / 256, 256, 0, stream>>>(dt1_w, Pdt1[p], 128, 64, 64, tdt[p], 65536);
    pack_w2_k<<<(131072 + 255) / 256, 256, 0, stream>>>(enc_w2, P2enc2, 64, 128, 64, t4, 131072);
    pack_w2_k<<<(147456 + 255) / 256, 256, 0, stream>>>(enc_w3, P2enc3, 128, 128, 64, t3, 147456);
    pack_w2_k<<<(36864 + 255) / 256, 256, 0, stream>>>(erb1_w1, P2e1w1, 128, 32, 32, t3, 36864);
    pack_w2_k<<<(4096 + 255) / 256, 256, 0, stream>>>(erb1_w2, P2e1w2, 32, 128, 64, t1, 4096);
    pack_w2_k<<<(36864 + 255) / 256, 256, 0, stream>>>(erb2_w1, P2e2w1, 128, 32, 32, t3, 36864);
    pack_w2_k<<<(4096 + 255) / 256, 256, 0, stream>>>(erb2_w2, P2e2w2, 32, 128, 64, t1, 4096);

    // ---- encoder (fp16-split MFMA, fp32-equivalent) ----
    enc1_k<<<16384, 256, 0, stream>>>(x, enc_w1, enc_b1, H1, L1);
    conv_mfma2_k<64><<<dim3(1024, 2), 256, 0, stream>>>(H1, L1, P2enc2, enc_b2,
        nullptr, H2, L2, nullptr, nullptr, 128, 128, 64, 128, 2, t4, 16, F_OUTRELU);
    conv_mfma2_k<64><<<dim3(1024, 2), 256, 0, stream>>>(H2, L2, P2enc3, enc_b3,
        nullptr, H3, L3, nullptr, nullptr, 64, 64, 128, 128, 1, t3, 9, 0);
    conv_mfma2_k<32><<<dim3(1024, 1), 256, 0, stream>>>(H3, L3, P2e1w1, nullptr,
        nullptr, Ht, Lt, nullptr, nullptr, 64, 64, 128, 32, 1, t3, 9, F_INRELU);
    conv_mfma2_k<64><<<dim3(1024, 2), 256, 0, stream>>>(Ht, Lt, P2e1w2, nullptr,
        nullptr, H4, L4, H3, L3, 64, 64, 32, 128, 1, t1, 1, F_INRELU | F_RES);
    conv_mfma2_k<32><<<dim3(1024, 1), 256, 0, stream>>>(H4, L4, P2e2w1, nullptr,
        nullptr, Ht, Lt, nullptr, nullptr, 64, 64, 128, 32, 1, t3, 9, F_INRELU);
    conv_mfma2_k<64><<<dim3(1024, 2), 256, 0, stream>>>(Ht, Lt, P2e2w2, nullptr,
        outF, nullptr, nullptr, H4, L4, 64, 64, 32, 128, 1, t1, 1, F_INRELU | F_RES | F_OUTRELU);

    // ---- VQ (fp32) ----
    vq_fused_k<<<1024, 256, 0, stream>>>(outF, emb, EN, outQ, Qb);

    // ---- decoder (bf16 MFMA) ----
    conv_mfma_k<64><<<dim3(1024, 2), 256, 0, stream>>>(Qb, Pdec, dec_b, Y0, Db, nullptr,
        128, 128, 64, 64, 1, 0, 0, t3, 9, 0);
    conv_mfma_k<32><<<dim3(1024, 1), 256, 0, stream>>>(Db, Pd1w1, nullptr, nullptr, Tb, nullptr,
        128, 32, 64, 64, 1, 0, 0, t3, 9, F_INRELU);
    conv_mfma_k<64><<<dim3(1024, 2), 256, 0, stream>>>(Tb, Pd1w2, nullptr, Y1, Y1b, Y0,
        32, 128, 64, 64, 1, 0, 0, t1, 1, F_INRELU | F_RES);
    conv_mfma_k<32><<<dim3(1024, 1), 256, 0, stream>>>(Y1b, Pd2w1, nullptr, nullptr, Tb, nullptr,
        128, 32, 64, 64, 1, 0, 0, t3, 9, F_INRELU);
    conv_mfma_k<64><<<dim3(1024, 2), 256, 0, stream>>>(Tb, Pd2w2, nullptr, nullptr, Y2b, Y1,
        32, 128, 64, 64, 1, 0, 0, t1, 1, F_INRELU | F_RES | F_OUTRELU);
    for (int p = 0; p < 4; ++p)
        conv_mfma_k<64><<<dim3(1024, 1), 256, 0, stream>>>(Y2b, Pdt1[p], dt1_b, A1, nullptr, nullptr,
            128, 64, 128, 128, 2, p >> 1, p & 1, tdt[p], 4, F_OUTRELU);
    convt_final_k<<<4096, 256, 0, stream>>>(A1, dt2_w, dt2_b, outY);
}

// Round 8
// 1008.941 us; speedup vs baseline: 12.8724x; 1.0635x over previous
//
#include <hip/hip_runtime.h>
#include <hip/hip_bf16.h>
#include <hip/hip_fp16.h>

using bf16 = __hip_bfloat16;
using frag_ab = __attribute__((ext_vector_type(8))) short;
using f16x8  = __attribute__((ext_vector_type(8))) _Float16;
using frag_cd = __attribute__((ext_vector_type(4))) float;

enum { F_INRELU = 1, F_OUTRELU = 2, F_RES = 4 };

struct TapSet { int dy[16]; int dx[16]; int wi[16]; };

__device__ __forceinline__ unsigned int relu_pk(unsigned int v) {
    unsigned int m = ((v & 0x80008000u) >> 15) * 0xFFFFu;
    return v & ~m;
}
__device__ __forceinline__ unsigned int mask_by(unsigned int v, unsigned int h) {
    unsigned int m = ((h & 0x80008000u) >> 15) * 0xFFFFu;
    return v & ~m;
}

// ---------------- weight pre-pack: bf16 (decoder) ----------------
__global__ void pack_w_k(const float* __restrict__ w, bf16* __restrict__ dst,
                         int Ci, int Co, int BN, TapSet taps, int total)
{
    int idx = blockIdx.x * 256 + threadIdx.x;
    if (idx >= total) return;
    int j  = idx & 7;
    int r1 = idx >> 3;
    int nl = r1 % BN;
    int r2 = r1 / BN;
    int q  = r2 & 3;
    int cb = r2 >> 2;
    int nblocks = Co / BN;
    int c  = cb / nblocks;
    int nb = cb - c * nblocks;
    int cpt = Ci >> 5;
    int tap = c / cpt;
    int ci  = (c - tap * cpt) * 32 + q * 8 + j;
    int n   = nb * BN + nl;
    dst[idx] = __float2bfloat16(w[(size_t)(taps.wi[tap] * Ci + ci) * Co + n]);
}

// ---------------- weight pre-pack: fp16 hi/lo split (encoder) ----------------
__global__ void pack_w2_k(const float* __restrict__ w, __half* __restrict__ dst,
                          int Ci, int Co, int BN, TapSet taps, int total)
{
    int idx = blockIdx.x * 256 + threadIdx.x;
    if (idx >= total) return;
    int j  = idx & 7;
    int r1 = idx >> 3;
    int nl = r1 % BN;
    int r2 = r1 / BN;
    int q  = r2 & 3;
    int cb = r2 >> 2;
    int nblocks = Co / BN;
    int c  = cb / nblocks;
    int nb = cb - c * nblocks;
    int cpt = Ci >> 5;
    int tap = c / cpt;
    int ci  = (c - tap * cpt) * 32 + q * 8 + j;
    int n   = nb * BN + nl;
    float v = w[(size_t)(taps.wi[tap] * Ci + ci) * Co + n];
    __half h = __float2half(v);
    __half l = __float2half((v - __half2float(h)) * 2048.0f);
    size_t base = (size_t)cb * (BN * 64) + (q * BN + nl) * 8 + j;
    dst[base] = h;
    dst[base + BN * 32] = l;
}

// ---------------- emb pre-pack: fp16 hi/lo in B-fragment layout ----------------
// per (nb,ch): 2048 hi halves [(q*64+nl)*8+j] then 2048 lo halves
__global__ void pack_emb_k(const float* __restrict__ emb, __half* __restrict__ dst)
{
    int idx = blockIdx.x * 256 + threadIdx.x;   // 65536
    int k = idx & 127;
    int n = idx >> 7;
    float v = emb[idx];
    __half h = __float2half(v);
    __half l = __float2half((v - __half2float(h)) * 2048.0f);
    int nb = n >> 6, nl = n & 63;
    int ch = k >> 5, q = (k >> 3) & 3, j = k & 7;
    size_t base = (size_t)(nb * 4 + ch) * 4096 + (q * 64 + nl) * 8 + j;
    dst[base] = h;
    dst[base + 2048] = l;
}

// ---------------- fp16-split MFMA implicit-GEMM conv (encoder) ----------------
template<int BN>
__global__ __launch_bounds__(256) void conv_mfma2_k(
    const __half* __restrict__ ah, const __half* __restrict__ al,
    const __half* __restrict__ wp, const float* __restrict__ bias,
    float* __restrict__ out, __half* __restrict__ oh, __half* __restrict__ ol,
    const __half* __restrict__ rh, const __half* __restrict__ rl,
    int IH, int IW, int Ci, int Co, int sy_in,
    TapSet taps, int ntaps, int flags)
{
    __shared__ __align__(16) short Ash[64 * 32];
    __shared__ __align__(16) short Asl[64 * 32];
    __shared__ __align__(16) short Bsh[BN * 32];
    __shared__ __align__(16) short Bsl[BN * 32];

    const int tid = threadIdx.x;
    const int m0 = blockIdx.x * 64;
    const int n0 = blockIdx.y * BN;

    const int am = tid >> 2;
    const int aq = tid & 3;
    const int gm  = m0 + am;
    const int nn_ = gm >> 12;
    const int rr_ = gm & 4095;
    const int oy_ = (rr_ >> 6) * sy_in;
    const int ox_ = (rr_ & 63) * sy_in;

    const int lane = tid & 63;
    const int wv4 = tid >> 6;
    constexpr int MT = (BN == 64) ? 2 : 1;
    constexpr int NT = 2;
    const int wm = (BN == 64) ? (wv4 & 1) * 32 : wv4 * 16;
    const int wn = (BN == 64) ? (wv4 >> 1) * 32 : 0;
    const int lm = lane & 15, lq = lane >> 4;
    constexpr int NLOAD = BN * 32 / 8;

    frag_cd accA[MT][NT], accB[MT][NT];
#pragma unroll
    for (int i = 0; i < MT; ++i)
#pragma unroll
        for (int j = 0; j < NT; ++j)
#pragma unroll
            for (int r = 0; r < 4; ++r) { accA[i][j][r] = 0.f; accB[i][j][r] = 0.f; }

    const int cpt = Ci >> 5;
    const int nch = ntaps * cpt;
    const bool inrelu = (flags & F_INRELU) != 0;

    int tap = 0, cc = 0, ci0 = 0;
    for (int c = 0; c < nch; ++c) {
        const int iy = oy_ + taps.dy[tap];
        const int ix = ox_ + taps.dx[tap];
        uint4 avh = make_uint4(0u, 0u, 0u, 0u);
        uint4 avl = make_uint4(0u, 0u, 0u, 0u);
        if (iy >= 0 && iy < IH && ix >= 0 && ix < IW) {
            const size_t off = (size_t)((nn_ * IH + iy) * IW + ix) * Ci + ci0 + aq * 8;
            avh = *(const uint4*)(ah + off);
            avl = *(const uint4*)(al + off);
        }
        if (inrelu) {
            avl.x = mask_by(avl.x, avh.x); avl.y = mask_by(avl.y, avh.y);
            avl.z = mask_by(avl.z, avh.z); avl.w = mask_by(avl.w, avh.w);
            avh.x = relu_pk(avh.x); avh.y = relu_pk(avh.y);
            avh.z = relu_pk(avh.z); avh.w = relu_pk(avh.w);
        }
        uint4 bvh, bvl;
        if (tid < NLOAD) {
            const __half* wc = wp + (size_t)(c * gridDim.y + blockIdx.y) * (BN * 64);
            bvh = *(const uint4*)(wc + tid * 8);
            bvl = *(const uint4*)(wc + BN * 32 + tid * 8);
        }

        __syncthreads();
        *(uint4*)&Ash[(aq * 64 + am) * 8] = avh;
        *(uint4*)&Asl[(aq * 64 + am) * 8] = avl;
        if (tid < NLOAD) {
            *(uint4*)&Bsh[tid * 8] = bvh;
            *(uint4*)&Bsl[tid * 8] = bvl;
        }
        __syncthreads();

        f16x8 afh[MT], afl[MT], bfh[NT], bfl[NT];
#pragma unroll
        for (int i = 0; i < MT; ++i) {
            afh[i] = *(const f16x8*)&Ash[(lq * 64 + wm + i * 16 + lm) * 8];
            afl[i] = *(const f16x8*)&Asl[(lq * 64 + wm + i * 16 + lm) * 8];
        }
#pragma unroll
        for (int j = 0; j < NT; ++j) {
            bfh[j] = *(const f16x8*)&Bsh[(lq * BN + wn + j * 16 + lm) * 8];
            bfl[j] = *(const f16x8*)&Bsl[(lq * BN + wn + j * 16 + lm) * 8];
        }
#pragma unroll
        for (int i = 0; i < MT; ++i)
#pragma unroll
            for (int j = 0; j < NT; ++j) {
                accA[i][j] = __builtin_amdgcn_mfma_f32_16x16x32_f16(afh[i], bfh[j], accA[i][j], 0, 0, 0);
                accB[i][j] = __builtin_amdgcn_mfma_f32_16x16x32_f16(afh[i], bfl[j], accB[i][j], 0, 0, 0);
                accB[i][j] = __builtin_amdgcn_mfma_f32_16x16x32_f16(afl[i], bfh[j], accB[i][j], 0, 0, 0);
            }

        ci0 += 32;
        if (++cc == cpt) { cc = 0; ci0 = 0; ++tap; }
    }

    const float s = 1.0f / 2048.0f;
#pragma unroll
    for (int j = 0; j < NT; ++j) {
        const int n_g = n0 + wn + j * 16 + lm;
        const float bv = bias ? bias[n_g] : 0.f;
#pragma unroll
        for (int i = 0; i < MT; ++i) {
#pragma unroll
            for (int r = 0; r < 4; ++r) {
                const int m_g = m0 + wm + i * 16 + lq * 4 + r;
                const size_t ob = (size_t)m_g * Co + n_g;
                float v = accA[i][j][r] + accB[i][j][r] * s + bv;
                if (flags & F_RES)
                    v += __half2float(rh[ob]) + __half2float(rl[ob]) * s;
                if (flags & F_OUTRELU) v = fmaxf(v, 0.f);
                if (out) out[ob] = v;
                if (oh) {
                    __half h = __float2half(v);
                    oh[ob] = h;
                    ol[ob] = __float2half((v - __half2float(h)) * 2048.0f);
                }
            }
        }
    }
}

// ---------------- bf16 MFMA implicit-GEMM conv (decoder) ----------------
template<int BN>
__global__ __launch_bounds__(256) void conv_mfma_k(
    const bf16* __restrict__ a, const bf16* __restrict__ wp,
    const float* __restrict__ bias,
    float* __restrict__ out, bf16* __restrict__ out_bf,
    const float* __restrict__ res,
    int Ci, int Co, int OHf, int OWf, int sy_out, int py, int px,
    TapSet taps, int ntaps, int flags)
{
    __shared__ __align__(16) short As[64 * 32];
    __shared__ __align__(16) short Bs[BN * 32];

    const int tid = threadIdx.x;
    const int m0 = blockIdx.x * 64;
    const int n0 = blockIdx.y * BN;

    const int am = tid >> 2;
    const int aq = tid & 3;
    const int gm  = m0 + am;
    const int nn_ = gm >> 12;
    const int rr_ = gm & 4095;
    const int oy_ = rr_ >> 6;
    const int ox_ = rr_ & 63;

    const int lane = tid & 63;
    const int wv4 = tid >> 6;
    constexpr int MT = (BN == 64) ? 2 : 1;
    constexpr int NT = 2;
    const int wm = (BN == 64) ? (wv4 & 1) * 32 : wv4 * 16;
    const int wn = (BN == 64) ? (wv4 >> 1) * 32 : 0;
    const int lm = lane & 15, lq = lane >> 4;
    constexpr int NLOAD = BN * 32 / 8;

    frag_cd acc[MT][NT];
#pragma unroll
    for (int i = 0; i < MT; ++i)
#pragma unroll
        for (int j = 0; j < NT; ++j)
#pragma unroll
            for (int r = 0; r < 4; ++r) acc[i][j][r] = 0.f;

    const int cpt = Ci >> 5;
    const int nch = ntaps * cpt;
    const bool inrelu = (flags & F_INRELU) != 0;

    int tap = 0, cc = 0, ci0 = 0;
    for (int c = 0; c < nch; ++c) {
        const int iy = oy_ + taps.dy[tap];
        const int ix = ox_ + taps.dx[tap];
        uint4 av = make_uint4(0u, 0u, 0u, 0u);
        if (iy >= 0 && iy < 64 && ix >= 0 && ix < 64)
            av = *(const uint4*)(a + (size_t)((nn_ * 64 + iy) * 64 + ix) * Ci + ci0 + aq * 8);
        if (inrelu) {
            av.x = relu_pk(av.x); av.y = relu_pk(av.y);
            av.z = relu_pk(av.z); av.w = relu_pk(av.w);
        }
        uint4 bv;
        if (tid < NLOAD)
            bv = *(const uint4*)(wp + ((size_t)c * gridDim.y + blockIdx.y) * (BN * 32) + tid * 8);

        __syncthreads();
        *(uint4*)&As[(aq * 64 + am) * 8] = av;
        if (tid < NLOAD) *(uint4*)&Bs[tid * 8] = bv;
        __syncthreads();

        frag_ab af[MT], bfr[NT];
#pragma unroll
        for (int i = 0; i < MT; ++i)
            af[i] = *(const frag_ab*)&As[(lq * 64 + wm + i * 16 + lm) * 8];
#pragma unroll
        for (int j = 0; j < NT; ++j)
            bfr[j] = *(const frag_ab*)&Bs[(lq * BN + wn + j * 16 + lm) * 8];
#pragma unroll
        for (int i = 0; i < MT; ++i)
#pragma unroll
            for (int j = 0; j < NT; ++j)
                acc[i][j] = __builtin_amdgcn_mfma_f32_16x16x32_bf16(af[i], bfr[j], acc[i][j], 0, 0, 0);

        ci0 += 32;
        if (++cc == cpt) { cc = 0; ci0 = 0; ++tap; }
    }

#pragma unroll
    for (int j = 0; j < NT; ++j) {
        const int n_g = n0 + wn + j * 16 + lm;
        const float bv = bias ? bias[n_g] : 0.f;
#pragma unroll
        for (int i = 0; i < MT; ++i) {
#pragma unroll
            for (int r = 0; r < 4; ++r) {
                const int m_g = m0 + wm + i * 16 + lq * 4 + r;
                const int nn2 = m_g >> 12;
                const int rr2 = m_g & 4095;
                const int oy = (rr2 >> 6) * sy_out + py;
                const int ox = (rr2 & 63) * sy_out + px;
                const size_t ob = ((size_t)(nn2 * OHf + oy) * OWf + ox) * Co + n_g;
                float v = acc[i][j][r] + bv;
                if (flags & F_RES)     v += res[ob];
                if (flags & F_OUTRELU) v = fmaxf(v, 0.f);
                if (out)    out[ob]    = v;
                if (out_bf) out_bf[ob] = __float2bfloat16(v);
            }
        }
    }
}

// ---------------- enc1: 4x4 s2 conv, 3->64, writes fp16 hi/lo planes ----------------
__global__ __launch_bounds__(256) void enc1_k(
    const float* __restrict__ x, const float* __restrict__ w,
    const float* __restrict__ bias, __half* __restrict__ oh, __half* __restrict__ ol)
{
    int idx = blockIdx.x * 256 + threadIdx.x;
    int cq  = (idx & 15) * 4;
    int pix = idx >> 4;
    int ox  = pix & 127;
    int t   = pix >> 7;
    int oy  = t & 127;
    int n   = t >> 7;
    float4 acc = *(const float4*)(bias + cq);
#pragma unroll
    for (int ky = 0; ky < 4; ++ky) {
        int iy = oy * 2 - 1 + ky;
        if (iy < 0 || iy >= 256) continue;
#pragma unroll
        for (int kx = 0; kx < 4; ++kx) {
            int ix = ox * 2 - 1 + kx;
            if (ix < 0 || ix >= 256) continue;
            const float* ip = x + (size_t)((n * 256 + iy) * 256 + ix) * 3;
            const float* wpk = w + (size_t)((ky * 4 + kx) * 3) * 64 + cq;
#pragma unroll
            for (int c = 0; c < 3; ++c) {
                float xv = ip[c];
                float4 wv = *(const float4*)(wpk + c * 64);
                acc.x = fmaf(xv, wv.x, acc.x);
                acc.y = fmaf(xv, wv.y, acc.y);
                acc.z = fmaf(xv, wv.z, acc.z);
                acc.w = fmaf(xv, wv.w, acc.w);
            }
        }
    }
    float v[4] = {fmaxf(acc.x, 0.f), fmaxf(acc.y, 0.f), fmaxf(acc.z, 0.f), fmaxf(acc.w, 0.f)};
    unsigned short hb[4], lb[4];
#pragma unroll
    for (int i = 0; i < 4; ++i) {
        __half h = __float2half(v[i]);
        hb[i] = __half_as_ushort(h);
        lb[i] = __half_as_ushort(__float2half((v[i] - __half2float(h)) * 2048.0f));
    }
    uint2 hv = make_uint2((unsigned)hb[0] | ((unsigned)hb[1] << 16),
                          (unsigned)hb[2] | ((unsigned)hb[3] << 16));
    uint2 lv = make_uint2((unsigned)lb[0] | ((unsigned)lb[1] << 16),
                          (unsigned)lb[2] | ((unsigned)lb[3] << 16));
    *(uint2*)(oh + (size_t)pix * 64 + cq) = hv;
    *(uint2*)(ol + (size_t)pix * 64 + cq) = lv;
}

// ---------------- dt2: convT 4x4 s2, 64->3 ----------------
__global__ __launch_bounds__(256) void convt_final_k(
    const float* __restrict__ in, const float* __restrict__ w,
    const float* __restrict__ bias, float* __restrict__ out)
{
    __shared__ __align__(16) float Wl[1536];
    const int tid = threadIdx.x;
    const int row = blockIdx.x;
    const int n   = row >> 8;
    const int oy  = row & 255;
    const int pY  = oy & 1;
    for (int i = tid; i < 1536; i += 256) {
        int co  = i >> 9;
        int rem = i & 511;
        int tap = rem >> 6;
        int ci  = rem & 63;
        int ky  = pY + ((tap >> 2) << 1);
        int kx  = tap & 3;
        Wl[i] = w[(size_t)((ky * 4 + kx) * 64 + ci) * 3 + co];
    }
    __syncthreads();
    const int wv = tid >> 6;
    const int p  = wv & 1;
    const int m  = ((wv >> 1) << 6) + (tid & 63);
    const int ox = 2 * m + p;
    float a0a = bias[0], a1a = bias[1], a2a = bias[2];
    float a0b = 0.f, a1b = 0.f, a2b = 0.f;
#pragma unroll
    for (int kyi = 0; kyi < 2; ++kyi) {
        int iy2 = oy + pY + 2 * kyi - 2;
        if (iy2 < 0 || iy2 >= 256) continue;
        int iy = iy2 >> 1;
#pragma unroll
        for (int t = 0; t < 2; ++t) {
            int ix = m + p + t - 1;
            if (ix < 0 || ix >= 128) continue;
            const float* ip = in + (size_t)((n * 128 + iy) * 128 + ix) * 64;
            const int kx = p + 2 * t;
            const float* w0 = Wl + ((kyi * 4 + kx) << 6);
            const float* w1 = w0 + 512;
            const float* w2 = w1 + 512;
#pragma unroll
            for (int q = 0; q < 16; ++q) {
                float4 v  = *(const float4*)(ip + q * 4);
                float4 b0 = *(const float4*)(w0 + q * 4);
                float4 b1 = *(const float4*)(w1 + q * 4);
                float4 b2 = *(const float4*)(w2 + q * 4);
                a0a = fmaf(v.x, b0.x, a0a); a0b = fmaf(v.y, b0.y, a0b);
                a0a = fmaf(v.z, b0.z, a0a); a0b = fmaf(v.w, b0.w, a0b);
                a1a = fmaf(v.x, b1.x, a1a); a1b = fmaf(v.y, b1.y, a1b);
                a1a = fmaf(v.z, b1.z, a1a); a1b = fmaf(v.w, b1.w, a1b);
                a2a = fmaf(v.x, b2.x, a2a); a2b = fmaf(v.y, b2.y, a2b);
                a2a = fmaf(v.z, b2.z, a2a); a2b = fmaf(v.w, b2.w, a2b);
            }
        }
    }
    float* op = out + (size_t)((n * 256 + oy) * 256 + ox) * 3;
    op[0] = a0a + a0b;
    op[1] = a1a + a1b;
    op[2] = a2a + a2b;
}

// ---------------- VQ ----------------
__global__ void enorm_k(const float* __restrict__ emb, float* __restrict__ en) {
    int k = blockIdx.x * 256 + threadIdx.x;
    if (k >= 512) return;
    const float4* e = (const float4*)(emb + k * 128);
    float s = 0.f;
    for (int i = 0; i < 32; ++i) {
        float4 v = e[i];
        s += v.x * v.x + v.y * v.y + v.z * v.z + v.w * v.w;
    }
    en[k] = s;
}

// MFMA VQ: block = 64 positions. f (hi/lo fp16) staged once in LDS in A-frag
// layout; B fragments stream from packed emb (L2). d = EN - 2(accA+accB/2048).
// Per-lane running argmin (codes ascend -> first occurrence), 16-lane shfl
// lexicographic reduce, fused gather.
__global__ __launch_bounds__(256) void vq_mfma_k(
    const __half* __restrict__ fh, const __half* __restrict__ fl,
    const __half* __restrict__ pe, const float* __restrict__ en,
    const float* __restrict__ emb, float* __restrict__ q, bf16* __restrict__ qb)
{
    __shared__ __align__(16) short Ash[64 * 128];  // [ch][q][m][8]
    __shared__ __align__(16) short Asl[64 * 128];
    __shared__ int sel[64];

    const int tid  = threadIdx.x;
    const int pos0 = blockIdx.x * 64;

    {
        const int am = tid >> 2;
        const int aq = tid & 3;
#pragma unroll
        for (int ch = 0; ch < 4; ++ch) {
            const size_t off = (size_t)(pos0 + am) * 128 + ch * 32 + aq * 8;
            uint4 vh = *(const uint4*)(fh + off);
            uint4 vl = *(const uint4*)(fl + off);
            *(uint4*)&Ash[((ch * 4 + aq) * 64 + am) * 8] = vh;
            *(uint4*)&Asl[((ch * 4 + aq) * 64 + am) * 8] = vl;
        }
    }
    __syncthreads();

    const int lane = tid & 63;
    const int w    = tid >> 6;          // wave: rows w*16..w*16+15
    const int lm = lane & 15, lq = lane >> 4;
    const int mbase = w * 16;
    const float s = 1.0f / 2048.0f;

    float best[4] = {3.4e38f, 3.4e38f, 3.4e38f, 3.4e38f};
    int   bidx[4] = {0, 0, 0, 0};

    f16x8 ah[4], alv[4];
#pragma unroll
    for (int ch = 0; ch < 4; ++ch) {
        ah[ch]  = *(const f16x8*)&Ash[((ch * 4 + lq) * 64 + mbase + lm) * 8];
        alv[ch] = *(const f16x8*)&Asl[((ch * 4 + lq) * 64 + mbase + lm) * 8];
    }

    for (int nb = 0; nb < 8; ++nb) {
        frag_cd accA[4], accB[4];
#pragma unroll
        for (int j = 0; j < 4; ++j)
#pragma unroll
            for (int r = 0; r < 4; ++r) { accA[j][r] = 0.f; accB[j][r] = 0.f; }

#pragma unroll
        for (int ch = 0; ch < 4; ++ch) {
            const __half* base = pe + (size_t)(nb * 4 + ch) * 4096;
            f16x8 bh[4], bl[4];
#pragma unroll
            for (int j = 0; j < 4; ++j) {
                const int o = (lq * 64 + j * 16 + lm) * 8;
                bh[j] = *(const f16x8*)(base + o);
                bl[j] = *(const f16x8*)(base + 2048 + o);
            }
#pragma unroll
            for (int j = 0; j < 4; ++j) {
                accA[j] = __builtin_amdgcn_mfma_f32_16x16x32_f16(ah[ch], bh[j], accA[j], 0, 0, 0);
                accB[j] = __builtin_amdgcn_mfma_f32_16x16x32_f16(ah[ch], bl[j], accB[j], 0, 0, 0);
                accB[j] = __builtin_amdgcn_mfma_f32_16x16x32_f16(alv[ch], bh[j], accB[j], 0, 0, 0);
            }
        }

#pragma unroll
        for (int j = 0; j < 4; ++j) {
            const int code = nb * 64 + j * 16 + lm;
            const float ec = en[code];
#pragma unroll
            for (int r = 0; r < 4; ++r) {
                float dot = accA[j][r] + accB[j][r] * s;
                float d = fmaf(dot, -2.f, ec);
                if (d < best[r]) { best[r] = d; bidx[r] = code; }
            }
        }
    }

#pragma unroll
    for (int r = 0; r < 4; ++r) {
        float d = best[r]; int ix = bidx[r];
#pragma unroll
        for (int m = 1; m < 16; m <<= 1) {
            float d2 = __shfl_xor(d, m);
            int   x2 = __shfl_xor(ix, m);
            if (d2 < d || (d2 == d && x2 < ix)) { d = d2; ix = x2; }
        }
        if (lm == 0) sel[mbase + lq * 4 + r] = ix;
    }
    __syncthreads();

#pragma unroll
    for (int jj = 0; jj < 32; ++jj) {
        int id = jj * 256 + tid;
        int p = id >> 7, k = id & 127;
        float v = emb[(size_t)sel[p] * 128 + k];
        q[(size_t)(pos0 + p) * 128 + k]  = v;
        qb[(size_t)(pos0 + p) * 128 + k] = __float2bfloat16(v);
    }
}

// ---------------- host ----------------
static TapSet conv_taps(int KH, int KW, int pad) {
    TapSet t{};
    for (int ky = 0; ky < KH; ++ky)
        for (int kx = 0; kx < KW; ++kx) {
            int i = ky * KW + kx;
            t.dy[i] = ky - pad; t.dx[i] = kx - pad; t.wi[i] = i;
        }
    return t;
}

static TapSet convt_taps(int py, int px) {
    TapSet t{};
    for (int ty = 0; ty < 2; ++ty)
        for (int tx = 0; tx < 2; ++tx) {
            int i = ty * 2 + tx;
            t.dy[i] = py + ty - 1;
            t.dx[i] = px + tx - 1;
            t.wi[i] = (py + 2 * ty) * 4 + (px + 2 * tx);
        }
    return t;
}

extern "C" void kernel_launch(void* const* d_in, const int* in_sizes, int n_in,
                              void* d_out, int out_size, void* d_ws, size_t ws_size,
                              hipStream_t stream)
{
    const float* x       = (const float*)d_in[0];
    const float* emb     = (const float*)d_in[1];
    const float* enc_w1  = (const float*)d_in[2];
    const float* enc_b1  = (const float*)d_in[3];
    const float* enc_w2  = (const float*)d_in[4];
    const float* enc_b2  = (const float*)d_in[5];
    const float* enc_w3  = (const float*)d_in[6];
    const float* enc_b3  = (const float*)d_in[7];
    const float* erb1_w1 = (const float*)d_in[8];
    const float* erb1_w2 = (const float*)d_in[9];
    const float* erb2_w1 = (const float*)d_in[10];
    const float* erb2_w2 = (const float*)d_in[11];
    const float* dec_w   = (const float*)d_in[12];
    const float* dec_b   = (const float*)d_in[13];
    const float* drb1_w1 = (const float*)d_in[14];
    const float* drb1_w2 = (const float*)d_in[15];
    const float* drb2_w1 = (const float*)d_in[16];
    const float* drb2_w2 = (const float*)d_in[17];
    const float* dt1_w   = (const float*)d_in[18];
    const float* dt1_b   = (const float*)d_in[19];
    const float* dt2_w   = (const float*)d_in[20];
    const float* dt2_b   = (const float*)d_in[21];

    char* wsb = (char*)d_ws;
    __half* H1 = (__half*)wsb;                           // 33.55 MB
    __half* L1 = (__half*)(wsb + (size_t)33554432);      // 33.55 MB
    __half* H2 = (__half*)(wsb + (size_t)67108864);      // 16.78 MB
    __half* L2 = (__half*)(wsb + (size_t)83886080);      // 16.78 MB
    __half* H3 = (__half*)wsb;
    __half* L3 = (__half*)(wsb + (size_t)16777216);
    __half* H4 = (__half*)(wsb + (size_t)33554432);
    __half* L4 = (__half*)(wsb + (size_t)50331648);
    __half* Ht = (__half*)(wsb + (size_t)100663296);     // 4.19 MB
    __half* Lt = (__half*)(wsb + (size_t)104857600);     // 4.19 MB
    float*  EN = (float*)(wsb + (size_t)109051904);      // 2 KB
    // VQ-phase: f hi/lo planes live in the (dead) H3/L3 region
    __half* Fh = (__half*)wsb;
    __half* Fl = (__half*)(wsb + (size_t)16777216);
    // decoder buffers
    bf16* Qb  = (bf16*)(wsb + (size_t)67108864);
    bf16* Db  = (bf16*)(wsb + (size_t)83886080);
    bf16* Y1b = Qb;
    bf16* Y2b = Db;
    bf16* Tb  = (bf16*)(wsb + (size_t)100663296);
    float* Y0 = (float*)wsb;
    float* Y1 = (float*)(wsb + (size_t)33554432);
    float* A1 = (float*)wsb;
    // packed weights
    char* pk = wsb + (size_t)109056000;
    bf16* Pdec  = (bf16*)pk;  pk += 147456 * 2;
    bf16* Pd1w1 = (bf16*)pk;  pk += 36864 * 2;
    bf16* Pd1w2 = (bf16*)pk;  pk += 4096 * 2;
    bf16* Pd2w1 = (bf16*)pk;  pk += 36864 * 2;
    bf16* Pd2w2 = (bf16*)pk;  pk += 4096 * 2;
    bf16* Pdt1[4];
    for (int i = 0; i < 4; ++i) { Pdt1[i] = (bf16*)pk; pk += 65536 * 2; }
    __half* P2enc2 = (__half*)pk; pk += 131072 * 4;
    __half* P2enc3 = (__half*)pk; pk += 147456 * 4;
    __half* P2e1w1 = (__half*)pk; pk += 36864 * 4;
    __half* P2e1w2 = (__half*)pk; pk += 4096 * 4;
    __half* P2e2w1 = (__half*)pk; pk += 36864 * 4;
    __half* P2e2w2 = (__half*)pk; pk += 4096 * 4;
    __half* Pe     = (__half*)pk; pk += 131072 * 2;      // packed emb hi/lo

    float* outY = (float*)d_out;
    float* outF = outY + 3145728;
    float* outQ = outF + 8388608;

    const TapSet t3 = conv_taps(3, 3, 1);
    const TapSet t4 = conv_taps(4, 4, 1);
    const TapSet t1 = conv_taps(1, 1, 0);
    TapSet tdt[4];
    for (int p = 0; p < 4; ++p) tdt[p] = convt_taps(p >> 1, p & 1);

    enorm_k<<<2, 256, 0, stream>>>(emb, EN);
    pack_emb_k<<<256, 256, 0, stream>>>(emb, Pe);

    // ---- weight packing ----
    pack_w_k<<<(147456 + 255) / 256, 256, 0, stream>>>(dec_w, Pdec, 128, 128, 64, t3, 147456);
    pack_w_k<<<(36864 + 255) / 256, 256, 0, stream>>>(drb1_w1, Pd1w1, 128, 32, 32, t3, 36864);
    pack_w_k<<<(4096 + 255) / 256, 256, 0, stream>>>(drb1_w2, Pd1w2, 32, 128, 64, t1, 4096);
    pack_w_k<<<(36864 + 255) / 256, 256, 0, stream>>>(drb2_w1, Pd2w1, 128, 32, 32, t3, 36864);
    pack_w_k<<<(4096 + 255) / 256, 256, 0, stream>>>(drb2_w2, Pd2w2, 32, 128, 64, t1, 4096);
    for (int p = 0; p < 4; ++p)
        pack_w_k<<<(65536 + 255) / 256, 256, 0, stream>>>(dt1_w, Pdt1[p], 128, 64, 64, tdt[p], 65536);
    pack_w2_k<<<(131072 + 255) / 256, 256, 0, stream>>>(enc_w2, P2enc2, 64, 128, 64, t4, 131072);
    pack_w2_k<<<(147456 + 255) / 256, 256, 0, stream>>>(enc_w3, P2enc3, 128, 128, 64, t3, 147456);
    pack_w2_k<<<(36864 + 255) / 256, 256, 0, stream>>>(erb1_w1, P2e1w1, 128, 32, 32, t3, 36864);
    pack_w2_k<<<(4096 + 255) / 256, 256, 0, stream>>>(erb1_w2, P2e1w2, 32, 128, 64, t1, 4096);
    pack_w2_k<<<(36864 + 255) / 256, 256, 0, stream>>>(erb2_w1, P2e2w1, 128, 32, 32, t3, 36864);
    pack_w2_k<<<(4096 + 255) / 256, 256, 0, stream>>>(erb2_w2, P2e2w2, 32, 128, 64, t1, 4096);

    // ---- encoder (fp16-split MFMA) ----
    enc1_k<<<16384, 256, 0, stream>>>(x, enc_w1, enc_b1, H1, L1);
    conv_mfma2_k<64><<<dim3(1024, 2), 256, 0, stream>>>(H1, L1, P2enc2, enc_b2,
        nullptr, H2, L2, nullptr, nullptr, 128, 128, 64, 128, 2, t4, 16, F_OUTRELU);
    conv_mfma2_k<64><<<dim3(1024, 2), 256, 0, stream>>>(H2, L2, P2enc3, enc_b3,
        nullptr, H3, L3, nullptr, nullptr, 64, 64, 128, 128, 1, t3, 9, 0);
    conv_mfma2_k<32><<<dim3(1024, 1), 256, 0, stream>>>(H3, L3, P2e1w1, nullptr,
        nullptr, Ht, Lt, nullptr, nullptr, 64, 64, 128, 32, 1, t3, 9, F_INRELU);
    conv_mfma2_k<64><<<dim3(1024, 2), 256, 0, stream>>>(Ht, Lt, P2e1w2, nullptr,
        nullptr, H4, L4, H3, L3, 64, 64, 32, 128, 1, t1, 1, F_INRELU | F_RES);
    conv_mfma2_k<32><<<dim3(1024, 1), 256, 0, stream>>>(H4, L4, P2e2w1, nullptr,
        nullptr, Ht, Lt, nullptr, nullptr, 64, 64, 128, 32, 1, t3, 9, F_INRELU);
    // final: writes f (fp32 output) + f hi/lo planes for the MFMA VQ
    conv_mfma2_k<64><<<dim3(1024, 2), 256, 0, stream>>>(Ht, Lt, P2e2w2, nullptr,
        outF, Fh, Fl, H4, L4, 64, 64, 32, 128, 1, t1, 1, F_INRELU | F_RES | F_OUTRELU);

    // ---- VQ (fp16-split MFMA distances, fp32-accurate argmin) ----
    vq_mfma_k<<<1024, 256, 0, stream>>>(Fh, Fl, Pe, EN, emb, outQ, Qb);

    // ---- decoder (bf16 MFMA) ----
    conv_mfma_k<64><<<dim3(1024, 2), 256, 0, stream>>>(Qb, Pdec, dec_b, Y0, Db, nullptr,
        128, 128, 64, 64, 1, 0, 0, t3, 9, 0);
    conv_mfma_k<32><<<dim3(1024, 1), 256, 0, stream>>>(Db, Pd1w1, nullptr, nullptr, Tb, nullptr,
        128, 32, 64, 64, 1, 0, 0, t3, 9, F_INRELU);
    conv_mfma_k<64><<<dim3(1024, 2), 256, 0, stream>>>(Tb, Pd1w2, nullptr, Y1, Y1b, Y0,
        32, 128, 64, 64, 1, 0, 0, t1, 1, F_INRELU | F_RES);
    conv_mfma_k<32><<<dim3(1024, 1), 256, 0, stream>>>(Y1b, Pd2w1, nullptr, nullptr, Tb, nullptr,
        128, 32, 64, 64, 1, 0, 0, t3, 9, F_INRELU);
    conv_mfma_k<64><<<dim3(1024, 2), 256, 0, stream>>>(Tb, Pd2w2, nullptr, nullptr, Y2b, Y1,
        32, 128, 64, 64, 1, 0, 0, t1, 1, F_INRELU | F_RES | F_OUTRELU);
    for (int p = 0; p < 4; ++p)
        conv_mfma_k<64><<<dim3(1024, 1), 256, 0, stream>>>(Y2b, Pdt1[p], dt1_b, A1, nullptr, nullptr,
            128, 64, 128, 128, 2, p >> 1, p & 1, tdt[p], 4, F_OUTRELU);
    convt_final_k<<<4096, 256, 0, stream>>>(A1, dt2_w, dt2_b, outY);
}

// Round 9
// 916.853 us; speedup vs baseline: 14.1653x; 1.1004x over previous
//
#include <hip/hip_runtime.h>
#include <hip/hip_bf16.h>
#include <hip/hip_fp16.h>

using bf16 = __hip_bfloat16;
using frag_ab = __attribute__((ext_vector_type(8))) short;
using f16x8  = __attribute__((ext_vector_type(8))) _Float16;
using frag_cd = __attribute__((ext_vector_type(4))) float;

enum { F_INRELU = 1, F_OUTRELU = 2, F_RES = 4 };

struct TapSet { int dy[16]; int dx[16]; int wi[16]; };

__device__ __forceinline__ unsigned int relu_pk(unsigned int v) {
    unsigned int m = ((v & 0x80008000u) >> 15) * 0xFFFFu;
    return v & ~m;
}
__device__ __forceinline__ unsigned int mask_by(unsigned int v, unsigned int h) {
    unsigned int m = ((h & 0x80008000u) >> 15) * 0xFFFFu;
    return v & ~m;
}

// ---------------- weight pre-pack: bf16 (decoder) ----------------
__global__ void pack_w_k(const float* __restrict__ w, bf16* __restrict__ dst,
                         int Ci, int Co, int BN, TapSet taps, int total)
{
    int idx = blockIdx.x * 256 + threadIdx.x;
    if (idx >= total) return;
    int j  = idx & 7;
    int r1 = idx >> 3;
    int nl = r1 % BN;
    int r2 = r1 / BN;
    int q  = r2 & 3;
    int cb = r2 >> 2;
    int nblocks = Co / BN;
    int c  = cb / nblocks;
    int nb = cb - c * nblocks;
    int cpt = Ci >> 5;
    int tap = c / cpt;
    int ci  = (c - tap * cpt) * 32 + q * 8 + j;
    int n   = nb * BN + nl;
    dst[idx] = __float2bfloat16(w[(size_t)(taps.wi[tap] * Ci + ci) * Co + n]);
}

// ---------------- weight pre-pack: fp16 hi/lo split (encoder) ----------------
__global__ void pack_w2_k(const float* __restrict__ w, __half* __restrict__ dst,
                          int Ci, int Co, int BN, TapSet taps, int total)
{
    int idx = blockIdx.x * 256 + threadIdx.x;
    if (idx >= total) return;
    int j  = idx & 7;
    int r1 = idx >> 3;
    int nl = r1 % BN;
    int r2 = r1 / BN;
    int q  = r2 & 3;
    int cb = r2 >> 2;
    int nblocks = Co / BN;
    int c  = cb / nblocks;
    int nb = cb - c * nblocks;
    int cpt = Ci >> 5;
    int tap = c / cpt;
    int ci  = (c - tap * cpt) * 32 + q * 8 + j;
    int n   = nb * BN + nl;
    float v = w[(size_t)(taps.wi[tap] * Ci + ci) * Co + n];
    __half h = __float2half(v);
    __half l = __float2half((v - __half2float(h)) * 2048.0f);
    size_t base = (size_t)cb * (BN * 64) + (q * BN + nl) * 8 + j;
    dst[base] = h;
    dst[base + BN * 32] = l;
}

// ---------------- enc1 weight pack: (4,4,3,64) -> K=64 (4th ch zero), hi/lo ----------------
__global__ void pack_we1_k(const float* __restrict__ w, __half* __restrict__ dst)
{
    int idx = blockIdx.x * 256 + threadIdx.x;   // 2*4*64*8 = 4096
    if (idx >= 4096) return;
    int j  = idx & 7;
    int r1 = idx >> 3;
    int nl = r1 & 63;
    int r2 = r1 >> 6;
    int q  = r2 & 3;
    int c  = r2 >> 2;                 // chunk 0/1
    int k  = c * 32 + q * 8 + j;
    int tap = k >> 2, ci = k & 3;
    float v = (ci < 3) ? w[(size_t)(tap * 3 + ci) * 64 + nl] : 0.f;
    __half h = __float2half(v);
    __half l = __float2half((v - __half2float(h)) * 2048.0f);
    size_t base = (size_t)c * 4096 + (q * 64 + nl) * 8 + j;
    dst[base] = h;
    dst[base + 2048] = l;
}

// ---------------- x pad: (16,256,256,3) fp32 -> (.,4) fp16 hi/lo ----------------
__global__ __launch_bounds__(256) void pad_x_k(
    const float* __restrict__ x, __half* __restrict__ xh, __half* __restrict__ xl)
{
    int pix = blockIdx.x * 256 + threadIdx.x;   // 1048576
    const float* ip = x + (size_t)pix * 3;
    float v0 = ip[0], v1 = ip[1], v2 = ip[2];
    unsigned short hb[4], lb[4];
    float vv[4] = {v0, v1, v2, 0.f};
#pragma unroll
    for (int i = 0; i < 4; ++i) {
        __half h = __float2half(vv[i]);
        hb[i] = __half_as_ushort(h);
        lb[i] = __half_as_ushort(__float2half((vv[i] - __half2float(h)) * 2048.0f));
    }
    uint2 hv = make_uint2((unsigned)hb[0] | ((unsigned)hb[1] << 16),
                          (unsigned)hb[2] | ((unsigned)hb[3] << 16));
    uint2 lv = make_uint2((unsigned)lb[0] | ((unsigned)lb[1] << 16),
                          (unsigned)lb[2] | ((unsigned)lb[3] << 16));
    *(uint2*)(xh + (size_t)pix * 4) = hv;
    *(uint2*)(xl + (size_t)pix * 4) = lv;
}

// ---------------- enc1: 4x4 s2, 4ch padded, fp16-split MFMA ----------------
// M = 16*128*128, K = 64 (16 taps x 4ch, 2 chunks), N = 64.
__global__ __launch_bounds__(256) void enc1_mfma_k(
    const __half* __restrict__ xh, const __half* __restrict__ xl,
    const __half* __restrict__ wp, const float* __restrict__ bias,
    __half* __restrict__ oh, __half* __restrict__ ol)
{
    __shared__ __align__(16) short Ash[64 * 32];
    __shared__ __align__(16) short Asl[64 * 32];
    __shared__ __align__(16) short Bsh[64 * 32];
    __shared__ __align__(16) short Bsl[64 * 32];

    const int tid = threadIdx.x;
    const int m0 = blockIdx.x * 64;

    const int am = tid >> 2;
    const int aq = tid & 3;
    const int gm  = m0 + am;
    const int nn_ = gm >> 14;            // 128*128 pixels/image
    const int rr_ = gm & 16383;
    const int iy0 = (rr_ >> 7) * 2 - 1;
    const int ix0 = (rr_ & 127) * 2 - 1;

    const int lane = tid & 63;
    const int wv4 = tid >> 6;
    const int wm = (wv4 & 1) * 32;
    const int wn = (wv4 >> 1) * 32;
    const int lm = lane & 15, lq = lane >> 4;

    frag_cd accA[2][2], accB[2][2];
#pragma unroll
    for (int i = 0; i < 2; ++i)
#pragma unroll
        for (int j = 0; j < 2; ++j)
#pragma unroll
            for (int r = 0; r < 4; ++r) { accA[i][j][r] = 0.f; accB[i][j][r] = 0.f; }

#pragma unroll
    for (int c = 0; c < 2; ++c) {
        // taps c*8 + aq*2, +1 : same ky, adjacent kx
        const int tap = c * 8 + aq * 2;
        const int ky = tap >> 2, kx = tap & 3;
        const int iy = iy0 + ky;
        const int ix = ix0 + kx;
        uint2 h0 = make_uint2(0u, 0u), h1 = h0, l0 = h0, l1 = h0;
        if (iy >= 0 && iy < 256) {
            const size_t rowb = (size_t)(nn_ * 256 + iy) * 256;
            if (ix >= 0 && ix < 256) {
                h0 = *(const uint2*)(xh + (rowb + ix) * 4);
                l0 = *(const uint2*)(xl + (rowb + ix) * 4);
            }
            if (ix + 1 >= 0 && ix + 1 < 256) {
                h1 = *(const uint2*)(xh + (rowb + ix + 1) * 4);
                l1 = *(const uint2*)(xl + (rowb + ix + 1) * 4);
            }
        }
        __syncthreads();
        *(uint4*)&Ash[(aq * 64 + am) * 8] = make_uint4(h0.x, h0.y, h1.x, h1.y);
        *(uint4*)&Asl[(aq * 64 + am) * 8] = make_uint4(l0.x, l0.y, l1.x, l1.y);
        {
            const __half* wc = wp + (size_t)c * 4096;
            *(uint4*)&Bsh[tid * 8] = *(const uint4*)(wc + tid * 8);
            *(uint4*)&Bsl[tid * 8] = *(const uint4*)(wc + 2048 + tid * 8);
        }
        __syncthreads();

        f16x8 afh[2], afl[2], bfh[2], bfl[2];
#pragma unroll
        for (int i = 0; i < 2; ++i) {
            afh[i] = *(const f16x8*)&Ash[(lq * 64 + wm + i * 16 + lm) * 8];
            afl[i] = *(const f16x8*)&Asl[(lq * 64 + wm + i * 16 + lm) * 8];
        }
#pragma unroll
        for (int j = 0; j < 2; ++j) {
            bfh[j] = *(const f16x8*)&Bsh[(lq * 64 + wn + j * 16 + lm) * 8];
            bfl[j] = *(const f16x8*)&Bsl[(lq * 64 + wn + j * 16 + lm) * 8];
        }
#pragma unroll
        for (int i = 0; i < 2; ++i)
#pragma unroll
            for (int j = 0; j < 2; ++j) {
                accA[i][j] = __builtin_amdgcn_mfma_f32_16x16x32_f16(afh[i], bfh[j], accA[i][j], 0, 0, 0);
                accB[i][j] = __builtin_amdgcn_mfma_f32_16x16x32_f16(afh[i], bfl[j], accB[i][j], 0, 0, 0);
                accB[i][j] = __builtin_amdgcn_mfma_f32_16x16x32_f16(afl[i], bfh[j], accB[i][j], 0, 0, 0);
            }
    }

    const float s = 1.0f / 2048.0f;
#pragma unroll
    for (int j = 0; j < 2; ++j) {
        const int n_g = wn + j * 16 + lm;
        const float bv = bias[n_g];
#pragma unroll
        for (int i = 0; i < 2; ++i) {
#pragma unroll
            for (int r = 0; r < 4; ++r) {
                const int m_g = m0 + wm + i * 16 + lq * 4 + r;
                const size_t ob = (size_t)m_g * 64 + n_g;
                float v = accA[i][j][r] + accB[i][j][r] * s + bv;
                v = fmaxf(v, 0.f);
                __half h = __float2half(v);
                oh[ob] = h;
                ol[ob] = __float2half((v - __half2float(h)) * 2048.0f);
            }
        }
    }
}

// ---------------- fp16-split MFMA implicit-GEMM conv (encoder) ----------------
template<int BN>
__global__ __launch_bounds__(256) void conv_mfma2_k(
    const __half* __restrict__ ah, const __half* __restrict__ al,
    const __half* __restrict__ wp, const float* __restrict__ bias,
    float* __restrict__ out, __half* __restrict__ oh, __half* __restrict__ ol,
    const __half* __restrict__ rh, const __half* __restrict__ rl,
    int IH, int IW, int Ci, int Co, int sy_in,
    TapSet taps, int ntaps, int flags)
{
    __shared__ __align__(16) short Ash[64 * 32];
    __shared__ __align__(16) short Asl[64 * 32];
    __shared__ __align__(16) short Bsh[BN * 32];
    __shared__ __align__(16) short Bsl[BN * 32];

    const int tid = threadIdx.x;
    const int m0 = blockIdx.x * 64;
    const int n0 = blockIdx.y * BN;

    const int am = tid >> 2;
    const int aq = tid & 3;
    const int gm  = m0 + am;
    const int nn_ = gm >> 12;
    const int rr_ = gm & 4095;
    const int oy_ = (rr_ >> 6) * sy_in;
    const int ox_ = (rr_ & 63) * sy_in;

    const int lane = tid & 63;
    const int wv4 = tid >> 6;
    constexpr int MT = (BN == 64) ? 2 : 1;
    constexpr int NT = 2;
    const int wm = (BN == 64) ? (wv4 & 1) * 32 : wv4 * 16;
    const int wn = (BN == 64) ? (wv4 >> 1) * 32 : 0;
    const int lm = lane & 15, lq = lane >> 4;
    constexpr int NLOAD = BN * 32 / 8;

    frag_cd accA[MT][NT], accB[MT][NT];
#pragma unroll
    for (int i = 0; i < MT; ++i)
#pragma unroll
        for (int j = 0; j < NT; ++j)
#pragma unroll
            for (int r = 0; r < 4; ++r) { accA[i][j][r] = 0.f; accB[i][j][r] = 0.f; }

    const int cpt = Ci >> 5;
    const int nch = ntaps * cpt;
    const bool inrelu = (flags & F_INRELU) != 0;

    int tap = 0, cc = 0, ci0 = 0;
    for (int c = 0; c < nch; ++c) {
        const int iy = oy_ + taps.dy[tap];
        const int ix = ox_ + taps.dx[tap];
        uint4 avh = make_uint4(0u, 0u, 0u, 0u);
        uint4 avl = make_uint4(0u, 0u, 0u, 0u);
        if (iy >= 0 && iy < IH && ix >= 0 && ix < IW) {
            const size_t off = (size_t)((nn_ * IH + iy) * IW + ix) * Ci + ci0 + aq * 8;
            avh = *(const uint4*)(ah + off);
            avl = *(const uint4*)(al + off);
        }
        if (inrelu) {
            avl.x = mask_by(avl.x, avh.x); avl.y = mask_by(avl.y, avh.y);
            avl.z = mask_by(avl.z, avh.z); avl.w = mask_by(avl.w, avh.w);
            avh.x = relu_pk(avh.x); avh.y = relu_pk(avh.y);
            avh.z = relu_pk(avh.z); avh.w = relu_pk(avh.w);
        }
        uint4 bvh, bvl;
        if (tid < NLOAD) {
            const __half* wc = wp + (size_t)(c * gridDim.y + blockIdx.y) * (BN * 64);
            bvh = *(const uint4*)(wc + tid * 8);
            bvl = *(const uint4*)(wc + BN * 32 + tid * 8);
        }

        __syncthreads();
        *(uint4*)&Ash[(aq * 64 + am) * 8] = avh;
        *(uint4*)&Asl[(aq * 64 + am) * 8] = avl;
        if (tid < NLOAD) {
            *(uint4*)&Bsh[tid * 8] = bvh;
            *(uint4*)&Bsl[tid * 8] = bvl;
        }
        __syncthreads();

        f16x8 afh[MT], afl[MT], bfh[NT], bfl[NT];
#pragma unroll
        for (int i = 0; i < MT; ++i) {
            afh[i] = *(const f16x8*)&Ash[(lq * 64 + wm + i * 16 + lm) * 8];
            afl[i] = *(const f16x8*)&Asl[(lq * 64 + wm + i * 16 + lm) * 8];
        }
#pragma unroll
        for (int j = 0; j < NT; ++j) {
            bfh[j] = *(const f16x8*)&Bsh[(lq * BN + wn + j * 16 + lm) * 8];
            bfl[j] = *(const f16x8*)&Bsl[(lq * BN + wn + j * 16 + lm) * 8];
        }
#pragma unroll
        for (int i = 0; i < MT; ++i)
#pragma unroll
            for (int j = 0; j < NT; ++j) {
                accA[i][j] = __builtin_amdgcn_mfma_f32_16x16x32_f16(afh[i], bfh[j], accA[i][j], 0, 0, 0);
                accB[i][j] = __builtin_amdgcn_mfma_f32_16x16x32_f16(afh[i], bfl[j], accB[i][j], 0, 0, 0);
                accB[i][j] = __builtin_amdgcn_mfma_f32_16x16x32_f16(afl[i], bfh[j], accB[i][j], 0, 0, 0);
            }

        ci0 += 32;
        if (++cc == cpt) { cc = 0; ci0 = 0; ++tap; }
    }

    const float s = 1.0f / 2048.0f;
#pragma unroll
    for (int j = 0; j < NT; ++j) {
        const int n_g = n0 + wn + j * 16 + lm;
        const float bv = bias ? bias[n_g] : 0.f;
#pragma unroll
        for (int i = 0; i < MT; ++i) {
#pragma unroll
            for (int r = 0; r < 4; ++r) {
                const int m_g = m0 + wm + i * 16 + lq * 4 + r;
                const size_t ob = (size_t)m_g * Co + n_g;
                float v = accA[i][j][r] + accB[i][j][r] * s + bv;
                if (flags & F_RES)
                    v += __half2float(rh[ob]) + __half2float(rl[ob]) * s;
                if (flags & F_OUTRELU) v = fmaxf(v, 0.f);
                if (out) out[ob] = v;
                if (oh) {
                    __half h = __float2half(v);
                    oh[ob] = h;
                    ol[ob] = __float2half((v - __half2float(h)) * 2048.0f);
                }
            }
        }
    }
}

// ---------------- bf16 MFMA implicit-GEMM conv (decoder) ----------------
template<int BN>
__global__ __launch_bounds__(256) void conv_mfma_k(
    const bf16* __restrict__ a, const bf16* __restrict__ wp,
    const float* __restrict__ bias,
    float* __restrict__ out, bf16* __restrict__ out_bf,
    const float* __restrict__ res,
    int Ci, int Co, int OHf, int OWf, int sy_out, int py, int px,
    TapSet taps, int ntaps, int flags)
{
    __shared__ __align__(16) short As[64 * 32];
    __shared__ __align__(16) short Bs[BN * 32];

    const int tid = threadIdx.x;
    const int m0 = blockIdx.x * 64;
    const int n0 = blockIdx.y * BN;

    const int am = tid >> 2;
    const int aq = tid & 3;
    const int gm  = m0 + am;
    const int nn_ = gm >> 12;
    const int rr_ = gm & 4095;
    const int oy_ = rr_ >> 6;
    const int ox_ = rr_ & 63;

    const int lane = tid & 63;
    const int wv4 = tid >> 6;
    constexpr int MT = (BN == 64) ? 2 : 1;
    constexpr int NT = 2;
    const int wm = (BN == 64) ? (wv4 & 1) * 32 : wv4 * 16;
    const int wn = (BN == 64) ? (wv4 >> 1) * 32 : 0;
    const int lm = lane & 15, lq = lane >> 4;
    constexpr int NLOAD = BN * 32 / 8;

    frag_cd acc[MT][NT];
#pragma unroll
    for (int i = 0; i < MT; ++i)
#pragma unroll
        for (int j = 0; j < NT; ++j)
#pragma unroll
            for (int r = 0; r < 4; ++r) acc[i][j][r] = 0.f;

    const int cpt = Ci >> 5;
    const int nch = ntaps * cpt;
    const bool inrelu = (flags & F_INRELU) != 0;

    int tap = 0, cc = 0, ci0 = 0;
    for (int c = 0; c < nch; ++c) {
        const int iy = oy_ + taps.dy[tap];
        const int ix = ox_ + taps.dx[tap];
        uint4 av = make_uint4(0u, 0u, 0u, 0u);
        if (iy >= 0 && iy < 64 && ix >= 0 && ix < 64)
            av = *(const uint4*)(a + (size_t)((nn_ * 64 + iy) * 64 + ix) * Ci + ci0 + aq * 8);
        if (inrelu) {
            av.x = relu_pk(av.x); av.y = relu_pk(av.y);
            av.z = relu_pk(av.z); av.w = relu_pk(av.w);
        }
        uint4 bv;
        if (tid < NLOAD)
            bv = *(const uint4*)(wp + ((size_t)c * gridDim.y + blockIdx.y) * (BN * 32) + tid * 8);

        __syncthreads();
        *(uint4*)&As[(aq * 64 + am) * 8] = av;
        if (tid < NLOAD) *(uint4*)&Bs[tid * 8] = bv;
        __syncthreads();

        frag_ab af[MT], bfr[NT];
#pragma unroll
        for (int i = 0; i < MT; ++i)
            af[i] = *(const frag_ab*)&As[(lq * 64 + wm + i * 16 + lm) * 8];
#pragma unroll
        for (int j = 0; j < NT; ++j)
            bfr[j] = *(const frag_ab*)&Bs[(lq * BN + wn + j * 16 + lm) * 8];
#pragma unroll
        for (int i = 0; i < MT; ++i)
#pragma unroll
            for (int j = 0; j < NT; ++j)
                acc[i][j] = __builtin_amdgcn_mfma_f32_16x16x32_bf16(af[i], bfr[j], acc[i][j], 0, 0, 0);

        ci0 += 32;
        if (++cc == cpt) { cc = 0; ci0 = 0; ++tap; }
    }

#pragma unroll
    for (int j = 0; j < NT; ++j) {
        const int n_g = n0 + wn + j * 16 + lm;
        const float bv = bias ? bias[n_g] : 0.f;
#pragma unroll
        for (int i = 0; i < MT; ++i) {
#pragma unroll
            for (int r = 0; r < 4; ++r) {
                const int m_g = m0 + wm + i * 16 + lq * 4 + r;
                const int nn2 = m_g >> 12;
                const int rr2 = m_g & 4095;
                const int oy = (rr2 >> 6) * sy_out + py;
                const int ox = (rr2 & 63) * sy_out + px;
                const size_t ob = ((size_t)(nn2 * OHf + oy) * OWf + ox) * Co + n_g;
                float v = acc[i][j][r] + bv;
                if (flags & F_RES)     v += res[ob];
                if (flags & F_OUTRELU) v = fmaxf(v, 0.f);
                if (out)    out[ob]    = v;
                if (out_bf) out_bf[ob] = __float2bfloat16(v);
            }
        }
    }
}

// ---------------- dt2: convT 4x4 s2, 64->3 ----------------
__global__ __launch_bounds__(256) void convt_final_k(
    const float* __restrict__ in, const float* __restrict__ w,
    const float* __restrict__ bias, float* __restrict__ out)
{
    __shared__ __align__(16) float Wl[1536];
    const int tid = threadIdx.x;
    const int row = blockIdx.x;
    const int n   = row >> 8;
    const int oy  = row & 255;
    const int pY  = oy & 1;
    for (int i = tid; i < 1536; i += 256) {
        int co  = i >> 9;
        int rem = i & 511;
        int tap = rem >> 6;
        int ci  = rem & 63;
        int ky  = pY + ((tap >> 2) << 1);
        int kx  = tap & 3;
        Wl[i] = w[(size_t)((ky * 4 + kx) * 64 + ci) * 3 + co];
    }
    __syncthreads();
    const int wv = tid >> 6;
    const int p  = wv & 1;
    const int m  = ((wv >> 1) << 6) + (tid & 63);
    const int ox = 2 * m + p;
    float a0a = bias[0], a1a = bias[1], a2a = bias[2];
    float a0b = 0.f, a1b = 0.f, a2b = 0.f;
#pragma unroll
    for (int kyi = 0; kyi < 2; ++kyi) {
        int iy2 = oy + pY + 2 * kyi - 2;
        if (iy2 < 0 || iy2 >= 256) continue;
        int iy = iy2 >> 1;
#pragma unroll
        for (int t = 0; t < 2; ++t) {
            int ix = m + p + t - 1;
            if (ix < 0 || ix >= 128) continue;
            const float* ip = in + (size_t)((n * 128 + iy) * 128 + ix) * 64;
            const int kx = p + 2 * t;
            const float* w0 = Wl + ((kyi * 4 + kx) << 6);
            const float* w1 = w0 + 512;
            const float* w2 = w1 + 512;
#pragma unroll
            for (int q = 0; q < 16; ++q) {
                float4 v  = *(const float4*)(ip + q * 4);
                float4 b0 = *(const float4*)(w0 + q * 4);
                float4 b1 = *(const float4*)(w1 + q * 4);
                float4 b2 = *(const float4*)(w2 + q * 4);
                a0a = fmaf(v.x, b0.x, a0a); a0b = fmaf(v.y, b0.y, a0b);
                a0a = fmaf(v.z, b0.z, a0a); a0b = fmaf(v.w, b0.w, a0b);
                a1a = fmaf(v.x, b1.x, a1a); a1b = fmaf(v.y, b1.y, a1b);
                a1a = fmaf(v.z, b1.z, a1a); a1b = fmaf(v.w, b1.w, a1b);
                a2a = fmaf(v.x, b2.x, a2a); a2b = fmaf(v.y, b2.y, a2b);
                a2a = fmaf(v.z, b2.z, a2a); a2b = fmaf(v.w, b2.w, a2b);
            }
        }
    }
    float* op = out + (size_t)((n * 256 + oy) * 256 + ox) * 3;
    op[0] = a0a + a0b;
    op[1] = a1a + a1b;
    op[2] = a2a + a2b;
}

// ---------------- VQ ----------------
__global__ void enorm_k(const float* __restrict__ emb, float* __restrict__ en) {
    int k = blockIdx.x * 256 + threadIdx.x;
    if (k >= 512) return;
    const float4* e = (const float4*)(emb + k * 128);
    float s = 0.f;
    for (int i = 0; i < 32; ++i) {
        float4 v = e[i];
        s += v.x * v.x + v.y * v.y + v.z * v.z + v.w * v.w;
    }
    en[k] = s;
}

__global__ void pack_emb_k(const float* __restrict__ emb, __half* __restrict__ dst)
{
    int idx = blockIdx.x * 256 + threadIdx.x;   // 65536
    int k = idx & 127;
    int n = idx >> 7;
    float v = emb[idx];
    __half h = __float2half(v);
    __half l = __float2half((v - __half2float(h)) * 2048.0f);
    int nb = n >> 6, nl = n & 63;
    int ch = k >> 5, q = (k >> 3) & 3, j = k & 7;
    size_t base = (size_t)(nb * 4 + ch) * 4096 + (q * 64 + nl) * 8 + j;
    dst[base] = h;
    dst[base + 2048] = l;
}

__global__ __launch_bounds__(256) void vq_mfma_k(
    const __half* __restrict__ fh, const __half* __restrict__ fl,
    const __half* __restrict__ pe, const float* __restrict__ en,
    const float* __restrict__ emb, float* __restrict__ q, bf16* __restrict__ qb)
{
    __shared__ __align__(16) short Ash[64 * 128];
    __shared__ __align__(16) short Asl[64 * 128];
    __shared__ int sel[64];

    const int tid  = threadIdx.x;
    const int pos0 = blockIdx.x * 64;

    {
        const int am = tid >> 2;
        const int aq = tid & 3;
#pragma unroll
        for (int ch = 0; ch < 4; ++ch) {
            const size_t off = (size_t)(pos0 + am) * 128 + ch * 32 + aq * 8;
            uint4 vh = *(const uint4*)(fh + off);
            uint4 vl = *(const uint4*)(fl + off);
            *(uint4*)&Ash[((ch * 4 + aq) * 64 + am) * 8] = vh;
            *(uint4*)&Asl[((ch * 4 + aq) * 64 + am) * 8] = vl;
        }
    }
    __syncthreads();

    const int lane = tid & 63;
    const int w    = tid >> 6;
    const int lm = lane & 15, lq = lane >> 4;
    const int mbase = w * 16;
    const float s = 1.0f / 2048.0f;

    float best[4] = {3.4e38f, 3.4e38f, 3.4e38f, 3.4e38f};
    int   bidx[4] = {0, 0, 0, 0};

    f16x8 ah[4], alv[4];
#pragma unroll
    for (int ch = 0; ch < 4; ++ch) {
        ah[ch]  = *(const f16x8*)&Ash[((ch * 4 + lq) * 64 + mbase + lm) * 8];
        alv[ch] = *(const f16x8*)&Asl[((ch * 4 + lq) * 64 + mbase + lm) * 8];
    }

    for (int nb = 0; nb < 8; ++nb) {
        frag_cd accA[4], accB[4];
#pragma unroll
        for (int j = 0; j < 4; ++j)
#pragma unroll
            for (int r = 0; r < 4; ++r) { accA[j][r] = 0.f; accB[j][r] = 0.f; }

#pragma unroll
        for (int ch = 0; ch < 4; ++ch) {
            const __half* base = pe + (size_t)(nb * 4 + ch) * 4096;
            f16x8 bh[4], bl[4];
#pragma unroll
            for (int j = 0; j < 4; ++j) {
                const int o = (lq * 64 + j * 16 + lm) * 8;
                bh[j] = *(const f16x8*)(base + o);
                bl[j] = *(const f16x8*)(base + 2048 + o);
            }
#pragma unroll
            for (int j = 0; j < 4; ++j) {
                accA[j] = __builtin_amdgcn_mfma_f32_16x16x32_f16(ah[ch], bh[j], accA[j], 0, 0, 0);
                accB[j] = __builtin_amdgcn_mfma_f32_16x16x32_f16(ah[ch], bl[j], accB[j], 0, 0, 0);
                accB[j] = __builtin_amdgcn_mfma_f32_16x16x32_f16(alv[ch], bh[j], accB[j], 0, 0, 0);
            }
        }

#pragma unroll
        for (int j = 0; j < 4; ++j) {
            const int code = nb * 64 + j * 16 + lm;
            const float ec = en[code];
#pragma unroll
            for (int r = 0; r < 4; ++r) {
                float dot = accA[j][r] + accB[j][r] * s;
                float d = fmaf(dot, -2.f, ec);
                if (d < best[r]) { best[r] = d; bidx[r] = code; }
            }
        }
    }

#pragma unroll
    for (int r = 0; r < 4; ++r) {
        float d = best[r]; int ix = bidx[r];
#pragma unroll
        for (int m = 1; m < 16; m <<= 1) {
            float d2 = __shfl_xor(d, m);
            int   x2 = __shfl_xor(ix, m);
            if (d2 < d || (d2 == d && x2 < ix)) { d = d2; ix = x2; }
        }
        if (lm == 0) sel[mbase + lq * 4 + r] = ix;
    }
    __syncthreads();

#pragma unroll
    for (int jj = 0; jj < 32; ++jj) {
        int id = jj * 256 + tid;
        int p = id >> 7, k = id & 127;
        float v = emb[(size_t)sel[p] * 128 + k];
        q[(size_t)(pos0 + p) * 128 + k]  = v;
        qb[(size_t)(pos0 + p) * 128 + k] = __float2bfloat16(v);
    }
}

// ---------------- host ----------------
static TapSet conv_taps(int KH, int KW, int pad) {
    TapSet t{};
    for (int ky = 0; ky < KH; ++ky)
        for (int kx = 0; kx < KW; ++kx) {
            int i = ky * KW + kx;
            t.dy[i] = ky - pad; t.dx[i] = kx - pad; t.wi[i] = i;
        }
    return t;
}

static TapSet convt_taps(int py, int px) {
    TapSet t{};
    for (int ty = 0; ty < 2; ++ty)
        for (int tx = 0; tx < 2; ++tx) {
            int i = ty * 2 + tx;
            t.dy[i] = py + ty - 1;
            t.dx[i] = px + tx - 1;
            t.wi[i] = (py + 2 * ty) * 4 + (px + 2 * tx);
        }
    return t;
}

extern "C" void kernel_launch(void* const* d_in, const int* in_sizes, int n_in,
                              void* d_out, int out_size, void* d_ws, size_t ws_size,
                              hipStream_t stream)
{
    const float* x       = (const float*)d_in[0];
    const float* emb     = (const float*)d_in[1];
    const float* enc_w1  = (const float*)d_in[2];
    const float* enc_b1  = (const float*)d_in[3];
    const float* enc_w2  = (const float*)d_in[4];
    const float* enc_b2  = (const float*)d_in[5];
    const float* enc_w3  = (const float*)d_in[6];
    const float* enc_b3  = (const float*)d_in[7];
    const float* erb1_w1 = (const float*)d_in[8];
    const float* erb1_w2 = (const float*)d_in[9];
    const float* erb2_w1 = (const float*)d_in[10];
    const float* erb2_w2 = (const float*)d_in[11];
    const float* dec_w   = (const float*)d_in[12];
    const float* dec_b   = (const float*)d_in[13];
    const float* drb1_w1 = (const float*)d_in[14];
    const float* drb1_w2 = (const float*)d_in[15];
    const float* drb2_w1 = (const float*)d_in[16];
    const float* drb2_w2 = (const float*)d_in[17];
    const float* dt1_w   = (const float*)d_in[18];
    const float* dt1_b   = (const float*)d_in[19];
    const float* dt2_w   = (const float*)d_in[20];
    const float* dt2_b   = (const float*)d_in[21];

    char* wsb = (char*)d_ws;
    __half* H1 = (__half*)wsb;                           // 33.55 MB
    __half* L1 = (__half*)(wsb + (size_t)33554432);      // 33.55 MB
    __half* H2 = (__half*)(wsb + (size_t)67108864);      // 16.78 MB
    __half* L2 = (__half*)(wsb + (size_t)83886080);      // 16.78 MB
    // x padded planes alias the (not-yet-written) H2/L2 region
    __half* Xh = (__half*)(wsb + (size_t)67108864);      // 8.39 MB
    __half* Xl = (__half*)(wsb + (size_t)75497472);      // 8.39 MB
    __half* H3 = (__half*)wsb;
    __half* L3 = (__half*)(wsb + (size_t)16777216);
    __half* H4 = (__half*)(wsb + (size_t)33554432);
    __half* L4 = (__half*)(wsb + (size_t)50331648);
    __half* Ht = (__half*)(wsb + (size_t)100663296);     // 4.19 MB
    __half* Lt = (__half*)(wsb + (size_t)104857600);     // 4.19 MB
    float*  EN = (float*)(wsb + (size_t)109051904);      // 2 KB
    __half* Fh = (__half*)wsb;
    __half* Fl = (__half*)(wsb + (size_t)16777216);
    bf16* Qb  = (bf16*)(wsb + (size_t)67108864);
    bf16* Db  = (bf16*)(wsb + (size_t)83886080);
    bf16* Y1b = Qb;
    bf16* Y2b = Db;
    bf16* Tb  = (bf16*)(wsb + (size_t)100663296);
    float* Y0 = (float*)wsb;
    float* Y1 = (float*)(wsb + (size_t)33554432);
    float* A1 = (float*)wsb;
    char* pk = wsb + (size_t)109056000;
    bf16* Pdec  = (bf16*)pk;  pk += 147456 * 2;
    bf16* Pd1w1 = (bf16*)pk;  pk += 36864 * 2;
    bf16* Pd1w2 = (bf16*)pk;  pk += 4096 * 2;
    bf16* Pd2w1 = (bf16*)pk;  pk += 36864 * 2;
    bf16* Pd2w2 = (bf16*)pk;  pk += 4096 * 2;
    bf16* Pdt1[4];
    for (int i = 0; i < 4; ++i) { Pdt1[i] = (bf16*)pk; pk += 65536 * 2; }
    __half* P2enc2 = (__half*)pk; pk += 131072 * 4;
    __half* P2enc3 = (__half*)pk; pk += 147456 * 4;
    __half* P2e1w1 = (__half*)pk; pk += 36864 * 4;
    __half* P2e1w2 = (__half*)pk; pk += 4096 * 4;
    __half* P2e2w1 = (__half*)pk; pk += 36864 * 4;
    __half* P2e2w2 = (__half*)pk; pk += 4096 * 4;
    __half* Pe     = (__half*)pk; pk += 131072 * 2;
    __half* Pe1    = (__half*)pk; pk += 8192 * 2;        // enc1 packed weights

    float* outY = (float*)d_out;
    float* outF = outY + 3145728;
    float* outQ = outF + 8388608;

    const TapSet t3 = conv_taps(3, 3, 1);
    const TapSet t4 = conv_taps(4, 4, 1);
    const TapSet t1 = conv_taps(1, 1, 0);
    TapSet tdt[4];
    for (int p = 0; p < 4; ++p) tdt[p] = convt_taps(p >> 1, p & 1);

    enorm_k<<<2, 256, 0, stream>>>(emb, EN);
    pack_emb_k<<<256, 256, 0, stream>>>(emb, Pe);
    pack_we1_k<<<16, 256, 0, stream>>>(enc_w1, Pe1);

    // ---- weight packing ----
    pack_w_k<<<(147456 + 255) / 256, 256, 0, stream>>>(dec_w, Pdec, 128, 128, 64, t3, 147456);
    pack_w_k<<<(36864 + 255) / 256, 256, 0, stream>>>(drb1_w1, Pd1w1, 128, 32, 32, t3, 36864);
    pack_w_k<<<(4096 + 255) / 256, 256, 0, stream>>>(drb1_w2, Pd1w2, 32, 128, 64, t1, 4096);
    pack_w_k<<<(36864 + 255) / 256, 256, 0, stream>>>(drb2_w1, Pd2w1, 128, 32, 32, t3, 36864);
    pack_w_k<<<(4096 + 255) / 256, 256, 0, stream>>>(drb2_w2, Pd2w2, 32, 128, 64, t1, 4096);
    for (int p = 0; p < 4; ++p)
        pack_w_k<<<(65536 + 255) / 256, 256, 0, stream>>>(dt1_w, Pdt1[p], 128, 64, 64, tdt[p], 65536);
    pack_w2_k<<<(131072 + 255) / 256, 256, 0, stream>>>(enc_w2, P2enc2, 64, 128, 64, t4, 131072);
    pack_w2_k<<<(147456 + 255) / 256, 256, 0, stream>>>(enc_w3, P2enc3, 128, 128, 64, t3, 147456);
    pack_w2_k<<<(36864 + 255) / 256, 256, 0, stream>>>(erb1_w1, P2e1w1, 128, 32, 32, t3, 36864);
    pack_w2_k<<<(4096 + 255) / 256, 256, 0, stream>>>(erb1_w2, P2e1w2, 32, 128, 64, t1, 4096);
    pack_w2_k<<<(36864 + 255) / 256, 256, 0, stream>>>(erb2_w1, P2e2w1, 128, 32, 32, t3, 36864);
    pack_w2_k<<<(4096 + 255) / 256, 256, 0, stream>>>(erb2_w2, P2e2w2, 32, 128, 64, t1, 4096);

    // ---- encoder (fp16-split MFMA) ----
    pad_x_k<<<4096, 256, 0, stream>>>(x, Xh, Xl);
    enc1_mfma_k<<<4096, 256, 0, stream>>>(Xh, Xl, Pe1, enc_b1, H1, L1);
    conv_mfma2_k<64><<<dim3(1024, 2), 256, 0, stream>>>(H1, L1, P2enc2, enc_b2,
        nullptr, H2, L2, nullptr, nullptr, 128, 128, 64, 128, 2, t4, 16, F_OUTRELU);
    conv_mfma2_k<64><<<dim3(1024, 2), 256, 0, stream>>>(H2, L2, P2enc3, enc_b3,
        nullptr, H3, L3, nullptr, nullptr, 64, 64, 128, 128, 1, t3, 9, 0);
    conv_mfma2_k<32><<<dim3(1024, 1), 256, 0, stream>>>(H3, L3, P2e1w1, nullptr,
        nullptr, Ht, Lt, nullptr, nullptr, 64, 64, 128, 32, 1, t3, 9, F_INRELU);
    conv_mfma2_k<64><<<dim3(1024, 2), 256, 0, stream>>>(Ht, Lt, P2e1w2, nullptr,
        nullptr, H4, L4, H3, L3, 64, 64, 32, 128, 1, t1, 1, F_INRELU | F_RES);
    conv_mfma2_k<32><<<dim3(1024, 1), 256, 0, stream>>>(H4, L4, P2e2w1, nullptr,
        nullptr, Ht, Lt, nullptr, nullptr, 64, 64, 128, 32, 1, t3, 9, F_INRELU);
    conv_mfma2_k<64><<<dim3(1024, 2), 256, 0, stream>>>(Ht, Lt, P2e2w2, nullptr,
        outF, Fh, Fl, H4, L4, 64, 64, 32, 128, 1, t1, 1, F_INRELU | F_RES | F_OUTRELU);

    // ---- VQ ----
    vq_mfma_k<<<1024, 256, 0, stream>>>(Fh, Fl, Pe, EN, emb, outQ, Qb);

    // ---- decoder (bf16 MFMA) ----
    conv_mfma_k<64><<<dim3(1024, 2), 256, 0, stream>>>(Qb, Pdec, dec_b, Y0, Db, nullptr,
        128, 128, 64, 64, 1, 0, 0, t3, 9, 0);
    conv_mfma_k<32><<<dim3(1024, 1), 256, 0, stream>>>(Db, Pd1w1, nullptr, nullptr, Tb, nullptr,
        128, 32, 64, 64, 1, 0, 0, t3, 9, F_INRELU);
    conv_mfma_k<64><<<dim3(1024, 2), 256, 0, stream>>>(Tb, Pd1w2, nullptr, Y1, Y1b, Y0,
        32, 128, 64, 64, 1, 0, 0, t1, 1, F_INRELU | F_RES);
    conv_mfma_k<32><<<dim3(1024, 1), 256, 0, stream>>>(Y1b, Pd2w1, nullptr, nullptr, Tb, nullptr,
        128, 32, 64, 64, 1, 0, 0, t3, 9, F_INRELU);
    conv_mfma_k<64><<<dim3(1024, 2), 256, 0, stream>>>(Tb, Pd2w2, nullptr, nullptr, Y2b, Y1,
        32, 128, 64, 64, 1, 0, 0, t1, 1, F_INRELU | F_RES | F_OUTRELU);
    for (int p = 0; p < 4; ++p)
        conv_mfma_k<64><<<dim3(1024, 1), 256, 0, stream>>>(Y2b, Pdt1[p], dt1_b, A1, nullptr, nullptr,
            128, 64, 128, 128, 2, p >> 1, p & 1, tdt[p], 4, F_OUTRELU);
    convt_final_k<<<4096, 256, 0, stream>>>(A1, dt2_w, dt2_b, outY);
}